// Round 10
// baseline (531.461 us; speedup 1.0000x reference)
//
#include <hip/hip_runtime.h>
#include <stdint.h>

// Problem constants
#define BB 4
#define LLEN 2048
#define DMODEL 2048
#define NH 24
#define DH 64
#define SS 64
#define DI 1536          // NH*DH
#define N2 3072          // 2*DI
#define NP 3096          // NH*(1+2*S)
#define NP_PAD 3200      // weight rows padded (zero rows 3096..3199); also xp ldc
#define MROWS 8192       // BB*LLEN
#define NCHUNK 16
#define QC 128           // chunk length

using bf16x8 = __bf16 __attribute__((ext_vector_type(8)));
using f32x4  = float __attribute__((ext_vector_type(4)));

__device__ __forceinline__ unsigned short f2bf(float f) {
  union { float f; unsigned int u; } v; v.f = f;
  unsigned int u = v.u + 0x7fffu + ((v.u >> 16) & 1u);
  return (unsigned short)(u >> 16);
}
__device__ __forceinline__ float bf2f(unsigned short h) {
  union { unsigned int u; float f; } v; v.u = ((unsigned int)h) << 16;
  return v.f;
}

__device__ __forceinline__ void gload16(const void* g, void* l) {
  __builtin_amdgcn_global_load_lds(
    reinterpret_cast<const __attribute__((address_space(1))) void*>(reinterpret_cast<uintptr_t>(g)),
    reinterpret_cast<__attribute__((address_space(3))) void*>((uint32_t)(reinterpret_cast<uintptr_t>(l))),
    16, 0, 0);
}

// ---------------- fp32 -> bf16 weight convert (with zero row padding) ----------
__global__ __launch_bounds__(256) void k_w2bf(const float* __restrict__ s,
                                              unsigned short* __restrict__ d,
                                              int n_src, int n_dst) {
  int i = blockIdx.x * 256 + threadIdx.x;
  if (i < n_dst) d[i] = (i < n_src) ? f2bf(s[i]) : (unsigned short)0;
}

// ---------------- RMSNorm -> bf16 ----------------
__global__ __launch_bounds__(256) void k_rmsnorm(const float* __restrict__ hs,
                                                 const float* __restrict__ w,
                                                 unsigned short* __restrict__ out) {
  const int row = blockIdx.x;
  const int t = threadIdx.x;
  const float* x = hs + (size_t)row * DMODEL;
  float4 v0 = reinterpret_cast<const float4*>(x)[t * 2 + 0];
  float4 v1 = reinterpret_cast<const float4*>(x)[t * 2 + 1];
  float ss = v0.x * v0.x + v0.y * v0.y + v0.z * v0.z + v0.w * v0.w +
             v1.x * v1.x + v1.y * v1.y + v1.z * v1.z + v1.w * v1.w;
#pragma unroll
  for (int o = 32; o; o >>= 1) ss += __shfl_xor(ss, o);
  __shared__ float red[4];
  if ((t & 63) == 0) red[t >> 6] = ss;
  __syncthreads();
  ss = red[0] + red[1] + red[2] + red[3];
  const float r = rsqrtf(ss * (1.0f / DMODEL) + 1.1920928955078125e-07f);
  float4 w0 = reinterpret_cast<const float4*>(w)[t * 2 + 0];
  float4 w1 = reinterpret_cast<const float4*>(w)[t * 2 + 1];
  union { unsigned short u[8]; uint4 v; } pk;
  pk.u[0] = f2bf(v0.x * r * w0.x); pk.u[1] = f2bf(v0.y * r * w0.y);
  pk.u[2] = f2bf(v0.z * r * w0.z); pk.u[3] = f2bf(v0.w * r * w0.w);
  pk.u[4] = f2bf(v1.x * r * w1.x); pk.u[5] = f2bf(v1.y * r * w1.y);
  pk.u[6] = f2bf(v1.z * r * w1.z); pk.u[7] = f2bf(v1.w * r * w1.w);
  *reinterpret_cast<uint4*>(out + (size_t)row * DMODEL + t * 8) = pk.v;
}

// ---------------- drift + distance-2 bf16 NT GEMM (128x256 tile, BK=64) --------
// ONE barrier per K-tile (waves drift; ds_reads overlap other waves' MFMA) AND
// 3-buffer ring with prefetch distance 2 + counted vmcnt(6) (2-tile ~2600cy
// latency coverage > 900cy HBM miss). EPI 1: bf16 C = acc+bias.
// EPI 2: fp32 C = resid + rg*(acc+bias). 512 thr = 8 waves (2M x 4N), 64x64/wave.
// LDS 144KB = 3 x (A 16KB + B 32KB).
template <int EPI>
__global__ __launch_bounds__(512, 2)
void k_gemm6(const unsigned short* __restrict__ A, const unsigned short* __restrict__ B,
             const float* __restrict__ bias, void* __restrict__ Cv,
             const float* __restrict__ resid, const float* __restrict__ gatep,
             int K, int NT_N, int Nout, int ldc) {
  constexpr int AELEM = 128 * 64;        // A elements per buffer
  constexpr int BUFE = AELEM + 16384;    // +B (256x64) = 24576 elems = 48KB
  __shared__ alignas(16) unsigned short sm[3 * BUFE];
  const int tid = threadIdx.x;
  const int lane = tid & 63, wid = tid >> 6;
  const int wm = wid >> 2, wn = wid & 3;
  const int fr = lane & 15, kg = lane >> 4;
  const int nwg = gridDim.x;
  const int wg = ((int)blockIdx.x & 7) * (nwg >> 3) + ((int)blockIdx.x >> 3);
  const int m0 = (wg / NT_N) * 128, n0 = (wg % NT_N) * 256;
  const int NT = K >> 6;

  // pre-swizzled per-lane global staging sources (granule q ^= row&7)
  const unsigned short* asrc[2];
  const unsigned short* bsrc[4];
#pragma unroll
  for (int li = 0; li < 2; ++li) {
    const int gi = li * 512 + tid, r = gi >> 3, q = gi & 7;
    asrc[li] = A + (size_t)(m0 + r) * K + ((q ^ (r & 7)) << 3);
  }
#pragma unroll
  for (int li = 0; li < 4; ++li) {
    const int gi = li * 512 + tid, r = gi >> 3, q = gi & 7;
    bsrc[li] = B + (size_t)(n0 + r) * K + ((q ^ (r & 7)) << 3);
  }
  const int wlds = wid * 64;

#define STG6(buf, ko)                                                          \
  { unsigned short* da_ = sm + (buf) * BUFE;                                   \
    gload16(asrc[0] + (ko), da_ + ((0 * 512 + wlds) << 3));                    \
    gload16(asrc[1] + (ko), da_ + ((1 * 512 + wlds) << 3));                    \
    unsigned short* db_ = sm + (buf) * BUFE + AELEM;                           \
    _Pragma("unroll") for (int li = 0; li < 4; ++li)                           \
      gload16(bsrc[li] + (ko), db_ + ((li * 512 + wlds) << 3)); }

#define ARD6(bufp, f, kk)                                                      \
  (*(const bf16x8*)((bufp) + (wm * 64 + (f) * 16 + fr) * 64 +                  \
      ((((kk) * 4 + kg) ^ (fr & 7)) << 3)))
#define BRD6(bufp, nf, kk)                                                     \
  (*(const bf16x8*)((bufp) + AELEM + (wn * 64 + (nf) * 16 + fr) * 64 +         \
      ((((kk) * 4 + kg) ^ (fr & 7)) << 3)))

  f32x4 acc[4][4] = {};

  // prologue: stage tiles 0 and 1 (12 loads); retire tile0's 6
  STG6(0, 0)
  STG6(1, 64)
  asm volatile("s_waitcnt vmcnt(6)" ::: "memory");
  __builtin_amdgcn_s_barrier();

  int bc_i = 0;
  for (int t = 0; t < NT; ++t) {
    unsigned short* bc = sm + bc_i * BUFE;
    const int bn_i = (bc_i + 2 >= 3) ? (bc_i - 1) : (bc_i + 2);
    const bool st = (t + 2) < NT;
    if (st) STG6(bn_i, (t + 2) << 6)

    bf16x8 bfv[4][2], af[4][2];
#pragma unroll
    for (int nf = 0; nf < 4; ++nf) {
      bfv[nf][0] = BRD6(bc, nf, 0);
      bfv[nf][1] = BRD6(bc, nf, 1);
    }
#pragma unroll
    for (int mf = 0; mf < 4; ++mf) {
      af[mf][0] = ARD6(bc, mf, 0);
      af[mf][1] = ARD6(bc, mf, 1);
    }
    __builtin_amdgcn_sched_barrier(0);
    asm volatile("s_waitcnt lgkmcnt(0)" ::: "memory");
    __builtin_amdgcn_sched_barrier(0);
    __builtin_amdgcn_s_setprio(1);
#pragma unroll
    for (int mf = 0; mf < 4; ++mf)
#pragma unroll
      for (int nf = 0; nf < 4; ++nf)
#pragma unroll
        for (int kk = 0; kk < 2; ++kk)
          acc[mf][nf] = __builtin_amdgcn_mfma_f32_16x16x32_bf16(
              af[mf][kk], bfv[nf][kk], acc[mf][nf], 0, 0, 0);
    __builtin_amdgcn_s_setprio(0);

    // boundary: tile t+1's loads must be resident (t+2's 6 may stay in flight)
    if (st) { asm volatile("s_waitcnt vmcnt(6)" ::: "memory"); }
    else    { asm volatile("s_waitcnt vmcnt(0)" ::: "memory"); }
    __builtin_amdgcn_s_barrier();
    bc_i = (bc_i + 1 >= 3) ? 0 : (bc_i + 1);
  }

  // epilogue
  float* Cf = (float*)Cv;
  unsigned short* Ch = (unsigned short*)Cv;
  const float rg = (EPI == 2) ? gatep[0] : 0.f;
#pragma unroll
  for (int nf = 0; nf < 4; ++nf) {
    const int col = n0 + wn * 64 + nf * 16 + fr;
    if (col >= Nout) continue;
    const float bv = bias[col];
#pragma unroll
    for (int mf = 0; mf < 4; ++mf) {
      const int rowb = m0 + wm * 64 + mf * 16 + kg * 4;
#pragma unroll
      for (int r = 0; r < 4; ++r) {
        const size_t o = (size_t)(rowb + r) * ldc + col;
        float v = acc[mf][nf][r] + bv;
        if (EPI == 1) {
          Ch[o] = f2bf(v);
        } else {
          if (EPI == 2) v = resid[o] + rg * v;
          Cf[o] = v;
        }
      }
    }
  }
#undef STG6
#undef ARD6
#undef BRD6
}

// ---------------- depthwise causal conv(4) + silu, 4 timesteps x 8 ch/thread ---
__global__ __launch_bounds__(256) void k_dwconv(const unsigned short* __restrict__ xz,
                                                const float* __restrict__ cw,
                                                const float* __restrict__ cb,
                                                unsigned short* __restrict__ out) {
  const int idx = blockIdx.x * 256 + threadIdx.x;  // < (MROWS/4)*192
  const int c0 = (idx % 192) * 8;
  const int bl0 = (idx / 192) * 4;
  const int lpos0 = bl0 & (LLEN - 1);
  float w[8][4];
#pragma unroll
  for (int j = 0; j < 8; ++j) {
    const float4 wv = *(const float4*)(cw + (c0 + j) * 4);
    w[j][0] = wv.x; w[j][1] = wv.y; w[j][2] = wv.z; w[j][3] = wv.w;
  }
  float xr[7][8];
#pragma unroll
  for (int m = 0; m < 7; ++m) {
    uint4 xv = make_uint4(0u, 0u, 0u, 0u);
    if (lpos0 - 3 + m >= 0)
      xv = *(const uint4*)(xz + (size_t)(bl0 - 3 + m) * N2 + c0);
    const unsigned short* xs = (const unsigned short*)&xv;
#pragma unroll
    for (int j = 0; j < 8; ++j) xr[m][j] = bf2f(xs[j]);
  }
  const float4 cb0 = *(const float4*)(cb + c0);
  const float4 cb1 = *(const float4*)(cb + c0 + 4);
  const float cbv[8] = {cb0.x, cb0.y, cb0.z, cb0.w, cb1.x, cb1.y, cb1.z, cb1.w};
#pragma unroll
  for (int t4 = 0; t4 < 4; ++t4) {
    union { unsigned short u[8]; uint4 v; } pk;
#pragma unroll
    for (int j = 0; j < 8; ++j) {
      float a = cbv[j];
#pragma unroll
      for (int k = 0; k < 4; ++k) a = fmaf(w[j][k], xr[t4 + k][j], a);
      a = a / (1.f + __expf(-a));
      pk.u[j] = f2bf(a);
    }
    *(uint4*)(out + (size_t)(bl0 + t4) * DI + c0) = pk.v;
  }
}

// ---------------- prep: read bf16 xp, write normalized B/C to Bn/Cn, alpha -----
__global__ __launch_bounds__(256) void k_prep(const unsigned short* __restrict__ xp,
                                              const unsigned short* __restrict__ xc,
                                              const float* __restrict__ A_log,
                                              const float* __restrict__ l2ab,
                                              const float* __restrict__ l2b,
                                              const float* __restrict__ se,
                                              unsigned short* __restrict__ Bn,
                                              unsigned short* __restrict__ Cn,
                                              float* __restrict__ al) {
  const int blk = blockIdx.x;               // MROWS*6
  const int w = threadIdx.x >> 6, lane = threadIdx.x & 63;
  const int bl = blk / 6, hq = blk % 6;
  const int h = hq * 4 + w;
  const size_t pbase = (size_t)bl * NP_PAD + h * 129;
  const float bs = bf2f(xp[pbase + 1 + lane]);
  const float cs = bf2f(xp[pbase + 65 + lane]);
  const float xv = bf2f(xc[(size_t)bl * DI + h * DH + lane]);
  float sb = bs * bs, sc = cs * cs, sx = xv;
#pragma unroll
  for (int o = 32; o; o >>= 1) {
    sb += __shfl_xor(sb, o);
    sc += __shfl_xor(sc, o);
    sx += __shfl_xor(sx, o);
  }
  const float nb = fmaxf(sqrtf(sb), 1e-12f);
  const float nc = fmaxf(sqrtf(sc), 1e-12f);
  const int b = bl >> 11, l = bl & (LLEN - 1);
  const size_t ob = (((size_t)(b * NH + h) << 11) + l) * 64 + lane;
  Bn[ob] = f2bf(bs / nb);
  Cn[ob] = f2bf(cs / nc);
  const float sumB2 = sb / (nb * nb);
  const float xmean = sx * (1.f / 64.f);
  const float dt = bf2f(xp[pbase]);
  const float sp = (dt > 20.f) ? dt : log1pf(expf(dt));
  const float Ac = fminf(fmaxf(A_log[h], -2.3f), -0.01f);
  const float aa = expf(Ac * sp);
  const float one_a = 1.f - aa;
  const float pe = one_a * one_a * xmean * xmean * sumB2 * (1.f / 64.f);
  const float ns = pe / (se[h] + 1e-6f);
  const float beta = exp2f(fminf(fmaxf(l2b[h], -2.f), 2.f));
  const float boost = fmaxf(tanhf(beta * ns), 0.f);
  const float ab = 1.f - exp2f(fminf(fmaxf(l2ab[h], -3.32f), -0.015f));
  const float alpha = fminf(fmaxf(ab + (1.f - ab) * boost, 0.01f), 0.999f);
  if (lane == 0) al[(((size_t)b * NH + h) << 11) + l] = alpha;
}

// ---------------- chunked scan, stage 1: intra-chunk Y + local state -----------
__global__ __launch_bounds__(256) void k_chunk1(
    const unsigned short* __restrict__ Bn, const unsigned short* __restrict__ Cn,
    const unsigned short* __restrict__ xcg, const float* __restrict__ al,
    unsigned short* __restrict__ xz, unsigned short* __restrict__ Hbuf,
    float* __restrict__ Dc) {
  const int blk = blockIdx.x;          // bh*16 + c
  const int bh = blk >> 4, c = blk & 15;
  const int b = bh / NH, h = bh % NH;
  const int tid = threadIdx.x, w = tid >> 6, lane = tid & 63;
  const int fr = lane & 15, kg = lane >> 4;
  const int rbase = b * LLEN + c * QC;
  const size_t bcb = (((size_t)bh << 11) + c * QC) * 64;  // Bn/Cn base

  __shared__ float lc[QC], ia[QC], escl[QC];
  __shared__ float wtot[2];
  __shared__ alignas(16) unsigned short XT[64][152];   // [d][u]
  __shared__ alignas(16) unsigned short BsT[64][152];  // [s][u] (scaled)
  __shared__ alignas(16) unsigned short Pt[128][88];   // [t][u-local]

  float a = 1.f, la = 0.f;
  if (tid < QC) { a = al[(size_t)bh * LLEN + c * QC + tid]; la = __logf(a); }
  float s = la;
#pragma unroll
  for (int o = 1; o < 64; o <<= 1) { float t2 = __shfl_up(s, o); if (lane >= o) s += t2; }
  if (tid < QC && lane == 63) wtot[w] = s;
  __syncthreads();
  if (tid < QC) { lc[tid] = s + ((w == 1) ? wtot[0] : 0.f); ia[tid] = 1.f - a; }
  __syncthreads();
  const float lcE = lc[QC - 1];
  if (tid < QC) escl[tid] = __expf(lcE - lc[tid]) * ia[tid];
  if (tid == 0) Dc[blk] = __expf(lcE);
  __syncthreads();

  {
    const int r8 = tid >> 3, q8 = tid & 7;
#pragma unroll
    for (int it = 0; it < 4; ++it) {
      const int u = it * 32 + r8;
      const uint4 xv = *(const uint4*)(xcg + (size_t)(rbase + u) * DI + h * DH + q8 * 8);
      const unsigned short* xs = (const unsigned short*)&xv;
#pragma unroll
      for (int j = 0; j < 8; ++j) XT[q8 * 8 + j][u] = xs[j];
      const uint4 bv = *(const uint4*)(Bn + bcb + (size_t)u * 64 + q8 * 8);
      const unsigned short* bsv = (const unsigned short*)&bv;
      const float e = escl[u];
#pragma unroll
      for (int j = 0; j < 8; ++j) BsT[q8 * 8 + j][u] = f2bf(bf2f(bsv[j]) * e);
    }
  }
  bf16x8 cf[2][2];
#pragma unroll
  for (int fi = 0; fi < 2; ++fi)
#pragma unroll
    for (int kk = 0; kk < 2; ++kk) {
      const int t = w * 32 + fi * 16 + fr;
      const uint4 v = *(const uint4*)(Cn + bcb + (size_t)t * 64 + kk * 32 + kg * 8);
      cf[fi][kk] = *(const bf16x8*)&v;
    }
  __syncthreads();

  float lct[2][4];
#pragma unroll
  for (int fi = 0; fi < 2; ++fi)
#pragma unroll
    for (int r = 0; r < 4; ++r) lct[fi][r] = lc[w * 32 + fi * 16 + kg * 4 + r];

  f32x4 yacc[2][4] = {};
  f32x4 hacc[4] = {};
#pragma unroll
  for (int ut = 0; ut < 2; ++ut) {
    f32x4 g[2][4] = {};
#pragma unroll
    for (int kk = 0; kk < 2; ++kk)
#pragma unroll
      for (int fj = 0; fj < 4; ++fj) {
        const int u = ut * 64 + fj * 16 + fr;
        const uint4 v = *(const uint4*)(Bn + bcb + (size_t)u * 64 + kk * 32 + kg * 8);
        const bf16x8 bfrag = *(const bf16x8*)&v;
#pragma unroll
        for (int fi = 0; fi < 2; ++fi)
          g[fi][fj] = __builtin_amdgcn_mfma_f32_16x16x32_bf16(cf[fi][kk], bfrag, g[fi][fj], 0, 0, 0);
      }
#pragma unroll
    for (int fi = 0; fi < 2; ++fi)
#pragma unroll
      for (int fj = 0; fj < 4; ++fj) {
        const int u = ut * 64 + fj * 16 + fr;
        const float lcu = lc[u], iau = ia[u];
#pragma unroll
        for (int r = 0; r < 4; ++r) {
          const int t = w * 32 + fi * 16 + kg * 4 + r;
          const float v = (t >= u) ? g[fi][fj][r] * __expf(lct[fi][r] - lcu) * iau : 0.f;
          Pt[t][fj * 16 + fr] = f2bf(v);
        }
      }
#pragma unroll
    for (int kk = 0; kk < 2; ++kk) {
      bf16x8 xf[4];
#pragma unroll
      for (int fj = 0; fj < 4; ++fj)
        xf[fj] = *(const bf16x8*)&XT[fj * 16 + fr][ut * 64 + kk * 32 + kg * 8];
      bf16x8 pf[2];
#pragma unroll
      for (int fi = 0; fi < 2; ++fi)
        pf[fi] = *(const bf16x8*)&Pt[w * 32 + fi * 16 + fr][kk * 32 + kg * 8];
#pragma unroll
      for (int fi = 0; fi < 2; ++fi)
#pragma unroll
        for (int fj = 0; fj < 4; ++fj)
          yacc[fi][fj] = __builtin_amdgcn_mfma_f32_16x16x32_bf16(pf[fi], xf[fj], yacc[fi][fj], 0, 0, 0);
      const bf16x8 xh = *(const bf16x8*)&XT[w * 16 + fr][ut * 64 + kk * 32 + kg * 8];
#pragma unroll
      for (int fi = 0; fi < 4; ++fi) {
        const bf16x8 bs = *(const bf16x8*)&BsT[fi * 16 + fr][ut * 64 + kk * 32 + kg * 8];
        hacc[fi] = __builtin_amdgcn_mfma_f32_16x16x32_bf16(bs, xh, hacc[fi], 0, 0, 0);
      }
    }
  }
#pragma unroll
  for (int fi = 0; fi < 2; ++fi)
#pragma unroll
    for (int fj = 0; fj < 4; ++fj)
#pragma unroll
      for (int r = 0; r < 4; ++r) {
        const int t = w * 32 + fi * 16 + kg * 4 + r;
        const int d = fj * 16 + fr;
        xz[(size_t)(rbase + t) * N2 + h * DH + d] = f2bf(yacc[fi][fj][r]);
      }
  const int dcol = w * 16 + fr;
#pragma unroll
  for (int fi = 0; fi < 4; ++fi) {
    ushort4 pk;
    pk.x = f2bf(hacc[fi][0]); pk.y = f2bf(hacc[fi][1]);
    pk.z = f2bf(hacc[fi][2]); pk.w = f2bf(hacc[fi][3]);
    *(ushort4*)(Hbuf + ((size_t)blk * 64 + dcol) * 64 + fi * 16 + kg * 4) = pk;
  }
}

// ---------------- chunked scan, stage 2: carry across chunks (in place) --------
__global__ __launch_bounds__(256) void k_carry(unsigned short* __restrict__ Hbuf,
                                               const float* __restrict__ Dc) {
  const int bh = blockIdx.x, tid = threadIdx.x;
  float carry[16];
#pragma unroll
  for (int j = 0; j < 16; ++j) carry[j] = 0.f;
  for (int c = 0; c < NCHUNK; ++c) {
    unsigned short* p = Hbuf + (((size_t)(bh * NCHUNK + c)) << 12) + tid * 16;
    const uint4 v0 = *(const uint4*)(p);
    const uint4 v1 = *(const uint4*)(p + 8);
    const unsigned short* hs0 = (const unsigned short*)&v0;
    const unsigned short* hs1 = (const unsigned short*)&v1;
    float hl[16];
#pragma unroll
    for (int j = 0; j < 8; ++j) { hl[j] = bf2f(hs0[j]); hl[8 + j] = bf2f(hs1[j]); }
    uint4 o0, o1;
    unsigned short* os0 = (unsigned short*)&o0;
    unsigned short* os1 = (unsigned short*)&o1;
#pragma unroll
    for (int j = 0; j < 8; ++j) { os0[j] = f2bf(carry[j]); os1[j] = f2bf(carry[8 + j]); }
    *(uint4*)(p) = o0;
    *(uint4*)(p + 8) = o1;
    const float dc = Dc[bh * NCHUNK + c];
#pragma unroll
    for (int j = 0; j < 16; ++j) carry[j] = fmaf(dc, carry[j], hl[j]);
  }
}

// ---------------- chunked scan, stage 3: inter-chunk Y + fused gating ----------
__global__ __launch_bounds__(256) void k_chunk2(
    const unsigned short* __restrict__ Cn, const float* __restrict__ al,
    const unsigned short* __restrict__ Hbuf, const unsigned short* __restrict__ xz,
    unsigned short* __restrict__ xcg) {
  const int blk = blockIdx.x;
  const int bh = blk >> 4, c = blk & 15;
  const int b = bh / NH, h = bh % NH;
  const int tid = threadIdx.x, w = tid >> 6, lane = tid & 63;
  const int fr = lane & 15, kg = lane >> 4;
  const int rbase = b * LLEN + c * QC;
  const size_t bcb = (((size_t)bh << 11) + c * QC) * 64;
  __shared__ float lc[QC];
  __shared__ float wtot[2];
  float a = 1.f, la = 0.f;
  if (tid < QC) { a = al[(size_t)bh * LLEN + c * QC + tid]; la = __logf(a); }
  float s = la;
#pragma unroll
  for (int o = 1; o < 64; o <<= 1) { float t2 = __shfl_up(s, o); if (lane >= o) s += t2; }
  if (tid < QC && lane == 63) wtot[w] = s;
  __syncthreads();
  if (tid < QC) lc[tid] = s + ((w == 1) ? wtot[0] : 0.f);
  __syncthreads();
  bf16x8 cf[2][2];
#pragma unroll
  for (int fi = 0; fi < 2; ++fi) {
    const int t = w * 32 + fi * 16 + fr;
    const float sc = __expf(lc[t]);
#pragma unroll
    for (int kk = 0; kk < 2; ++kk) {
      const uint4 v = *(const uint4*)(Cn + bcb + (size_t)t * 64 + kk * 32 + kg * 8);
      const unsigned short* cs = (const unsigned short*)&v;
      union { unsigned short us[8]; bf16x8 vv; } uv;
#pragma unroll
      for (int q = 0; q < 8; ++q) uv.us[q] = f2bf(bf2f(cs[q]) * sc);
      cf[fi][kk] = uv.vv;
    }
  }
  bf16x8 hf[4][2];
#pragma unroll
  for (int fj = 0; fj < 4; ++fj)
#pragma unroll
    for (int kk = 0; kk < 2; ++kk) {
      const uint4 v = *(const uint4*)(Hbuf + ((size_t)blk * 64 + fj * 16 + fr) * 64 + kk * 32 + kg * 8);
      hf[fj][kk] = *(const bf16x8*)&v;
    }
  f32x4 y[2][4] = {};
#pragma unroll
  for (int kk = 0; kk < 2; ++kk)
#pragma unroll
    for (int fi = 0; fi < 2; ++fi)
#pragma unroll
      for (int fj = 0; fj < 4; ++fj)
        y[fi][fj] = __builtin_amdgcn_mfma_f32_16x16x32_bf16(cf[fi][kk], hf[fj][kk], y[fi][fj], 0, 0, 0);
#pragma unroll
  for (int fi = 0; fi < 2; ++fi)
#pragma unroll
    for (int fj = 0; fj < 4; ++fj)
#pragma unroll
      for (int r = 0; r < 4; ++r) {
        const int t = w * 32 + fi * 16 + kg * 4 + r;
        const int d = fj * 16 + fr;
        const size_t rowg = (size_t)(rbase + t);
        const float yv = y[fi][fj][r] + bf2f(xz[rowg * N2 + h * DH + d]);
        const float zv = bf2f(xz[rowg * N2 + DI + h * DH + d]);
        const float g = yv * (zv / (1.f + __expf(-zv)));
        xcg[rowg * DI + h * DH + d] = f2bf(g);
      }
}

extern "C" void kernel_launch(void* const* d_in, const int* in_sizes, int n_in,
                              void* d_out, int out_size, void* d_ws, size_t ws_size,
                              hipStream_t stream) {
  const float* hs     = (const float*)d_in[0];
  const float* norm_w = (const float*)d_in[1];
  const float* in_w   = (const float*)d_in[2];
  const float* in_b   = (const float*)d_in[3];
  const float* cw     = (const float*)d_in[4];
  const float* cb     = (const float*)d_in[5];
  const float* xw     = (const float*)d_in[6];
  const float* xb     = (const float*)d_in[7];
  const float* A_log  = (const float*)d_in[8];
  const float* l2ab   = (const float*)d_in[9];
  const float* l2b    = (const float*)d_in[10];
  const float* se     = (const float*)d_in[11];
  const float* ow     = (const float*)d_in[12];
  const float* ob     = (const float*)d_in[13];
  const float* rg     = (const float*)d_in[14];
  float* out = (float*)d_out;

  char* ws = (char*)d_ws;
  unsigned short* xnorm = (unsigned short*)(ws);
  unsigned short* wA    = (unsigned short*)(ws + 33554432ull);
  unsigned short* wX    = (unsigned short*)(ws + 46137344ull);
  unsigned short* wO    = (unsigned short*)(ws + 55967744ull);
  unsigned short* xz    = (unsigned short*)(ws + 62259200ull);
  unsigned short* xp    = (unsigned short*)(ws + 112590848ull);
  unsigned short* Bn    = (unsigned short*)(ws + 165019648ull);
  unsigned short* Cn    = (unsigned short*)(ws + 190185472ull);
  unsigned short* xcg   = xnorm;
  unsigned short* Hbuf  = wA;
  float* al             = (float*)(ws + 46137344ull);
  float* Dc             = (float*)(ws + 46137344ull + 786432ull);

  k_w2bf<<<(N2 * DMODEL) / 256, 256, 0, stream>>>(in_w, wA, N2 * DMODEL, N2 * DMODEL);
  k_w2bf<<<(NP_PAD * DI) / 256, 256, 0, stream>>>(xw, wX, NP * DI, NP_PAD * DI);
  k_w2bf<<<(DMODEL * DI) / 256, 256, 0, stream>>>(ow, wO, DMODEL * DI, DMODEL * DI);

  k_rmsnorm<<<MROWS, 256, 0, stream>>>(hs, norm_w, xnorm);
  // in_proj: 64 x 12 = 768 blocks (exactly 3 rounds), bf16 out
  k_gemm6<1><<<768, 512, 0, stream>>>(xnorm, wA, in_b, xz, nullptr, nullptr,
                                      DMODEL, 12, N2, N2);
  k_dwconv<<<(MROWS / 4) * 192 / 256, 256, 0, stream>>>(xz, cw, cb, xcg);
  // x_proj: 64 x 13 = 832 blocks, bf16 out, ldc 3200
  k_gemm6<1><<<832, 512, 0, stream>>>(xcg, wX, xb, xp, nullptr, nullptr,
                                      DI, 13, NP, NP_PAD);
  k_prep<<<MROWS * 6, 256, 0, stream>>>(xp, xcg, A_log, l2ab, l2b, se, Bn, Cn, al);

  k_chunk1<<<BB * NH * NCHUNK, 256, 0, stream>>>(Bn, Cn, xcg, al, xz, Hbuf, Dc);
  k_carry<<<BB * NH, 256, 0, stream>>>(Hbuf, Dc);
  k_chunk2<<<BB * NH * NCHUNK, 256, 0, stream>>>(Cn, al, Hbuf, xz, xcg);

  // out_proj: 64 x 8 = 512 blocks (exactly 2 rounds), fp32 + residual
  k_gemm6<2><<<512, 512, 0, stream>>>(xcg, wO, ob, out, hs, rg,
                                      DI, 8, DMODEL, DMODEL);
}

// Round 11
// 507.695 us; speedup vs baseline: 1.0468x; 1.0468x over previous
//
#include <hip/hip_runtime.h>
#include <stdint.h>

// Problem constants
#define BB 4
#define LLEN 2048
#define DMODEL 2048
#define NH 24
#define DH 64
#define SS 64
#define DI 1536          // NH*DH
#define N2 3072          // 2*DI
#define NP 3096          // NH*(1+2*S)
#define NP_PAD 3200      // weight rows padded (zero rows 3096..3199)
#define MROWS 8192       // BB*LLEN
#define NCHUNK 16
#define QC 128           // chunk length
#define XP2LD 136        // xp2 row stride (17*8 -> 16B-aligned rows)

using bf16x8 = __bf16 __attribute__((ext_vector_type(8)));
using f32x4  = float __attribute__((ext_vector_type(4)));

__device__ __forceinline__ unsigned short f2bf(float f) {
  union { float f; unsigned int u; } v; v.f = f;
  unsigned int u = v.u + 0x7fffu + ((v.u >> 16) & 1u);
  return (unsigned short)(u >> 16);
}
__device__ __forceinline__ float bf2f(unsigned short h) {
  union { unsigned int u; float f; } v; v.u = ((unsigned int)h) << 16;
  return v.f;
}

__device__ __forceinline__ void gload16(const void* g, void* l) {
  __builtin_amdgcn_global_load_lds(
    reinterpret_cast<const __attribute__((address_space(1))) void*>(reinterpret_cast<uintptr_t>(g)),
    reinterpret_cast<__attribute__((address_space(3))) void*>((uint32_t)(reinterpret_cast<uintptr_t>(l))),
    16, 0, 0);
}

// ---------------- fused fp32 -> bf16 weight convert (3 weights, 1 launch) ------
__global__ __launch_bounds__(256) void k_w2bf3(
    const float* __restrict__ s0, unsigned short* __restrict__ d0, int n0,
    const float* __restrict__ s1, unsigned short* __restrict__ d1, int n1s, int n1d,
    const float* __restrict__ s2, unsigned short* __restrict__ d2, int n2) {
  int i = blockIdx.x * 256 + threadIdx.x;
  if (i < n0) { d0[i] = f2bf(s0[i]); return; }
  i -= n0;
  if (i < n1d) { d1[i] = (i < n1s) ? f2bf(s1[i]) : (unsigned short)0; return; }
  i -= n1d;
  if (i < n2) d2[i] = f2bf(s2[i]);
}

// ---------------- RMSNorm -> bf16 ----------------
__global__ __launch_bounds__(256) void k_rmsnorm(const float* __restrict__ hs,
                                                 const float* __restrict__ w,
                                                 unsigned short* __restrict__ out) {
  const int row = blockIdx.x;
  const int t = threadIdx.x;
  const float* x = hs + (size_t)row * DMODEL;
  float4 v0 = reinterpret_cast<const float4*>(x)[t * 2 + 0];
  float4 v1 = reinterpret_cast<const float4*>(x)[t * 2 + 1];
  float ss = v0.x * v0.x + v0.y * v0.y + v0.z * v0.z + v0.w * v0.w +
             v1.x * v1.x + v1.y * v1.y + v1.z * v1.z + v1.w * v1.w;
#pragma unroll
  for (int o = 32; o; o >>= 1) ss += __shfl_xor(ss, o);
  __shared__ float red[4];
  if ((t & 63) == 0) red[t >> 6] = ss;
  __syncthreads();
  ss = red[0] + red[1] + red[2] + red[3];
  const float r = rsqrtf(ss * (1.0f / DMODEL) + 1.1920928955078125e-07f);
  float4 w0 = reinterpret_cast<const float4*>(w)[t * 2 + 0];
  float4 w1 = reinterpret_cast<const float4*>(w)[t * 2 + 1];
  union { unsigned short u[8]; uint4 v; } pk;
  pk.u[0] = f2bf(v0.x * r * w0.x); pk.u[1] = f2bf(v0.y * r * w0.y);
  pk.u[2] = f2bf(v0.z * r * w0.z); pk.u[3] = f2bf(v0.w * r * w0.w);
  pk.u[4] = f2bf(v1.x * r * w1.x); pk.u[5] = f2bf(v1.y * r * w1.y);
  pk.u[6] = f2bf(v1.z * r * w1.z); pk.u[7] = f2bf(v1.w * r * w1.w);
  *reinterpret_cast<uint4*>(out + (size_t)row * DMODEL + t * 8) = pk.v;
}

// ---------------- drift + distance-2 bf16 NT GEMM (128x256 tile, BK=64) --------
// EPI 1: bf16 C = acc+bias. EPI 2: fp32 C = resid + rg*(acc+bias).
// EPI 3: bf16 head-blocked xp2 write: col -> (h=col/129, e=col%129);
//        dst = ((b*NH+h)*2048 + l)*136 + (e==0 ? 128 : e-1).
template <int EPI>
__global__ __launch_bounds__(512, 2)
void k_gemm6(const unsigned short* __restrict__ A, const unsigned short* __restrict__ B,
             const float* __restrict__ bias, void* __restrict__ Cv,
             const float* __restrict__ resid, const float* __restrict__ gatep,
             int K, int NT_N, int Nout, int ldc) {
  constexpr int AELEM = 128 * 64;
  constexpr int BUFE = AELEM + 16384;
  __shared__ alignas(16) unsigned short sm[3 * BUFE];
  const int tid = threadIdx.x;
  const int lane = tid & 63, wid = tid >> 6;
  const int wm = wid >> 2, wn = wid & 3;
  const int fr = lane & 15, kg = lane >> 4;
  const int nwg = gridDim.x;
  const int wg = ((int)blockIdx.x & 7) * (nwg >> 3) + ((int)blockIdx.x >> 3);
  const int m0 = (wg / NT_N) * 128, n0 = (wg % NT_N) * 256;
  const int NT = K >> 6;

  const unsigned short* asrc[2];
  const unsigned short* bsrc[4];
#pragma unroll
  for (int li = 0; li < 2; ++li) {
    const int gi = li * 512 + tid, r = gi >> 3, q = gi & 7;
    asrc[li] = A + (size_t)(m0 + r) * K + ((q ^ (r & 7)) << 3);
  }
#pragma unroll
  for (int li = 0; li < 4; ++li) {
    const int gi = li * 512 + tid, r = gi >> 3, q = gi & 7;
    bsrc[li] = B + (size_t)(n0 + r) * K + ((q ^ (r & 7)) << 3);
  }
  const int wlds = wid * 64;

#define STG6(buf, ko)                                                          \
  { unsigned short* da_ = sm + (buf) * BUFE;                                   \
    gload16(asrc[0] + (ko), da_ + ((0 * 512 + wlds) << 3));                    \
    gload16(asrc[1] + (ko), da_ + ((1 * 512 + wlds) << 3));                    \
    unsigned short* db_ = sm + (buf) * BUFE + AELEM;                           \
    _Pragma("unroll") for (int li = 0; li < 4; ++li)                           \
      gload16(bsrc[li] + (ko), db_ + ((li * 512 + wlds) << 3)); }

#define ARD6(bufp, f, kk)                                                      \
  (*(const bf16x8*)((bufp) + (wm * 64 + (f) * 16 + fr) * 64 +                  \
      ((((kk) * 4 + kg) ^ (fr & 7)) << 3)))
#define BRD6(bufp, nf, kk)                                                     \
  (*(const bf16x8*)((bufp) + AELEM + (wn * 64 + (nf) * 16 + fr) * 64 +         \
      ((((kk) * 4 + kg) ^ (fr & 7)) << 3)))

  f32x4 acc[4][4] = {};

  STG6(0, 0)
  STG6(1, 64)
  asm volatile("s_waitcnt vmcnt(6)" ::: "memory");
  __builtin_amdgcn_s_barrier();

  int bc_i = 0;
  for (int t = 0; t < NT; ++t) {
    unsigned short* bc = sm + bc_i * BUFE;
    const int bn_i = (bc_i + 2 >= 3) ? (bc_i - 1) : (bc_i + 2);
    const bool st = (t + 2) < NT;
    if (st) STG6(bn_i, (t + 2) << 6)

    bf16x8 bfv[4][2], af[4][2];
#pragma unroll
    for (int nf = 0; nf < 4; ++nf) {
      bfv[nf][0] = BRD6(bc, nf, 0);
      bfv[nf][1] = BRD6(bc, nf, 1);
    }
#pragma unroll
    for (int mf = 0; mf < 4; ++mf) {
      af[mf][0] = ARD6(bc, mf, 0);
      af[mf][1] = ARD6(bc, mf, 1);
    }
    __builtin_amdgcn_sched_barrier(0);
    asm volatile("s_waitcnt lgkmcnt(0)" ::: "memory");
    __builtin_amdgcn_sched_barrier(0);
    __builtin_amdgcn_s_setprio(1);
#pragma unroll
    for (int mf = 0; mf < 4; ++mf)
#pragma unroll
      for (int nf = 0; nf < 4; ++nf)
#pragma unroll
        for (int kk = 0; kk < 2; ++kk)
          acc[mf][nf] = __builtin_amdgcn_mfma_f32_16x16x32_bf16(
              af[mf][kk], bfv[nf][kk], acc[mf][nf], 0, 0, 0);
    __builtin_amdgcn_s_setprio(0);

    if (st) { asm volatile("s_waitcnt vmcnt(6)" ::: "memory"); }
    else    { asm volatile("s_waitcnt vmcnt(0)" ::: "memory"); }
    __builtin_amdgcn_s_barrier();
    bc_i = (bc_i + 1 >= 3) ? 0 : (bc_i + 1);
  }

  // epilogue
  float* Cf = (float*)Cv;
  unsigned short* Ch = (unsigned short*)Cv;
  const float rg = (EPI == 2) ? gatep[0] : 0.f;
#pragma unroll
  for (int nf = 0; nf < 4; ++nf) {
    const int col = n0 + wn * 64 + nf * 16 + fr;
    if (col >= Nout) continue;
    const float bv = bias[col];
    int h = 0, ep = 0;
    if (EPI == 3) {
      h = col / 129;
      const int e = col - h * 129;
      ep = (e == 0) ? 128 : (e - 1);
    }
#pragma unroll
    for (int mf = 0; mf < 4; ++mf) {
      const int rowb = m0 + wm * 64 + mf * 16 + kg * 4;
#pragma unroll
      for (int r = 0; r < 4; ++r) {
        const int row = rowb + r;
        float v = acc[mf][nf][r] + bv;
        if (EPI == 3) {
          const size_t dst =
              (((size_t)((row >> 11) * NH + h) << 11) + (row & (LLEN - 1))) * XP2LD + ep;
          Ch[dst] = f2bf(v);
        } else {
          const size_t o = (size_t)row * ldc + col;
          if (EPI == 1) {
            Ch[o] = f2bf(v);
          } else {
            v = resid[o] + rg * v;
            Cf[o] = v;
          }
        }
      }
    }
  }
#undef STG6
#undef ARD6
#undef BRD6
}

// ---------------- depthwise causal conv(4) + silu, 4 timesteps x 8 ch/thread ---
__global__ __launch_bounds__(256) void k_dwconv(const unsigned short* __restrict__ xz,
                                                const float* __restrict__ cw,
                                                const float* __restrict__ cb,
                                                unsigned short* __restrict__ out) {
  const int idx = blockIdx.x * 256 + threadIdx.x;  // < (MROWS/4)*192
  const int c0 = (idx % 192) * 8;
  const int bl0 = (idx / 192) * 4;
  const int lpos0 = bl0 & (LLEN - 1);
  float w[8][4];
#pragma unroll
  for (int j = 0; j < 8; ++j) {
    const float4 wv = *(const float4*)(cw + (c0 + j) * 4);
    w[j][0] = wv.x; w[j][1] = wv.y; w[j][2] = wv.z; w[j][3] = wv.w;
  }
  float xr[7][8];
#pragma unroll
  for (int m = 0; m < 7; ++m) {
    uint4 xv = make_uint4(0u, 0u, 0u, 0u);
    if (lpos0 - 3 + m >= 0)
      xv = *(const uint4*)(xz + (size_t)(bl0 - 3 + m) * N2 + c0);
    const unsigned short* xs = (const unsigned short*)&xv;
#pragma unroll
    for (int j = 0; j < 8; ++j) xr[m][j] = bf2f(xs[j]);
  }
  const float4 cb0 = *(const float4*)(cb + c0);
  const float4 cb1 = *(const float4*)(cb + c0 + 4);
  const float cbv[8] = {cb0.x, cb0.y, cb0.z, cb0.w, cb1.x, cb1.y, cb1.z, cb1.w};
#pragma unroll
  for (int t4 = 0; t4 < 4; ++t4) {
    union { unsigned short u[8]; uint4 v; } pk;
#pragma unroll
    for (int j = 0; j < 8; ++j) {
      float a = cbv[j];
#pragma unroll
      for (int k = 0; k < 4; ++k) a = fmaf(w[j][k], xr[t4 + k][j], a);
      a = a / (1.f + __expf(-a));
      pk.u[j] = f2bf(a);
    }
    *(uint4*)(out + (size_t)(bl0 + t4) * DI + c0) = pk.v;
  }
}

// ---------------- prep2: alpha only (sumB2 == 1 identity after normalization) --
__global__ __launch_bounds__(256) void k_prep2(const unsigned short* __restrict__ xp2,
                                               const unsigned short* __restrict__ xc,
                                               const float* __restrict__ A_log,
                                               const float* __restrict__ l2ab,
                                               const float* __restrict__ l2b,
                                               const float* __restrict__ se,
                                               float* __restrict__ al) {
  const int blk = blockIdx.x;               // MROWS*6
  const int w = threadIdx.x >> 6, lane = threadIdx.x & 63;
  const int bl = blk / 6, hq = blk % 6;
  const int h = hq * 4 + w;
  const float xv = bf2f(xc[(size_t)bl * DI + h * DH + lane]);
  float sx = xv;
#pragma unroll
  for (int o = 32; o; o >>= 1) sx += __shfl_xor(sx, o);
  if (lane == 0) {
    const int b = bl >> 11, l = bl & (LLEN - 1);
    const size_t r2 = ((size_t)(b * NH + h) << 11) + l;
    const float xmean = sx * (1.f / 64.f);
    const float dt = bf2f(xp2[r2 * XP2LD + 128]);
    const float sp = (dt > 20.f) ? dt : log1pf(expf(dt));
    const float Ac = fminf(fmaxf(A_log[h], -2.3f), -0.01f);
    const float aa = expf(Ac * sp);
    const float one_a = 1.f - aa;
    const float pe = one_a * one_a * xmean * xmean * (1.f / 64.f);  // sumB2 == 1
    const float ns = pe / (se[h] + 1e-6f);
    const float beta = exp2f(fminf(fmaxf(l2b[h], -2.f), 2.f));
    const float boost = fmaxf(tanhf(beta * ns), 0.f);
    const float ab = 1.f - exp2f(fminf(fmaxf(l2ab[h], -3.32f), -0.015f));
    al[r2] = fminf(fmaxf(ab + (1.f - ab) * boost, 0.01f), 0.999f);
  }
}

// ---------------- chunked scan, stage 1: intra-chunk Y + local state -----------
// Reads raw B/C from xp2; normalizes inline (8-lane shuffle reduce); rcpB folded
// into BsT/mask scales, rcpC folded into the P mask scale (post-MFMA).
__global__ __launch_bounds__(256) void k_chunk1(
    const unsigned short* __restrict__ xp2, const unsigned short* __restrict__ xcg,
    const float* __restrict__ al, unsigned short* __restrict__ xz,
    unsigned short* __restrict__ Hbuf, float* __restrict__ Dc) {
  const int blk = blockIdx.x;          // bh*16 + c
  const int bh = blk >> 4, c = blk & 15;
  const int b = bh / NH, h = bh % NH;
  const int tid = threadIdx.x, w = tid >> 6, lane = tid & 63;
  const int fr = lane & 15, kg = lane >> 4;
  const int rbase = b * LLEN + c * QC;                 // xcg/xz row base
  const size_t rbase2 = ((size_t)bh << 11) + c * QC;   // xp2 row base

  __shared__ float lc[QC], ia[QC], escl[QC], rbA[QC], rcC[QC];
  __shared__ float wtot[2];
  __shared__ alignas(16) unsigned short XT[64][152];   // [d][u]
  __shared__ alignas(16) unsigned short BsT[64][152];  // [s][u] (scaled)
  __shared__ alignas(16) unsigned short Pt[128][88];   // [t][u-local]

  float a = 1.f, la = 0.f;
  if (tid < QC) { a = al[(size_t)bh * LLEN + c * QC + tid]; la = __logf(a); }
  float s = la;
#pragma unroll
  for (int o = 1; o < 64; o <<= 1) { float t2 = __shfl_up(s, o); if (lane >= o) s += t2; }
  if (tid < QC && lane == 63) wtot[w] = s;
  __syncthreads();
  if (tid < QC) { lc[tid] = s + ((w == 1) ? wtot[0] : 0.f); ia[tid] = 1.f - a; }
  __syncthreads();
  const float lcE = lc[QC - 1];
  if (tid < QC) escl[tid] = __expf(lcE - lc[tid]);
  if (tid == 0) Dc[blk] = __expf(lcE);
  __syncthreads();

  // staging: XT (transposed X), BsT (B * escl * ia * rcpB), norms for B and C
  {
    const int r8 = tid >> 3, q8 = tid & 7;
#pragma unroll
    for (int it = 0; it < 4; ++it) {
      const int u = it * 32 + r8;
      const uint4 xv = *(const uint4*)(xcg + (size_t)(rbase + u) * DI + h * DH + q8 * 8);
      const unsigned short* xs = (const unsigned short*)&xv;
#pragma unroll
      for (int j = 0; j < 8; ++j) XT[q8 * 8 + j][u] = xs[j];
      const size_t prow = (rbase2 + u) * XP2LD;
      const uint4 bv = *(const uint4*)(xp2 + prow + q8 * 8);
      const uint4 cv = *(const uint4*)(xp2 + prow + 64 + q8 * 8);
      const unsigned short* bsv = (const unsigned short*)&bv;
      const unsigned short* csv = (const unsigned short*)&cv;
      float bb[8], sb = 0.f, sc2 = 0.f;
#pragma unroll
      for (int j = 0; j < 8; ++j) {
        bb[j] = bf2f(bsv[j]);
        sb = fmaf(bb[j], bb[j], sb);
        const float cc = bf2f(csv[j]);
        sc2 = fmaf(cc, cc, sc2);
      }
      sb += __shfl_xor(sb, 1); sb += __shfl_xor(sb, 2); sb += __shfl_xor(sb, 4);
      sc2 += __shfl_xor(sc2, 1); sc2 += __shfl_xor(sc2, 2); sc2 += __shfl_xor(sc2, 4);
      const float rcpB = 1.f / fmaxf(sqrtf(sb), 1e-12f);
      const float e = escl[u] * ia[u] * rcpB;
#pragma unroll
      for (int j = 0; j < 8; ++j) BsT[q8 * 8 + j][u] = f2bf(bb[j] * e);
      if (q8 == 0) {
        rbA[u] = ia[u] * rcpB;
        rcC[u] = 1.f / fmaxf(sqrtf(sc2), 1e-12f);
      }
    }
  }
  __syncthreads();

  // raw C fragments (scale rcpC applied post-MFMA in the mask step)
  bf16x8 cf[2][2];
#pragma unroll
  for (int fi = 0; fi < 2; ++fi)
#pragma unroll
    for (int kk = 0; kk < 2; ++kk) {
      const int t = w * 32 + fi * 16 + fr;
      const uint4 v = *(const uint4*)(xp2 + (rbase2 + t) * XP2LD + 64 + kk * 32 + kg * 8);
      cf[fi][kk] = *(const bf16x8*)&v;
    }

  float lct[2][4], rct[2][4];
#pragma unroll
  for (int fi = 0; fi < 2; ++fi)
#pragma unroll
    for (int r = 0; r < 4; ++r) {
      const int t = w * 32 + fi * 16 + kg * 4 + r;
      lct[fi][r] = lc[t];
      rct[fi][r] = rcC[t];
    }

  f32x4 yacc[2][4] = {};
  f32x4 hacc[4] = {};
#pragma unroll
  for (int ut = 0; ut < 2; ++ut) {
    f32x4 g[2][4] = {};
#pragma unroll
    for (int kk = 0; kk < 2; ++kk)
#pragma unroll
      for (int fj = 0; fj < 4; ++fj) {
        const int u = ut * 64 + fj * 16 + fr;
        const uint4 v = *(const uint4*)(xp2 + (rbase2 + u) * XP2LD + kk * 32 + kg * 8);
        const bf16x8 bfrag = *(const bf16x8*)&v;
#pragma unroll
        for (int fi = 0; fi < 2; ++fi)
          g[fi][fj] = __builtin_amdgcn_mfma_f32_16x16x32_bf16(cf[fi][kk], bfrag, g[fi][fj], 0, 0, 0);
      }
#pragma unroll
    for (int fi = 0; fi < 2; ++fi)
#pragma unroll
      for (int fj = 0; fj < 4; ++fj) {
        const int u = ut * 64 + fj * 16 + fr;
        const float lcu = lc[u], sbu = rbA[u];
#pragma unroll
        for (int r = 0; r < 4; ++r) {
          const int t = w * 32 + fi * 16 + kg * 4 + r;
          const float v = (t >= u) ? g[fi][fj][r] * __expf(lct[fi][r] - lcu) * sbu * rct[fi][r] : 0.f;
          Pt[t][fj * 16 + fr] = f2bf(v);
        }
      }
#pragma unroll
    for (int kk = 0; kk < 2; ++kk) {
      bf16x8 xf[4];
#pragma unroll
      for (int fj = 0; fj < 4; ++fj)
        xf[fj] = *(const bf16x8*)&XT[fj * 16 + fr][ut * 64 + kk * 32 + kg * 8];
      bf16x8 pf[2];
#pragma unroll
      for (int fi = 0; fi < 2; ++fi)
        pf[fi] = *(const bf16x8*)&Pt[w * 32 + fi * 16 + fr][kk * 32 + kg * 8];
#pragma unroll
      for (int fi = 0; fi < 2; ++fi)
#pragma unroll
        for (int fj = 0; fj < 4; ++fj)
          yacc[fi][fj] = __builtin_amdgcn_mfma_f32_16x16x32_bf16(pf[fi], xf[fj], yacc[fi][fj], 0, 0, 0);
      const bf16x8 xh = *(const bf16x8*)&XT[w * 16 + fr][ut * 64 + kk * 32 + kg * 8];
#pragma unroll
      for (int fi = 0; fi < 4; ++fi) {
        const bf16x8 bs = *(const bf16x8*)&BsT[fi * 16 + fr][ut * 64 + kk * 32 + kg * 8];
        hacc[fi] = __builtin_amdgcn_mfma_f32_16x16x32_bf16(bs, xh, hacc[fi], 0, 0, 0);
      }
    }
  }
#pragma unroll
  for (int fi = 0; fi < 2; ++fi)
#pragma unroll
    for (int fj = 0; fj < 4; ++fj)
#pragma unroll
      for (int r = 0; r < 4; ++r) {
        const int t = w * 32 + fi * 16 + kg * 4 + r;
        const int d = fj * 16 + fr;
        xz[(size_t)(rbase + t) * N2 + h * DH + d] = f2bf(yacc[fi][fj][r]);
      }
  const int dcol = w * 16 + fr;
#pragma unroll
  for (int fi = 0; fi < 4; ++fi) {
    ushort4 pk;
    pk.x = f2bf(hacc[fi][0]); pk.y = f2bf(hacc[fi][1]);
    pk.z = f2bf(hacc[fi][2]); pk.w = f2bf(hacc[fi][3]);
    *(ushort4*)(Hbuf + ((size_t)blk * 64 + dcol) * 64 + fi * 16 + kg * 4) = pk;
  }
}

// ---------------- chunked scan, stage 2: carry across chunks (in place) --------
__global__ __launch_bounds__(256) void k_carry(unsigned short* __restrict__ Hbuf,
                                               const float* __restrict__ Dc) {
  const int bh = blockIdx.x, tid = threadIdx.x;
  float carry[16];
#pragma unroll
  for (int j = 0; j < 16; ++j) carry[j] = 0.f;
  for (int c = 0; c < NCHUNK; ++c) {
    unsigned short* p = Hbuf + (((size_t)(bh * NCHUNK + c)) << 12) + tid * 16;
    const uint4 v0 = *(const uint4*)(p);
    const uint4 v1 = *(const uint4*)(p + 8);
    const unsigned short* hs0 = (const unsigned short*)&v0;
    const unsigned short* hs1 = (const unsigned short*)&v1;
    float hl[16];
#pragma unroll
    for (int j = 0; j < 8; ++j) { hl[j] = bf2f(hs0[j]); hl[8 + j] = bf2f(hs1[j]); }
    uint4 o0, o1;
    unsigned short* os0 = (unsigned short*)&o0;
    unsigned short* os1 = (unsigned short*)&o1;
#pragma unroll
    for (int j = 0; j < 8; ++j) { os0[j] = f2bf(carry[j]); os1[j] = f2bf(carry[8 + j]); }
    *(uint4*)(p) = o0;
    *(uint4*)(p + 8) = o1;
    const float dc = Dc[bh * NCHUNK + c];
#pragma unroll
    for (int j = 0; j < 16; ++j) carry[j] = fmaf(dc, carry[j], hl[j]);
  }
}

// ---------------- chunked scan, stage 3: inter-chunk Y + fused gating ----------
// Raw-C MFMA; rcpC * exp(lc) folded into the per-row output scale.
__global__ __launch_bounds__(256) void k_chunk2(
    const unsigned short* __restrict__ xp2, const float* __restrict__ al,
    const unsigned short* __restrict__ Hbuf, const unsigned short* __restrict__ xz,
    unsigned short* __restrict__ xcg) {
  const int blk = blockIdx.x;
  const int bh = blk >> 4, c = blk & 15;
  const int b = bh / NH, h = bh % NH;
  const int tid = threadIdx.x, w = tid >> 6, lane = tid & 63;
  const int fr = lane & 15, kg = lane >> 4;
  const int rbase = b * LLEN + c * QC;
  const size_t rbase2 = ((size_t)bh << 11) + c * QC;
  __shared__ float lc[QC], rc2[QC];
  __shared__ float wtot[2];
  float a = 1.f, la = 0.f;
  if (tid < QC) { a = al[(size_t)bh * LLEN + c * QC + tid]; la = __logf(a); }
  float s = la;
#pragma unroll
  for (int o = 1; o < 64; o <<= 1) { float t2 = __shfl_up(s, o); if (lane >= o) s += t2; }
  if (tid < QC && lane == 63) wtot[w] = s;
  __syncthreads();
  if (tid < QC) lc[tid] = s + ((w == 1) ? wtot[0] : 0.f);
  __syncthreads();
  // raw C fragments; rcpC per row via kg-group shuffle reduce
  bf16x8 cf[2][2];
#pragma unroll
  for (int fi = 0; fi < 2; ++fi) {
    const int t = w * 32 + fi * 16 + fr;
    float ss = 0.f;
#pragma unroll
    for (int kk = 0; kk < 2; ++kk) {
      const uint4 v = *(const uint4*)(xp2 + (rbase2 + t) * XP2LD + 64 + kk * 32 + kg * 8);
      cf[fi][kk] = *(const bf16x8*)&v;
      const unsigned short* cs = (const unsigned short*)&v;
#pragma unroll
      for (int q = 0; q < 8; ++q) { const float cc = bf2f(cs[q]); ss = fmaf(cc, cc, ss); }
    }
    ss += __shfl_xor(ss, 16);
    ss += __shfl_xor(ss, 32);
    if (kg == 0) rc2[t] = 1.f / fmaxf(sqrtf(ss), 1e-12f);
  }
  bf16x8 hf[4][2];
#pragma unroll
  for (int fj = 0; fj < 4; ++fj)
#pragma unroll
    for (int kk = 0; kk < 2; ++kk) {
      const uint4 v = *(const uint4*)(Hbuf + ((size_t)blk * 64 + fj * 16 + fr) * 64 + kk * 32 + kg * 8);
      hf[fj][kk] = *(const bf16x8*)&v;
    }
  __syncthreads();
  f32x4 y[2][4] = {};
#pragma unroll
  for (int kk = 0; kk < 2; ++kk)
#pragma unroll
    for (int fi = 0; fi < 2; ++fi)
#pragma unroll
      for (int fj = 0; fj < 4; ++fj)
        y[fi][fj] = __builtin_amdgcn_mfma_f32_16x16x32_bf16(cf[fi][kk], hf[fj][kk], y[fi][fj], 0, 0, 0);
#pragma unroll
  for (int fi = 0; fi < 2; ++fi)
#pragma unroll
    for (int fj = 0; fj < 4; ++fj)
#pragma unroll
      for (int r = 0; r < 4; ++r) {
        const int t = w * 32 + fi * 16 + kg * 4 + r;
        const int d = fj * 16 + fr;
        const float scl = rc2[t] * __expf(lc[t]);
        const size_t rowg = (size_t)(rbase + t);
        const float yv = y[fi][fj][r] * scl + bf2f(xz[rowg * N2 + h * DH + d]);
        const float zv = bf2f(xz[rowg * N2 + DI + h * DH + d]);
        const float g = yv * (zv / (1.f + __expf(-zv)));
        xcg[rowg * DI + h * DH + d] = f2bf(g);
      }
}

extern "C" void kernel_launch(void* const* d_in, const int* in_sizes, int n_in,
                              void* d_out, int out_size, void* d_ws, size_t ws_size,
                              hipStream_t stream) {
  const float* hs     = (const float*)d_in[0];
  const float* norm_w = (const float*)d_in[1];
  const float* in_w   = (const float*)d_in[2];
  const float* in_b   = (const float*)d_in[3];
  const float* cw     = (const float*)d_in[4];
  const float* cb     = (const float*)d_in[5];
  const float* xw     = (const float*)d_in[6];
  const float* xb     = (const float*)d_in[7];
  const float* A_log  = (const float*)d_in[8];
  const float* l2ab   = (const float*)d_in[9];
  const float* l2b    = (const float*)d_in[10];
  const float* se     = (const float*)d_in[11];
  const float* ow     = (const float*)d_in[12];
  const float* ob     = (const float*)d_in[13];
  const float* rg     = (const float*)d_in[14];
  float* out = (float*)d_out;

  char* ws = (char*)d_ws;
  // layout (~166 MB):
  //   0          xnorm / xcg bf16 (33.5 MB)
  //   33554432   wA bf16 (12.58 MB) -> Hbuf after in_proj
  //   46137344   wX bf16 (9.83 MB)  -> al (0.79 MB) + Dc (6 KB) after x_proj
  //   55967744   wO bf16 (6.29 MB)
  //   62259200   xz bf16 8192x3072 (50.3 MB; x-half reused for Y_intra)
  //   112590848  xp2 bf16 head-blocked 96x2048x136 (53.5 MB)
  unsigned short* xnorm = (unsigned short*)(ws);
  unsigned short* wA    = (unsigned short*)(ws + 33554432ull);
  unsigned short* wX    = (unsigned short*)(ws + 46137344ull);
  unsigned short* wO    = (unsigned short*)(ws + 55967744ull);
  unsigned short* xz    = (unsigned short*)(ws + 62259200ull);
  unsigned short* xp2   = (unsigned short*)(ws + 112590848ull);
  unsigned short* xcg   = xnorm;
  unsigned short* Hbuf  = wA;
  float* al             = (float*)(ws + 46137344ull);
  float* Dc             = (float*)(ws + 46137344ull + 786432ull);

  // fused weight conversion: (6291456 + 4915200 + 3145728) / 256 = 56064 blocks
  k_w2bf3<<<56064, 256, 0, stream>>>(in_w, wA, N2 * DMODEL,
                                     xw, wX, NP * DI, NP_PAD * DI,
                                     ow, wO, DMODEL * DI);

  k_rmsnorm<<<MROWS, 256, 0, stream>>>(hs, norm_w, xnorm);
  // in_proj: 64 x 12 = 768 blocks, bf16 out
  k_gemm6<1><<<768, 512, 0, stream>>>(xnorm, wA, in_b, xz, nullptr, nullptr,
                                      DMODEL, 12, N2, N2);
  k_dwconv<<<(MROWS / 4) * 192 / 256, 256, 0, stream>>>(xz, cw, cb, xcg);
  // x_proj: 64 x 13 = 832 blocks, head-blocked xp2 out
  k_gemm6<3><<<832, 512, 0, stream>>>(xcg, wX, xb, xp2, nullptr, nullptr,
                                      DI, 13, NP, 0);
  k_prep2<<<MROWS * 6, 256, 0, stream>>>(xp2, xcg, A_log, l2ab, l2b, se, al);

  k_chunk1<<<BB * NH * NCHUNK, 256, 0, stream>>>(xp2, xcg, al, xz, Hbuf, Dc);
  k_carry<<<BB * NH, 256, 0, stream>>>(Hbuf, Dc);
  k_chunk2<<<BB * NH * NCHUNK, 256, 0, stream>>>(xp2, al, Hbuf, xz, xcg);

  // out_proj: 64 x 8 = 512 blocks, fp32 + residual
  k_gemm6<2><<<512, 512, 0, stream>>>(xcg, wO, ob, out, hs, rg,
                                      DI, 8, DMODEL, DMODEL);
}

// Round 12
// 485.690 us; speedup vs baseline: 1.0942x; 1.0453x over previous
//
#include <hip/hip_runtime.h>
#include <stdint.h>

// Problem constants
#define BB 4
#define LLEN 2048
#define DMODEL 2048
#define NH 24
#define DH 64
#define SS 64
#define DI 1536          // NH*DH
#define N2 3072          // 2*DI
#define NP 3096          // NH*(1+2*S)
#define NP_PAD 3200      // weight rows padded (zero rows 3096..3199)
#define MROWS 8192       // BB*LLEN
#define NCHUNK 16
#define QC 128           // chunk length
#define XP2LD 128        // xp2 row stride (B 0..63, C 64..127) -> 256B rows
#define WBLK 56064       // weight-convert blocks in k_pre

using bf16x8 = __bf16 __attribute__((ext_vector_type(8)));
using f32x4  = float __attribute__((ext_vector_type(4)));

__device__ __forceinline__ unsigned short f2bf(float f) {
  union { float f; unsigned int u; } v; v.f = f;
  unsigned int u = v.u + 0x7fffu + ((v.u >> 16) & 1u);
  return (unsigned short)(u >> 16);
}
__device__ __forceinline__ float bf2f(unsigned short h) {
  union { unsigned int u; float f; } v; v.u = ((unsigned int)h) << 16;
  return v.f;
}

__device__ __forceinline__ void gload16(const void* g, void* l) {
  __builtin_amdgcn_global_load_lds(
    reinterpret_cast<const __attribute__((address_space(1))) void*>(reinterpret_cast<uintptr_t>(g)),
    reinterpret_cast<__attribute__((address_space(3))) void*>((uint32_t)(reinterpret_cast<uintptr_t>(l))),
    16, 0, 0);
}

// ---------------- fused front kernel: weight conversion + RMSNorm + hc table ---
// blocks [0, WBLK): fp32->bf16 weight convert (wA, wX padded, wO)
// blocks [WBLK, WBLK+MROWS): RMSNorm rows
// block WBLK+MROWS: per-head constants hc[0..23]=Ac, [24..47]=beta,
//                   [48..71]=alpha_base, [72..95]=1/(se+1e-6)
__global__ __launch_bounds__(256) void k_pre(
    const float* __restrict__ in_w, unsigned short* __restrict__ wA,
    const float* __restrict__ xw, unsigned short* __restrict__ wX,
    const float* __restrict__ ow, unsigned short* __restrict__ wO,
    const float* __restrict__ hs, const float* __restrict__ norm_w,
    unsigned short* __restrict__ xnorm,
    const float* __restrict__ A_log, const float* __restrict__ l2ab,
    const float* __restrict__ l2b, const float* __restrict__ se,
    float* __restrict__ hc) {
  const int blk = blockIdx.x;
  const int t = threadIdx.x;
  if (blk < WBLK) {
    int i = blk * 256 + t;
    if (i < N2 * DMODEL) { wA[i] = f2bf(in_w[i]); return; }
    i -= N2 * DMODEL;
    if (i < NP_PAD * DI) { wX[i] = (i < NP * DI) ? f2bf(xw[i]) : (unsigned short)0; return; }
    i -= NP_PAD * DI;
    wO[i] = f2bf(ow[i]);
    return;
  }
  if (blk == WBLK + MROWS) {
    if (t < NH) {
      hc[t]          = fminf(fmaxf(A_log[t], -2.3f), -0.01f);
      hc[NH + t]     = exp2f(fminf(fmaxf(l2b[t], -2.f), 2.f));
      hc[2 * NH + t] = 1.f - exp2f(fminf(fmaxf(l2ab[t], -3.32f), -0.015f));
      hc[3 * NH + t] = 1.f / (se[t] + 1e-6f);
    }
    return;
  }
  const int row = blk - WBLK;
  const float* x = hs + (size_t)row * DMODEL;
  float4 v0 = reinterpret_cast<const float4*>(x)[t * 2 + 0];
  float4 v1 = reinterpret_cast<const float4*>(x)[t * 2 + 1];
  float ss = v0.x * v0.x + v0.y * v0.y + v0.z * v0.z + v0.w * v0.w +
             v1.x * v1.x + v1.y * v1.y + v1.z * v1.z + v1.w * v1.w;
#pragma unroll
  for (int o = 32; o; o >>= 1) ss += __shfl_xor(ss, o);
  __shared__ float red[4];
  if ((t & 63) == 0) red[t >> 6] = ss;
  __syncthreads();
  ss = red[0] + red[1] + red[2] + red[3];
  const float r = rsqrtf(ss * (1.0f / DMODEL) + 1.1920928955078125e-07f);
  float4 w0 = reinterpret_cast<const float4*>(norm_w)[t * 2 + 0];
  float4 w1 = reinterpret_cast<const float4*>(norm_w)[t * 2 + 1];
  union { unsigned short u[8]; uint4 v; } pk;
  pk.u[0] = f2bf(v0.x * r * w0.x); pk.u[1] = f2bf(v0.y * r * w0.y);
  pk.u[2] = f2bf(v0.z * r * w0.z); pk.u[3] = f2bf(v0.w * r * w0.w);
  pk.u[4] = f2bf(v1.x * r * w1.x); pk.u[5] = f2bf(v1.y * r * w1.y);
  pk.u[6] = f2bf(v1.z * r * w1.z); pk.u[7] = f2bf(v1.w * r * w1.w);
  *reinterpret_cast<uint4*>(xnorm + (size_t)row * DMODEL + t * 8) = pk.v;
}

// ---------------- drift + distance-2 bf16 NT GEMM (128x256 tile, BK=64) --------
// EPI 1: bf16 C = acc+bias. EPI 2: fp32 C = resid + rg*(acc+bias).
// EPI 3: head-blocked xp2 write (B/C cols) + inline alpha for dt cols (e==0):
//        alpha from fp32 dt + xmean + hc table -> al (prep kernel eliminated).
template <int EPI>
__global__ __launch_bounds__(512, 2)
void k_gemm6(const unsigned short* __restrict__ A, const unsigned short* __restrict__ B,
             const float* __restrict__ bias, void* __restrict__ Cv,
             const float* __restrict__ resid, const float* __restrict__ gatep,
             const float* __restrict__ xmean, float* __restrict__ al,
             const float* __restrict__ hc,
             int K, int NT_N, int Nout, int ldc) {
  constexpr int AELEM = 128 * 64;
  constexpr int BUFE = AELEM + 16384;
  __shared__ alignas(16) unsigned short sm[3 * BUFE];
  const int tid = threadIdx.x;
  const int lane = tid & 63, wid = tid >> 6;
  const int wm = wid >> 2, wn = wid & 3;
  const int fr = lane & 15, kg = lane >> 4;
  const int nwg = gridDim.x;
  const int wg = ((int)blockIdx.x & 7) * (nwg >> 3) + ((int)blockIdx.x >> 3);
  const int m0 = (wg / NT_N) * 128, n0 = (wg % NT_N) * 256;
  const int NT = K >> 6;

  const unsigned short* asrc[2];
  const unsigned short* bsrc[4];
#pragma unroll
  for (int li = 0; li < 2; ++li) {
    const int gi = li * 512 + tid, r = gi >> 3, q = gi & 7;
    asrc[li] = A + (size_t)(m0 + r) * K + ((q ^ (r & 7)) << 3);
  }
#pragma unroll
  for (int li = 0; li < 4; ++li) {
    const int gi = li * 512 + tid, r = gi >> 3, q = gi & 7;
    bsrc[li] = B + (size_t)(n0 + r) * K + ((q ^ (r & 7)) << 3);
  }
  const int wlds = wid * 64;

#define STG6(buf, ko)                                                          \
  { unsigned short* da_ = sm + (buf) * BUFE;                                   \
    gload16(asrc[0] + (ko), da_ + ((0 * 512 + wlds) << 3));                    \
    gload16(asrc[1] + (ko), da_ + ((1 * 512 + wlds) << 3));                    \
    unsigned short* db_ = sm + (buf) * BUFE + AELEM;                           \
    _Pragma("unroll") for (int li = 0; li < 4; ++li)                           \
      gload16(bsrc[li] + (ko), db_ + ((li * 512 + wlds) << 3)); }

#define ARD6(bufp, f, kk)                                                      \
  (*(const bf16x8*)((bufp) + (wm * 64 + (f) * 16 + fr) * 64 +                  \
      ((((kk) * 4 + kg) ^ (fr & 7)) << 3)))
#define BRD6(bufp, nf, kk)                                                     \
  (*(const bf16x8*)((bufp) + AELEM + (wn * 64 + (nf) * 16 + fr) * 64 +         \
      ((((kk) * 4 + kg) ^ (fr & 7)) << 3)))

  f32x4 acc[4][4] = {};

  STG6(0, 0)
  STG6(1, 64)
  asm volatile("s_waitcnt vmcnt(6)" ::: "memory");
  __builtin_amdgcn_s_barrier();

  int bc_i = 0;
  for (int t = 0; t < NT; ++t) {
    unsigned short* bc = sm + bc_i * BUFE;
    const int bn_i = (bc_i + 2 >= 3) ? (bc_i - 1) : (bc_i + 2);
    const bool st = (t + 2) < NT;
    if (st) STG6(bn_i, (t + 2) << 6)

    bf16x8 bfv[4][2], af[4][2];
#pragma unroll
    for (int nf = 0; nf < 4; ++nf) {
      bfv[nf][0] = BRD6(bc, nf, 0);
      bfv[nf][1] = BRD6(bc, nf, 1);
    }
#pragma unroll
    for (int mf = 0; mf < 4; ++mf) {
      af[mf][0] = ARD6(bc, mf, 0);
      af[mf][1] = ARD6(bc, mf, 1);
    }
    __builtin_amdgcn_sched_barrier(0);
    asm volatile("s_waitcnt lgkmcnt(0)" ::: "memory");
    __builtin_amdgcn_sched_barrier(0);
    __builtin_amdgcn_s_setprio(1);
#pragma unroll
    for (int mf = 0; mf < 4; ++mf)
#pragma unroll
      for (int nf = 0; nf < 4; ++nf)
#pragma unroll
        for (int kk = 0; kk < 2; ++kk)
          acc[mf][nf] = __builtin_amdgcn_mfma_f32_16x16x32_bf16(
              af[mf][kk], bfv[nf][kk], acc[mf][nf], 0, 0, 0);
    __builtin_amdgcn_s_setprio(0);

    if (st) { asm volatile("s_waitcnt vmcnt(6)" ::: "memory"); }
    else    { asm volatile("s_waitcnt vmcnt(0)" ::: "memory"); }
    __builtin_amdgcn_s_barrier();
    bc_i = (bc_i + 1 >= 3) ? 0 : (bc_i + 1);
  }

  // epilogue
  float* Cf = (float*)Cv;
  unsigned short* Ch = (unsigned short*)Cv;
  const float rg = (EPI == 2) ? gatep[0] : 0.f;
#pragma unroll
  for (int nf = 0; nf < 4; ++nf) {
    const int col = n0 + wn * 64 + nf * 16 + fr;
    if (col >= Nout) continue;
    const float bv = bias[col];
    if (EPI == 3) {
      const int h = col / 129;
      const int e = col - h * 129;
      if (e == 0) {
        // dt column: compute alpha inline, write al
        const float Ac = hc[h], bet = hc[NH + h], ab = hc[2 * NH + h], rse = hc[3 * NH + h];
#pragma unroll
        for (int mf = 0; mf < 4; ++mf) {
          const int rowb = m0 + wm * 64 + mf * 16 + kg * 4;
#pragma unroll
          for (int r = 0; r < 4; ++r) {
            const int row = rowb + r;
            const float dt = acc[mf][nf][r] + bv;
            const float sp = (dt > 20.f) ? dt : log1pf(expf(dt));
            const float one_a = 1.f - expf(Ac * sp);
            const size_t r2 = (((size_t)((row >> 11) * NH + h)) << 11) + (row & (LLEN - 1));
            const float xm = xmean[r2];
            const float pe = one_a * one_a * xm * xm * (1.f / 64.f);
            const float boost = fmaxf(tanhf(bet * pe * rse), 0.f);
            al[r2] = fminf(fmaxf(ab + (1.f - ab) * boost, 0.01f), 0.999f);
          }
        }
      } else {
        const int ep = e - 1;
#pragma unroll
        for (int mf = 0; mf < 4; ++mf) {
          const int rowb = m0 + wm * 64 + mf * 16 + kg * 4;
#pragma unroll
          for (int r = 0; r < 4; ++r) {
            const int row = rowb + r;
            const size_t dst =
                (((size_t)((row >> 11) * NH + h) << 11) + (row & (LLEN - 1))) * XP2LD + ep;
            Ch[dst] = f2bf(acc[mf][nf][r] + bv);
          }
        }
      }
    } else {
#pragma unroll
      for (int mf = 0; mf < 4; ++mf) {
        const int rowb = m0 + wm * 64 + mf * 16 + kg * 4;
#pragma unroll
        for (int r = 0; r < 4; ++r) {
          const size_t o = (size_t)(rowb + r) * ldc + col;
          float v = acc[mf][nf][r] + bv;
          if (EPI == 1) {
            Ch[o] = f2bf(v);
          } else {
            v = resid[o] + rg * v;
            Cf[o] = v;
          }
        }
      }
    }
  }
#undef STG6
#undef ARD6
#undef BRD6
}

// ---------------- depthwise causal conv(4) + silu + per-head x-mean ------------
// 4 timesteps x 8 ch/thread; the 8 lane-contiguous threads of one head reduce
// the silu'd values -> xmean[b,l,h] (feeds alpha in x_proj's epilogue).
__global__ __launch_bounds__(256) void k_dwconv(const unsigned short* __restrict__ xz,
                                                const float* __restrict__ cw,
                                                const float* __restrict__ cb,
                                                unsigned short* __restrict__ out,
                                                float* __restrict__ xmean) {
  const int idx = blockIdx.x * 256 + threadIdx.x;  // < (MROWS/4)*192
  const int c0 = (idx % 192) * 8;
  const int bl0 = (idx / 192) * 4;
  const int lpos0 = bl0 & (LLEN - 1);
  float w[8][4];
#pragma unroll
  for (int j = 0; j < 8; ++j) {
    const float4 wv = *(const float4*)(cw + (c0 + j) * 4);
    w[j][0] = wv.x; w[j][1] = wv.y; w[j][2] = wv.z; w[j][3] = wv.w;
  }
  float xr[7][8];
#pragma unroll
  for (int m = 0; m < 7; ++m) {
    uint4 xv = make_uint4(0u, 0u, 0u, 0u);
    if (lpos0 - 3 + m >= 0)
      xv = *(const uint4*)(xz + (size_t)(bl0 - 3 + m) * N2 + c0);
    const unsigned short* xs = (const unsigned short*)&xv;
#pragma unroll
    for (int j = 0; j < 8; ++j) xr[m][j] = bf2f(xs[j]);
  }
  const float4 cb0 = *(const float4*)(cb + c0);
  const float4 cb1 = *(const float4*)(cb + c0 + 4);
  const float cbv[8] = {cb0.x, cb0.y, cb0.z, cb0.w, cb1.x, cb1.y, cb1.z, cb1.w};
  float hsum[4] = {0.f, 0.f, 0.f, 0.f};
#pragma unroll
  for (int t4 = 0; t4 < 4; ++t4) {
    union { unsigned short u[8]; uint4 v; } pk;
#pragma unroll
    for (int j = 0; j < 8; ++j) {
      float a = cbv[j];
#pragma unroll
      for (int k = 0; k < 4; ++k) a = fmaf(w[j][k], xr[t4 + k][j], a);
      a = a / (1.f + __expf(-a));
      hsum[t4] += a;
      pk.u[j] = f2bf(a);
    }
    *(uint4*)(out + (size_t)(bl0 + t4) * DI + c0) = pk.v;
  }
  // 8-lane reduce over the head's 64 channels
#pragma unroll
  for (int o = 1; o < 8; o <<= 1) {
#pragma unroll
    for (int t4 = 0; t4 < 4; ++t4) hsum[t4] += __shfl_xor(hsum[t4], o);
  }
  if ((threadIdx.x & 7) == 0) {
    const int h = (idx % 192) >> 3;
    const int b = bl0 >> 11;
    float4 xm = make_float4(hsum[0] * (1.f / 64.f), hsum[1] * (1.f / 64.f),
                            hsum[2] * (1.f / 64.f), hsum[3] * (1.f / 64.f));
    *(float4*)(xmean + (((size_t)(b * NH + h)) << 11) + lpos0) = xm;
  }
}

// ---------------- chunked scan, stage 1: intra-chunk Y + local state -----------
__global__ __launch_bounds__(256) void k_chunk1(
    const unsigned short* __restrict__ xp2, const unsigned short* __restrict__ xcg,
    const float* __restrict__ al, unsigned short* __restrict__ xz,
    unsigned short* __restrict__ Hbuf, float* __restrict__ Dc) {
  const int blk = blockIdx.x;          // bh*16 + c
  const int bh = blk >> 4, c = blk & 15;
  const int b = bh / NH, h = bh % NH;
  const int tid = threadIdx.x, w = tid >> 6, lane = tid & 63;
  const int fr = lane & 15, kg = lane >> 4;
  const int rbase = b * LLEN + c * QC;
  const size_t rbase2 = ((size_t)bh << 11) + c * QC;

  __shared__ float lc[QC], ia[QC], escl[QC], rbA[QC], rcC[QC];
  __shared__ float wtot[2];
  __shared__ alignas(16) unsigned short XT[64][152];
  __shared__ alignas(16) unsigned short BsT[64][152];
  __shared__ alignas(16) unsigned short Pt[128][88];

  float a = 1.f, la = 0.f;
  if (tid < QC) { a = al[(size_t)bh * LLEN + c * QC + tid]; la = __logf(a); }
  float s = la;
#pragma unroll
  for (int o = 1; o < 64; o <<= 1) { float t2 = __shfl_up(s, o); if (lane >= o) s += t2; }
  if (tid < QC && lane == 63) wtot[w] = s;
  __syncthreads();
  if (tid < QC) { lc[tid] = s + ((w == 1) ? wtot[0] : 0.f); ia[tid] = 1.f - a; }
  __syncthreads();
  const float lcE = lc[QC - 1];
  if (tid < QC) escl[tid] = __expf(lcE - lc[tid]);
  if (tid == 0) Dc[blk] = __expf(lcE);
  __syncthreads();

  {
    const int r8 = tid >> 3, q8 = tid & 7;
#pragma unroll
    for (int it = 0; it < 4; ++it) {
      const int u = it * 32 + r8;
      const uint4 xv = *(const uint4*)(xcg + (size_t)(rbase + u) * DI + h * DH + q8 * 8);
      const unsigned short* xs = (const unsigned short*)&xv;
#pragma unroll
      for (int j = 0; j < 8; ++j) XT[q8 * 8 + j][u] = xs[j];
      const size_t prow = (rbase2 + u) * XP2LD;
      const uint4 bv = *(const uint4*)(xp2 + prow + q8 * 8);
      const uint4 cv = *(const uint4*)(xp2 + prow + 64 + q8 * 8);
      const unsigned short* bsv = (const unsigned short*)&bv;
      const unsigned short* csv = (const unsigned short*)&cv;
      float bb[8], sb = 0.f, sc2 = 0.f;
#pragma unroll
      for (int j = 0; j < 8; ++j) {
        bb[j] = bf2f(bsv[j]);
        sb = fmaf(bb[j], bb[j], sb);
        const float cc = bf2f(csv[j]);
        sc2 = fmaf(cc, cc, sc2);
      }
      sb += __shfl_xor(sb, 1); sb += __shfl_xor(sb, 2); sb += __shfl_xor(sb, 4);
      sc2 += __shfl_xor(sc2, 1); sc2 += __shfl_xor(sc2, 2); sc2 += __shfl_xor(sc2, 4);
      const float rcpB = 1.f / fmaxf(sqrtf(sb), 1e-12f);
      const float e = escl[u] * ia[u] * rcpB;
#pragma unroll
      for (int j = 0; j < 8; ++j) BsT[q8 * 8 + j][u] = f2bf(bb[j] * e);
      if (q8 == 0) {
        rbA[u] = ia[u] * rcpB;
        rcC[u] = 1.f / fmaxf(sqrtf(sc2), 1e-12f);
      }
    }
  }
  __syncthreads();

  bf16x8 cf[2][2];
#pragma unroll
  for (int fi = 0; fi < 2; ++fi)
#pragma unroll
    for (int kk = 0; kk < 2; ++kk) {
      const int t = w * 32 + fi * 16 + fr;
      const uint4 v = *(const uint4*)(xp2 + (rbase2 + t) * XP2LD + 64 + kk * 32 + kg * 8);
      cf[fi][kk] = *(const bf16x8*)&v;
    }

  float lct[2][4], rct[2][4];
#pragma unroll
  for (int fi = 0; fi < 2; ++fi)
#pragma unroll
    for (int r = 0; r < 4; ++r) {
      const int t = w * 32 + fi * 16 + kg * 4 + r;
      lct[fi][r] = lc[t];
      rct[fi][r] = rcC[t];
    }

  f32x4 yacc[2][4] = {};
  f32x4 hacc[4] = {};
#pragma unroll
  for (int ut = 0; ut < 2; ++ut) {
    f32x4 g[2][4] = {};
#pragma unroll
    for (int kk = 0; kk < 2; ++kk)
#pragma unroll
      for (int fj = 0; fj < 4; ++fj) {
        const int u = ut * 64 + fj * 16 + fr;
        const uint4 v = *(const uint4*)(xp2 + (rbase2 + u) * XP2LD + kk * 32 + kg * 8);
        const bf16x8 bfrag = *(const bf16x8*)&v;
#pragma unroll
        for (int fi = 0; fi < 2; ++fi)
          g[fi][fj] = __builtin_amdgcn_mfma_f32_16x16x32_bf16(cf[fi][kk], bfrag, g[fi][fj], 0, 0, 0);
      }
#pragma unroll
    for (int fi = 0; fi < 2; ++fi)
#pragma unroll
      for (int fj = 0; fj < 4; ++fj) {
        const int u = ut * 64 + fj * 16 + fr;
        const float lcu = lc[u], sbu = rbA[u];
#pragma unroll
        for (int r = 0; r < 4; ++r) {
          const int t = w * 32 + fi * 16 + kg * 4 + r;
          const float v = (t >= u) ? g[fi][fj][r] * __expf(lct[fi][r] - lcu) * sbu * rct[fi][r] : 0.f;
          Pt[t][fj * 16 + fr] = f2bf(v);
        }
      }
#pragma unroll
    for (int kk = 0; kk < 2; ++kk) {
      bf16x8 xf[4];
#pragma unroll
      for (int fj = 0; fj < 4; ++fj)
        xf[fj] = *(const bf16x8*)&XT[fj * 16 + fr][ut * 64 + kk * 32 + kg * 8];
      bf16x8 pf[2];
#pragma unroll
      for (int fi = 0; fi < 2; ++fi)
        pf[fi] = *(const bf16x8*)&Pt[w * 32 + fi * 16 + fr][kk * 32 + kg * 8];
#pragma unroll
      for (int fi = 0; fi < 2; ++fi)
#pragma unroll
        for (int fj = 0; fj < 4; ++fj)
          yacc[fi][fj] = __builtin_amdgcn_mfma_f32_16x16x32_bf16(pf[fi], xf[fj], yacc[fi][fj], 0, 0, 0);
      const bf16x8 xh = *(const bf16x8*)&XT[w * 16 + fr][ut * 64 + kk * 32 + kg * 8];
#pragma unroll
      for (int fi = 0; fi < 4; ++fi) {
        const bf16x8 bs = *(const bf16x8*)&BsT[fi * 16 + fr][ut * 64 + kk * 32 + kg * 8];
        hacc[fi] = __builtin_amdgcn_mfma_f32_16x16x32_bf16(bs, xh, hacc[fi], 0, 0, 0);
      }
    }
  }
#pragma unroll
  for (int fi = 0; fi < 2; ++fi)
#pragma unroll
    for (int fj = 0; fj < 4; ++fj)
#pragma unroll
      for (int r = 0; r < 4; ++r) {
        const int t = w * 32 + fi * 16 + kg * 4 + r;
        const int d = fj * 16 + fr;
        xz[(size_t)(rbase + t) * N2 + h * DH + d] = f2bf(yacc[fi][fj][r]);
      }
  const int dcol = w * 16 + fr;
#pragma unroll
  for (int fi = 0; fi < 4; ++fi) {
    ushort4 pk;
    pk.x = f2bf(hacc[fi][0]); pk.y = f2bf(hacc[fi][1]);
    pk.z = f2bf(hacc[fi][2]); pk.w = f2bf(hacc[fi][3]);
    *(ushort4*)(Hbuf + ((size_t)blk * 64 + dcol) * 64 + fi * 16 + kg * 4) = pk;
  }
}

// ---------------- chunked scan, stage 2: carry across chunks (in place) --------
__global__ __launch_bounds__(256) void k_carry(unsigned short* __restrict__ Hbuf,
                                               const float* __restrict__ Dc) {
  const int bh = blockIdx.x, tid = threadIdx.x;
  float carry[16];
#pragma unroll
  for (int j = 0; j < 16; ++j) carry[j] = 0.f;
  for (int c = 0; c < NCHUNK; ++c) {
    unsigned short* p = Hbuf + (((size_t)(bh * NCHUNK + c)) << 12) + tid * 16;
    const uint4 v0 = *(const uint4*)(p);
    const uint4 v1 = *(const uint4*)(p + 8);
    const unsigned short* hs0 = (const unsigned short*)&v0;
    const unsigned short* hs1 = (const unsigned short*)&v1;
    float hl[16];
#pragma unroll
    for (int j = 0; j < 8; ++j) { hl[j] = bf2f(hs0[j]); hl[8 + j] = bf2f(hs1[j]); }
    uint4 o0, o1;
    unsigned short* os0 = (unsigned short*)&o0;
    unsigned short* os1 = (unsigned short*)&o1;
#pragma unroll
    for (int j = 0; j < 8; ++j) { os0[j] = f2bf(carry[j]); os1[j] = f2bf(carry[8 + j]); }
    *(uint4*)(p) = o0;
    *(uint4*)(p + 8) = o1;
    const float dc = Dc[bh * NCHUNK + c];
#pragma unroll
    for (int j = 0; j < 16; ++j) carry[j] = fmaf(dc, carry[j], hl[j]);
  }
}

// ---------------- chunked scan, stage 3: inter-chunk Y + fused gating ----------
__global__ __launch_bounds__(256) void k_chunk2(
    const unsigned short* __restrict__ xp2, const float* __restrict__ al,
    const unsigned short* __restrict__ Hbuf, const unsigned short* __restrict__ xz,
    unsigned short* __restrict__ xcg) {
  const int blk = blockIdx.x;
  const int bh = blk >> 4, c = blk & 15;
  const int b = bh / NH, h = bh % NH;
  const int tid = threadIdx.x, w = tid >> 6, lane = tid & 63;
  const int fr = lane & 15, kg = lane >> 4;
  const int rbase = b * LLEN + c * QC;
  const size_t rbase2 = ((size_t)bh << 11) + c * QC;
  __shared__ float lc[QC], rc2[QC];
  __shared__ float wtot[2];
  float a = 1.f, la = 0.f;
  if (tid < QC) { a = al[(size_t)bh * LLEN + c * QC + tid]; la = __logf(a); }
  float s = la;
#pragma unroll
  for (int o = 1; o < 64; o <<= 1) { float t2 = __shfl_up(s, o); if (lane >= o) s += t2; }
  if (tid < QC && lane == 63) wtot[w] = s;
  __syncthreads();
  if (tid < QC) lc[tid] = s + ((w == 1) ? wtot[0] : 0.f);
  __syncthreads();
  bf16x8 cf[2][2];
#pragma unroll
  for (int fi = 0; fi < 2; ++fi) {
    const int t = w * 32 + fi * 16 + fr;
    float ss = 0.f;
#pragma unroll
    for (int kk = 0; kk < 2; ++kk) {
      const uint4 v = *(const uint4*)(xp2 + (rbase2 + t) * XP2LD + 64 + kk * 32 + kg * 8);
      cf[fi][kk] = *(const bf16x8*)&v;
      const unsigned short* cs = (const unsigned short*)&v;
#pragma unroll
      for (int q = 0; q < 8; ++q) { const float cc = bf2f(cs[q]); ss = fmaf(cc, cc, ss); }
    }
    ss += __shfl_xor(ss, 16);
    ss += __shfl_xor(ss, 32);
    if (kg == 0) rc2[t] = 1.f / fmaxf(sqrtf(ss), 1e-12f);
  }
  bf16x8 hf[4][2];
#pragma unroll
  for (int fj = 0; fj < 4; ++fj)
#pragma unroll
    for (int kk = 0; kk < 2; ++kk) {
      const uint4 v = *(const uint4*)(Hbuf + ((size_t)blk * 64 + fj * 16 + fr) * 64 + kk * 32 + kg * 8);
      hf[fj][kk] = *(const bf16x8*)&v;
    }
  __syncthreads();
  f32x4 y[2][4] = {};
#pragma unroll
  for (int kk = 0; kk < 2; ++kk)
#pragma unroll
    for (int fi = 0; fi < 2; ++fi)
#pragma unroll
      for (int fj = 0; fj < 4; ++fj)
        y[fi][fj] = __builtin_amdgcn_mfma_f32_16x16x32_bf16(cf[fi][kk], hf[fj][kk], y[fi][fj], 0, 0, 0);
#pragma unroll
  for (int fi = 0; fi < 2; ++fi)
#pragma unroll
    for (int fj = 0; fj < 4; ++fj)
#pragma unroll
      for (int r = 0; r < 4; ++r) {
        const int t = w * 32 + fi * 16 + kg * 4 + r;
        const int d = fj * 16 + fr;
        const float scl = rc2[t] * __expf(lc[t]);
        const size_t rowg = (size_t)(rbase + t);
        const float yv = y[fi][fj][r] * scl + bf2f(xz[rowg * N2 + h * DH + d]);
        const float zv = bf2f(xz[rowg * N2 + DI + h * DH + d]);
        const float g = yv * (zv / (1.f + __expf(-zv)));
        xcg[rowg * DI + h * DH + d] = f2bf(g);
      }
}

extern "C" void kernel_launch(void* const* d_in, const int* in_sizes, int n_in,
                              void* d_out, int out_size, void* d_ws, size_t ws_size,
                              hipStream_t stream) {
  const float* hs     = (const float*)d_in[0];
  const float* norm_w = (const float*)d_in[1];
  const float* in_w   = (const float*)d_in[2];
  const float* in_b   = (const float*)d_in[3];
  const float* cw     = (const float*)d_in[4];
  const float* cb     = (const float*)d_in[5];
  const float* xw     = (const float*)d_in[6];
  const float* xb     = (const float*)d_in[7];
  const float* A_log  = (const float*)d_in[8];
  const float* l2ab   = (const float*)d_in[9];
  const float* l2b    = (const float*)d_in[10];
  const float* se     = (const float*)d_in[11];
  const float* ow     = (const float*)d_in[12];
  const float* ob     = (const float*)d_in[13];
  const float* rg     = (const float*)d_in[14];
  float* out = (float*)d_out;

  char* ws = (char*)d_ws;
  // layout (~165 MB):
  //   0          xnorm / xcg bf16 (33.5 MB)
  //   33554432   wA bf16 (12.58 MB) -> Hbuf after in_proj
  //   46137344   wX bf16 (9.83 MB)
  //   55967744   wO bf16 (6.29 MB)
  //   62259200   xz bf16 8192x3072 (50.3 MB; x-half reused for Y_intra)
  //   112590848  xp2 bf16 head-blocked 96x2048x128 (50.3 MB)
  //   162922496  xmean fp32 (786 KB)
  //   163708928  al fp32 (786 KB)
  //   164495360  Dc fp32 (6 KB)
  //   164501504  hc fp32 (384 B)
  unsigned short* xnorm = (unsigned short*)(ws);
  unsigned short* wA    = (unsigned short*)(ws + 33554432ull);
  unsigned short* wX    = (unsigned short*)(ws + 46137344ull);
  unsigned short* wO    = (unsigned short*)(ws + 55967744ull);
  unsigned short* xz    = (unsigned short*)(ws + 62259200ull);
  unsigned short* xp2   = (unsigned short*)(ws + 112590848ull);
  float* xmean          = (float*)(ws + 162922496ull);
  float* al             = (float*)(ws + 163708928ull);
  float* Dc             = (float*)(ws + 164495360ull);
  float* hc             = (float*)(ws + 164501504ull);
  unsigned short* xcg   = xnorm;
  unsigned short* Hbuf  = wA;

  // fused front: weight convert (56064 blocks) + RMSNorm (8192) + hc (1)
  k_pre<<<WBLK + MROWS + 1, 256, 0, stream>>>(in_w, wA, xw, wX, ow, wO,
                                              hs, norm_w, xnorm,
                                              A_log, l2ab, l2b, se, hc);
  // in_proj: 64 x 12 = 768 blocks, bf16 out
  k_gemm6<1><<<768, 512, 0, stream>>>(xnorm, wA, in_b, xz, nullptr, nullptr,
                                      nullptr, nullptr, nullptr,
                                      DMODEL, 12, N2, N2);
  // conv + silu + xmean
  k_dwconv<<<(MROWS / 4) * 192 / 256, 256, 0, stream>>>(xz, cw, cb, xcg, xmean);
  // x_proj: 64 x 13 = 832 blocks; head-blocked xp2 + inline alpha
  k_gemm6<3><<<832, 512, 0, stream>>>(xcg, wX, xb, xp2, nullptr, nullptr,
                                      xmean, al, hc,
                                      DI, 13, NP, 0);
  // chunked scan
  k_chunk1<<<BB * NH * NCHUNK, 256, 0, stream>>>(xp2, xcg, al, xz, Hbuf, Dc);
  k_carry<<<BB * NH, 256, 0, stream>>>(Hbuf, Dc);
  k_chunk2<<<BB * NH * NCHUNK, 256, 0, stream>>>(xp2, al, Hbuf, xz, xcg);
  // out_proj: 64 x 8 = 512 blocks, fp32 + residual
  k_gemm6<2><<<512, 512, 0, stream>>>(xcg, wO, ob, out, hs, rg,
                                      nullptr, nullptr, nullptr,
                                      DI, 8, DMODEL, DMODEL);
}

// Round 13
// 484.732 us; speedup vs baseline: 1.0964x; 1.0020x over previous
//
#include <hip/hip_runtime.h>
#include <stdint.h>

// Problem constants
#define BB 4
#define LLEN 2048
#define DMODEL 2048
#define NH 24
#define DH 64
#define SS 64
#define DI 1536          // NH*DH
#define N2 3072          // 2*DI
#define NP 3096          // NH*(1+2*S)
#define NP_PAD 3200      // weight rows padded (zero rows 3096..3199)
#define MROWS 8192       // BB*LLEN
#define NCHUNK 16
#define QC 128           // chunk length
// xp2 row stride: 136 elems = 272B = 17*16B. NON-power-of-2 on purpose:
// 128 (256B) row stride causes L2 set-aliasing on the scattered epilogue
// writes (r12: WRITE_SIZE 51->78MB, dispatch 118->161us). Slots: B 0..63,
// C 64..127, 128..135 pad.
#define XP2LD 136
#define WBLK 56064       // weight-convert blocks in k_pre

using bf16x8 = __bf16 __attribute__((ext_vector_type(8)));
using f32x4  = float __attribute__((ext_vector_type(4)));

__device__ __forceinline__ unsigned short f2bf(float f) {
  union { float f; unsigned int u; } v; v.f = f;
  unsigned int u = v.u + 0x7fffu + ((v.u >> 16) & 1u);
  return (unsigned short)(u >> 16);
}
__device__ __forceinline__ float bf2f(unsigned short h) {
  union { unsigned int u; float f; } v; v.u = ((unsigned int)h) << 16;
  return v.f;
}

__device__ __forceinline__ void gload16(const void* g, void* l) {
  __builtin_amdgcn_global_load_lds(
    reinterpret_cast<const __attribute__((address_space(1))) void*>(reinterpret_cast<uintptr_t>(g)),
    reinterpret_cast<__attribute__((address_space(3))) void*>((uint32_t)(reinterpret_cast<uintptr_t>(l))),
    16, 0, 0);
}

// ---------------- fused front kernel: weight conversion + RMSNorm + hc table ---
__global__ __launch_bounds__(256) void k_pre(
    const float* __restrict__ in_w, unsigned short* __restrict__ wA,
    const float* __restrict__ xw, unsigned short* __restrict__ wX,
    const float* __restrict__ ow, unsigned short* __restrict__ wO,
    const float* __restrict__ hs, const float* __restrict__ norm_w,
    unsigned short* __restrict__ xnorm,
    const float* __restrict__ A_log, const float* __restrict__ l2ab,
    const float* __restrict__ l2b, const float* __restrict__ se,
    float* __restrict__ hc) {
  const int blk = blockIdx.x;
  const int t = threadIdx.x;
  if (blk < WBLK) {
    int i = blk * 256 + t;
    if (i < N2 * DMODEL) { wA[i] = f2bf(in_w[i]); return; }
    i -= N2 * DMODEL;
    if (i < NP_PAD * DI) { wX[i] = (i < NP * DI) ? f2bf(xw[i]) : (unsigned short)0; return; }
    i -= NP_PAD * DI;
    wO[i] = f2bf(ow[i]);
    return;
  }
  if (blk == WBLK + MROWS) {
    if (t < NH) {
      hc[t]          = fminf(fmaxf(A_log[t], -2.3f), -0.01f);
      hc[NH + t]     = exp2f(fminf(fmaxf(l2b[t], -2.f), 2.f));
      hc[2 * NH + t] = 1.f - exp2f(fminf(fmaxf(l2ab[t], -3.32f), -0.015f));
      hc[3 * NH + t] = 1.f / (se[t] + 1e-6f);
    }
    return;
  }
  const int row = blk - WBLK;
  const float* x = hs + (size_t)row * DMODEL;
  float4 v0 = reinterpret_cast<const float4*>(x)[t * 2 + 0];
  float4 v1 = reinterpret_cast<const float4*>(x)[t * 2 + 1];
  float ss = v0.x * v0.x + v0.y * v0.y + v0.z * v0.z + v0.w * v0.w +
             v1.x * v1.x + v1.y * v1.y + v1.z * v1.z + v1.w * v1.w;
#pragma unroll
  for (int o = 32; o; o >>= 1) ss += __shfl_xor(ss, o);
  __shared__ float red[4];
  if ((t & 63) == 0) red[t >> 6] = ss;
  __syncthreads();
  ss = red[0] + red[1] + red[2] + red[3];
  const float r = rsqrtf(ss * (1.0f / DMODEL) + 1.1920928955078125e-07f);
  float4 w0 = reinterpret_cast<const float4*>(norm_w)[t * 2 + 0];
  float4 w1 = reinterpret_cast<const float4*>(norm_w)[t * 2 + 1];
  union { unsigned short u[8]; uint4 v; } pk;
  pk.u[0] = f2bf(v0.x * r * w0.x); pk.u[1] = f2bf(v0.y * r * w0.y);
  pk.u[2] = f2bf(v0.z * r * w0.z); pk.u[3] = f2bf(v0.w * r * w0.w);
  pk.u[4] = f2bf(v1.x * r * w1.x); pk.u[5] = f2bf(v1.y * r * w1.y);
  pk.u[6] = f2bf(v1.z * r * w1.z); pk.u[7] = f2bf(v1.w * r * w1.w);
  *reinterpret_cast<uint4*>(xnorm + (size_t)row * DMODEL + t * 8) = pk.v;
}

// ---------------- drift + distance-2 bf16 NT GEMM (128x256 tile, BK=64) --------
// EPI 1: bf16 C = acc+bias. EPI 2: fp32 C = resid + rg*(acc+bias).
// EPI 3: head-blocked xp2 write (B/C cols, stride XP2LD) + inline alpha (e==0).
template <int EPI>
__global__ __launch_bounds__(512, 2)
void k_gemm6(const unsigned short* __restrict__ A, const unsigned short* __restrict__ B,
             const float* __restrict__ bias, void* __restrict__ Cv,
             const float* __restrict__ resid, const float* __restrict__ gatep,
             const float* __restrict__ xmean, float* __restrict__ al,
             const float* __restrict__ hc,
             int K, int NT_N, int Nout, int ldc) {
  constexpr int AELEM = 128 * 64;
  constexpr int BUFE = AELEM + 16384;
  __shared__ alignas(16) unsigned short sm[3 * BUFE];
  const int tid = threadIdx.x;
  const int lane = tid & 63, wid = tid >> 6;
  const int wm = wid >> 2, wn = wid & 3;
  const int fr = lane & 15, kg = lane >> 4;
  const int nwg = gridDim.x;
  const int wg = ((int)blockIdx.x & 7) * (nwg >> 3) + ((int)blockIdx.x >> 3);
  const int m0 = (wg / NT_N) * 128, n0 = (wg % NT_N) * 256;
  const int NT = K >> 6;

  const unsigned short* asrc[2];
  const unsigned short* bsrc[4];
#pragma unroll
  for (int li = 0; li < 2; ++li) {
    const int gi = li * 512 + tid, r = gi >> 3, q = gi & 7;
    asrc[li] = A + (size_t)(m0 + r) * K + ((q ^ (r & 7)) << 3);
  }
#pragma unroll
  for (int li = 0; li < 4; ++li) {
    const int gi = li * 512 + tid, r = gi >> 3, q = gi & 7;
    bsrc[li] = B + (size_t)(n0 + r) * K + ((q ^ (r & 7)) << 3);
  }
  const int wlds = wid * 64;

#define STG6(buf, ko)                                                          \
  { unsigned short* da_ = sm + (buf) * BUFE;                                   \
    gload16(asrc[0] + (ko), da_ + ((0 * 512 + wlds) << 3));                    \
    gload16(asrc[1] + (ko), da_ + ((1 * 512 + wlds) << 3));                    \
    unsigned short* db_ = sm + (buf) * BUFE + AELEM;                           \
    _Pragma("unroll") for (int li = 0; li < 4; ++li)                           \
      gload16(bsrc[li] + (ko), db_ + ((li * 512 + wlds) << 3)); }

#define ARD6(bufp, f, kk)                                                      \
  (*(const bf16x8*)((bufp) + (wm * 64 + (f) * 16 + fr) * 64 +                  \
      ((((kk) * 4 + kg) ^ (fr & 7)) << 3)))
#define BRD6(bufp, nf, kk)                                                     \
  (*(const bf16x8*)((bufp) + AELEM + (wn * 64 + (nf) * 16 + fr) * 64 +         \
      ((((kk) * 4 + kg) ^ (fr & 7)) << 3)))

  f32x4 acc[4][4] = {};

  STG6(0, 0)
  STG6(1, 64)
  asm volatile("s_waitcnt vmcnt(6)" ::: "memory");
  __builtin_amdgcn_s_barrier();

  int bc_i = 0;
  for (int t = 0; t < NT; ++t) {
    unsigned short* bc = sm + bc_i * BUFE;
    const int bn_i = (bc_i + 2 >= 3) ? (bc_i - 1) : (bc_i + 2);
    const bool st = (t + 2) < NT;
    if (st) STG6(bn_i, (t + 2) << 6)

    bf16x8 bfv[4][2], af[4][2];
#pragma unroll
    for (int nf = 0; nf < 4; ++nf) {
      bfv[nf][0] = BRD6(bc, nf, 0);
      bfv[nf][1] = BRD6(bc, nf, 1);
    }
#pragma unroll
    for (int mf = 0; mf < 4; ++mf) {
      af[mf][0] = ARD6(bc, mf, 0);
      af[mf][1] = ARD6(bc, mf, 1);
    }
    __builtin_amdgcn_sched_barrier(0);
    asm volatile("s_waitcnt lgkmcnt(0)" ::: "memory");
    __builtin_amdgcn_sched_barrier(0);
    __builtin_amdgcn_s_setprio(1);
#pragma unroll
    for (int mf = 0; mf < 4; ++mf)
#pragma unroll
      for (int nf = 0; nf < 4; ++nf)
#pragma unroll
        for (int kk = 0; kk < 2; ++kk)
          acc[mf][nf] = __builtin_amdgcn_mfma_f32_16x16x32_bf16(
              af[mf][kk], bfv[nf][kk], acc[mf][nf], 0, 0, 0);
    __builtin_amdgcn_s_setprio(0);

    if (st) { asm volatile("s_waitcnt vmcnt(6)" ::: "memory"); }
    else    { asm volatile("s_waitcnt vmcnt(0)" ::: "memory"); }
    __builtin_amdgcn_s_barrier();
    bc_i = (bc_i + 1 >= 3) ? 0 : (bc_i + 1);
  }

  // epilogue
  float* Cf = (float*)Cv;
  unsigned short* Ch = (unsigned short*)Cv;
  const float rg = (EPI == 2) ? gatep[0] : 0.f;
#pragma unroll
  for (int nf = 0; nf < 4; ++nf) {
    const int col = n0 + wn * 64 + nf * 16 + fr;
    if (col >= Nout) continue;
    const float bv = bias[col];
    if (EPI == 3) {
      const int h = col / 129;
      const int e = col - h * 129;
      if (e == 0) {
        const float Ac = hc[h], bet = hc[NH + h], ab = hc[2 * NH + h], rse = hc[3 * NH + h];
#pragma unroll
        for (int mf = 0; mf < 4; ++mf) {
          const int rowb = m0 + wm * 64 + mf * 16 + kg * 4;
#pragma unroll
          for (int r = 0; r < 4; ++r) {
            const int row = rowb + r;
            const float dt = acc[mf][nf][r] + bv;
            const float sp = (dt > 20.f) ? dt : log1pf(expf(dt));
            const float one_a = 1.f - expf(Ac * sp);
            const size_t r2 = (((size_t)((row >> 11) * NH + h)) << 11) + (row & (LLEN - 1));
            const float xm = xmean[r2];
            const float pe = one_a * one_a * xm * xm * (1.f / 64.f);
            const float boost = fmaxf(tanhf(bet * pe * rse), 0.f);
            al[r2] = fminf(fmaxf(ab + (1.f - ab) * boost, 0.01f), 0.999f);
          }
        }
      } else {
        const int ep = e - 1;
#pragma unroll
        for (int mf = 0; mf < 4; ++mf) {
          const int rowb = m0 + wm * 64 + mf * 16 + kg * 4;
#pragma unroll
          for (int r = 0; r < 4; ++r) {
            const int row = rowb + r;
            const size_t dst =
                (((size_t)((row >> 11) * NH + h) << 11) + (row & (LLEN - 1))) * XP2LD + ep;
            Ch[dst] = f2bf(acc[mf][nf][r] + bv);
          }
        }
      }
    } else {
#pragma unroll
      for (int mf = 0; mf < 4; ++mf) {
        const int rowb = m0 + wm * 64 + mf * 16 + kg * 4;
#pragma unroll
        for (int r = 0; r < 4; ++r) {
          const size_t o = (size_t)(rowb + r) * ldc + col;
          float v = acc[mf][nf][r] + bv;
          if (EPI == 1) {
            Ch[o] = f2bf(v);
          } else {
            v = resid[o] + rg * v;
            Cf[o] = v;
          }
        }
      }
    }
  }
#undef STG6
#undef ARD6
#undef BRD6
}

// ---------------- depthwise causal conv(4) + silu + per-head x-mean ------------
__global__ __launch_bounds__(256) void k_dwconv(const unsigned short* __restrict__ xz,
                                                const float* __restrict__ cw,
                                                const float* __restrict__ cb,
                                                unsigned short* __restrict__ out,
                                                float* __restrict__ xmean) {
  const int idx = blockIdx.x * 256 + threadIdx.x;  // < (MROWS/4)*192
  const int c0 = (idx % 192) * 8;
  const int bl0 = (idx / 192) * 4;
  const int lpos0 = bl0 & (LLEN - 1);
  float w[8][4];
#pragma unroll
  for (int j = 0; j < 8; ++j) {
    const float4 wv = *(const float4*)(cw + (c0 + j) * 4);
    w[j][0] = wv.x; w[j][1] = wv.y; w[j][2] = wv.z; w[j][3] = wv.w;
  }
  float xr[7][8];
#pragma unroll
  for (int m = 0; m < 7; ++m) {
    uint4 xv = make_uint4(0u, 0u, 0u, 0u);
    if (lpos0 - 3 + m >= 0)
      xv = *(const uint4*)(xz + (size_t)(bl0 - 3 + m) * N2 + c0);
    const unsigned short* xs = (const unsigned short*)&xv;
#pragma unroll
    for (int j = 0; j < 8; ++j) xr[m][j] = bf2f(xs[j]);
  }
  const float4 cb0 = *(const float4*)(cb + c0);
  const float4 cb1 = *(const float4*)(cb + c0 + 4);
  const float cbv[8] = {cb0.x, cb0.y, cb0.z, cb0.w, cb1.x, cb1.y, cb1.z, cb1.w};
  float hsum[4] = {0.f, 0.f, 0.f, 0.f};
#pragma unroll
  for (int t4 = 0; t4 < 4; ++t4) {
    union { unsigned short u[8]; uint4 v; } pk;
#pragma unroll
    for (int j = 0; j < 8; ++j) {
      float a = cbv[j];
#pragma unroll
      for (int k = 0; k < 4; ++k) a = fmaf(w[j][k], xr[t4 + k][j], a);
      a = a / (1.f + __expf(-a));
      hsum[t4] += a;
      pk.u[j] = f2bf(a);
    }
    *(uint4*)(out + (size_t)(bl0 + t4) * DI + c0) = pk.v;
  }
#pragma unroll
  for (int o = 1; o < 8; o <<= 1) {
#pragma unroll
    for (int t4 = 0; t4 < 4; ++t4) hsum[t4] += __shfl_xor(hsum[t4], o);
  }
  if ((threadIdx.x & 7) == 0) {
    const int h = (idx % 192) >> 3;
    const int b = bl0 >> 11;
    float4 xm = make_float4(hsum[0] * (1.f / 64.f), hsum[1] * (1.f / 64.f),
                            hsum[2] * (1.f / 64.f), hsum[3] * (1.f / 64.f));
    *(float4*)(xmean + (((size_t)(b * NH + h)) << 11) + lpos0) = xm;
  }
}

// ---------------- chunked scan, stage 1: intra-chunk Y + local state -----------
__global__ __launch_bounds__(256) void k_chunk1(
    const unsigned short* __restrict__ xp2, const unsigned short* __restrict__ xcg,
    const float* __restrict__ al, unsigned short* __restrict__ xz,
    unsigned short* __restrict__ Hbuf, float* __restrict__ Dc) {
  const int blk = blockIdx.x;          // bh*16 + c
  const int bh = blk >> 4, c = blk & 15;
  const int b = bh / NH, h = bh % NH;
  const int tid = threadIdx.x, w = tid >> 6, lane = tid & 63;
  const int fr = lane & 15, kg = lane >> 4;
  const int rbase = b * LLEN + c * QC;
  const size_t rbase2 = ((size_t)bh << 11) + c * QC;

  __shared__ float lc[QC], ia[QC], escl[QC], rbA[QC], rcC[QC];
  __shared__ float wtot[2];
  __shared__ alignas(16) unsigned short XT[64][152];
  __shared__ alignas(16) unsigned short BsT[64][152];
  __shared__ alignas(16) unsigned short Pt[128][88];

  float a = 1.f, la = 0.f;
  if (tid < QC) { a = al[(size_t)bh * LLEN + c * QC + tid]; la = __logf(a); }
  float s = la;
#pragma unroll
  for (int o = 1; o < 64; o <<= 1) { float t2 = __shfl_up(s, o); if (lane >= o) s += t2; }
  if (tid < QC && lane == 63) wtot[w] = s;
  __syncthreads();
  if (tid < QC) { lc[tid] = s + ((w == 1) ? wtot[0] : 0.f); ia[tid] = 1.f - a; }
  __syncthreads();
  const float lcE = lc[QC - 1];
  if (tid < QC) escl[tid] = __expf(lcE - lc[tid]);
  if (tid == 0) Dc[blk] = __expf(lcE);
  __syncthreads();

  {
    const int r8 = tid >> 3, q8 = tid & 7;
#pragma unroll
    for (int it = 0; it < 4; ++it) {
      const int u = it * 32 + r8;
      const uint4 xv = *(const uint4*)(xcg + (size_t)(rbase + u) * DI + h * DH + q8 * 8);
      const unsigned short* xs = (const unsigned short*)&xv;
#pragma unroll
      for (int j = 0; j < 8; ++j) XT[q8 * 8 + j][u] = xs[j];
      const size_t prow = (rbase2 + u) * XP2LD;
      const uint4 bv = *(const uint4*)(xp2 + prow + q8 * 8);
      const uint4 cv = *(const uint4*)(xp2 + prow + 64 + q8 * 8);
      const unsigned short* bsv = (const unsigned short*)&bv;
      const unsigned short* csv = (const unsigned short*)&cv;
      float bb[8], sb = 0.f, sc2 = 0.f;
#pragma unroll
      for (int j = 0; j < 8; ++j) {
        bb[j] = bf2f(bsv[j]);
        sb = fmaf(bb[j], bb[j], sb);
        const float cc = bf2f(csv[j]);
        sc2 = fmaf(cc, cc, sc2);
      }
      sb += __shfl_xor(sb, 1); sb += __shfl_xor(sb, 2); sb += __shfl_xor(sb, 4);
      sc2 += __shfl_xor(sc2, 1); sc2 += __shfl_xor(sc2, 2); sc2 += __shfl_xor(sc2, 4);
      const float rcpB = 1.f / fmaxf(sqrtf(sb), 1e-12f);
      const float e = escl[u] * ia[u] * rcpB;
#pragma unroll
      for (int j = 0; j < 8; ++j) BsT[q8 * 8 + j][u] = f2bf(bb[j] * e);
      if (q8 == 0) {
        rbA[u] = ia[u] * rcpB;
        rcC[u] = 1.f / fmaxf(sqrtf(sc2), 1e-12f);
      }
    }
  }
  __syncthreads();

  bf16x8 cf[2][2];
#pragma unroll
  for (int fi = 0; fi < 2; ++fi)
#pragma unroll
    for (int kk = 0; kk < 2; ++kk) {
      const int t = w * 32 + fi * 16 + fr;
      const uint4 v = *(const uint4*)(xp2 + (rbase2 + t) * XP2LD + 64 + kk * 32 + kg * 8);
      cf[fi][kk] = *(const bf16x8*)&v;
    }

  float lct[2][4], rct[2][4];
#pragma unroll
  for (int fi = 0; fi < 2; ++fi)
#pragma unroll
    for (int r = 0; r < 4; ++r) {
      const int t = w * 32 + fi * 16 + kg * 4 + r;
      lct[fi][r] = lc[t];
      rct[fi][r] = rcC[t];
    }

  f32x4 yacc[2][4] = {};
  f32x4 hacc[4] = {};
#pragma unroll
  for (int ut = 0; ut < 2; ++ut) {
    f32x4 g[2][4] = {};
#pragma unroll
    for (int kk = 0; kk < 2; ++kk)
#pragma unroll
      for (int fj = 0; fj < 4; ++fj) {
        const int u = ut * 64 + fj * 16 + fr;
        const uint4 v = *(const uint4*)(xp2 + (rbase2 + u) * XP2LD + kk * 32 + kg * 8);
        const bf16x8 bfrag = *(const bf16x8*)&v;
#pragma unroll
        for (int fi = 0; fi < 2; ++fi)
          g[fi][fj] = __builtin_amdgcn_mfma_f32_16x16x32_bf16(cf[fi][kk], bfrag, g[fi][fj], 0, 0, 0);
      }
#pragma unroll
    for (int fi = 0; fi < 2; ++fi)
#pragma unroll
      for (int fj = 0; fj < 4; ++fj) {
        const int u = ut * 64 + fj * 16 + fr;
        const float lcu = lc[u], sbu = rbA[u];
#pragma unroll
        for (int r = 0; r < 4; ++r) {
          const int t = w * 32 + fi * 16 + kg * 4 + r;
          const float v = (t >= u) ? g[fi][fj][r] * __expf(lct[fi][r] - lcu) * sbu * rct[fi][r] : 0.f;
          Pt[t][fj * 16 + fr] = f2bf(v);
        }
      }
#pragma unroll
    for (int kk = 0; kk < 2; ++kk) {
      bf16x8 xf[4];
#pragma unroll
      for (int fj = 0; fj < 4; ++fj)
        xf[fj] = *(const bf16x8*)&XT[fj * 16 + fr][ut * 64 + kk * 32 + kg * 8];
      bf16x8 pf[2];
#pragma unroll
      for (int fi = 0; fi < 2; ++fi)
        pf[fi] = *(const bf16x8*)&Pt[w * 32 + fi * 16 + fr][kk * 32 + kg * 8];
#pragma unroll
      for (int fi = 0; fi < 2; ++fi)
#pragma unroll
        for (int fj = 0; fj < 4; ++fj)
          yacc[fi][fj] = __builtin_amdgcn_mfma_f32_16x16x32_bf16(pf[fi], xf[fj], yacc[fi][fj], 0, 0, 0);
      const bf16x8 xh = *(const bf16x8*)&XT[w * 16 + fr][ut * 64 + kk * 32 + kg * 8];
#pragma unroll
      for (int fi = 0; fi < 4; ++fi) {
        const bf16x8 bs = *(const bf16x8*)&BsT[fi * 16 + fr][ut * 64 + kk * 32 + kg * 8];
        hacc[fi] = __builtin_amdgcn_mfma_f32_16x16x32_bf16(bs, xh, hacc[fi], 0, 0, 0);
      }
    }
  }
#pragma unroll
  for (int fi = 0; fi < 2; ++fi)
#pragma unroll
    for (int fj = 0; fj < 4; ++fj)
#pragma unroll
      for (int r = 0; r < 4; ++r) {
        const int t = w * 32 + fi * 16 + kg * 4 + r;
        const int d = fj * 16 + fr;
        xz[(size_t)(rbase + t) * N2 + h * DH + d] = f2bf(yacc[fi][fj][r]);
      }
  const int dcol = w * 16 + fr;
#pragma unroll
  for (int fi = 0; fi < 4; ++fi) {
    ushort4 pk;
    pk.x = f2bf(hacc[fi][0]); pk.y = f2bf(hacc[fi][1]);
    pk.z = f2bf(hacc[fi][2]); pk.w = f2bf(hacc[fi][3]);
    *(ushort4*)(Hbuf + ((size_t)blk * 64 + dcol) * 64 + fi * 16 + kg * 4) = pk;
  }
}

// ---------------- chunked scan, stage 2: carry across chunks (in place) --------
__global__ __launch_bounds__(256) void k_carry(unsigned short* __restrict__ Hbuf,
                                               const float* __restrict__ Dc) {
  const int bh = blockIdx.x, tid = threadIdx.x;
  float carry[16];
#pragma unroll
  for (int j = 0; j < 16; ++j) carry[j] = 0.f;
  for (int c = 0; c < NCHUNK; ++c) {
    unsigned short* p = Hbuf + (((size_t)(bh * NCHUNK + c)) << 12) + tid * 16;
    const uint4 v0 = *(const uint4*)(p);
    const uint4 v1 = *(const uint4*)(p + 8);
    const unsigned short* hs0 = (const unsigned short*)&v0;
    const unsigned short* hs1 = (const unsigned short*)&v1;
    float hl[16];
#pragma unroll
    for (int j = 0; j < 8; ++j) { hl[j] = bf2f(hs0[j]); hl[8 + j] = bf2f(hs1[j]); }
    uint4 o0, o1;
    unsigned short* os0 = (unsigned short*)&o0;
    unsigned short* os1 = (unsigned short*)&o1;
#pragma unroll
    for (int j = 0; j < 8; ++j) { os0[j] = f2bf(carry[j]); os1[j] = f2bf(carry[8 + j]); }
    *(uint4*)(p) = o0;
    *(uint4*)(p + 8) = o1;
    const float dc = Dc[bh * NCHUNK + c];
#pragma unroll
    for (int j = 0; j < 16; ++j) carry[j] = fmaf(dc, carry[j], hl[j]);
  }
}

// ---------------- chunked scan, stage 3: inter-chunk Y + fused gating ----------
__global__ __launch_bounds__(256) void k_chunk2(
    const unsigned short* __restrict__ xp2, const float* __restrict__ al,
    const unsigned short* __restrict__ Hbuf, const unsigned short* __restrict__ xz,
    unsigned short* __restrict__ xcg) {
  const int blk = blockIdx.x;
  const int bh = blk >> 4, c = blk & 15;
  const int b = bh / NH, h = bh % NH;
  const int tid = threadIdx.x, w = tid >> 6, lane = tid & 63;
  const int fr = lane & 15, kg = lane >> 4;
  const int rbase = b * LLEN + c * QC;
  const size_t rbase2 = ((size_t)bh << 11) + c * QC;
  __shared__ float lc[QC], rc2[QC];
  __shared__ float wtot[2];
  float a = 1.f, la = 0.f;
  if (tid < QC) { a = al[(size_t)bh * LLEN + c * QC + tid]; la = __logf(a); }
  float s = la;
#pragma unroll
  for (int o = 1; o < 64; o <<= 1) { float t2 = __shfl_up(s, o); if (lane >= o) s += t2; }
  if (tid < QC && lane == 63) wtot[w] = s;
  __syncthreads();
  if (tid < QC) lc[tid] = s + ((w == 1) ? wtot[0] : 0.f);
  __syncthreads();
  bf16x8 cf[2][2];
#pragma unroll
  for (int fi = 0; fi < 2; ++fi) {
    const int t = w * 32 + fi * 16 + fr;
    float ss = 0.f;
#pragma unroll
    for (int kk = 0; kk < 2; ++kk) {
      const uint4 v = *(const uint4*)(xp2 + (rbase2 + t) * XP2LD + 64 + kk * 32 + kg * 8);
      cf[fi][kk] = *(const bf16x8*)&v;
      const unsigned short* cs = (const unsigned short*)&v;
#pragma unroll
      for (int q = 0; q < 8; ++q) { const float cc = bf2f(cs[q]); ss = fmaf(cc, cc, ss); }
    }
    ss += __shfl_xor(ss, 16);
    ss += __shfl_xor(ss, 32);
    if (kg == 0) rc2[t] = 1.f / fmaxf(sqrtf(ss), 1e-12f);
  }
  bf16x8 hf[4][2];
#pragma unroll
  for (int fj = 0; fj < 4; ++fj)
#pragma unroll
    for (int kk = 0; kk < 2; ++kk) {
      const uint4 v = *(const uint4*)(Hbuf + ((size_t)blk * 64 + fj * 16 + fr) * 64 + kk * 32 + kg * 8);
      hf[fj][kk] = *(const bf16x8*)&v;
    }
  __syncthreads();
  f32x4 y[2][4] = {};
#pragma unroll
  for (int kk = 0; kk < 2; ++kk)
#pragma unroll
    for (int fi = 0; fi < 2; ++fi)
#pragma unroll
      for (int fj = 0; fj < 4; ++fj)
        y[fi][fj] = __builtin_amdgcn_mfma_f32_16x16x32_bf16(cf[fi][kk], hf[fj][kk], y[fi][fj], 0, 0, 0);
#pragma unroll
  for (int fi = 0; fi < 2; ++fi)
#pragma unroll
    for (int fj = 0; fj < 4; ++fj)
#pragma unroll
      for (int r = 0; r < 4; ++r) {
        const int t = w * 32 + fi * 16 + kg * 4 + r;
        const int d = fj * 16 + fr;
        const float scl = rc2[t] * __expf(lc[t]);
        const size_t rowg = (size_t)(rbase + t);
        const float yv = y[fi][fj][r] * scl + bf2f(xz[rowg * N2 + h * DH + d]);
        const float zv = bf2f(xz[rowg * N2 + DI + h * DH + d]);
        const float g = yv * (zv / (1.f + __expf(-zv)));
        xcg[rowg * DI + h * DH + d] = f2bf(g);
      }
}

extern "C" void kernel_launch(void* const* d_in, const int* in_sizes, int n_in,
                              void* d_out, int out_size, void* d_ws, size_t ws_size,
                              hipStream_t stream) {
  const float* hs     = (const float*)d_in[0];
  const float* norm_w = (const float*)d_in[1];
  const float* in_w   = (const float*)d_in[2];
  const float* in_b   = (const float*)d_in[3];
  const float* cw     = (const float*)d_in[4];
  const float* cb     = (const float*)d_in[5];
  const float* xw     = (const float*)d_in[6];
  const float* xb     = (const float*)d_in[7];
  const float* A_log  = (const float*)d_in[8];
  const float* l2ab   = (const float*)d_in[9];
  const float* l2b    = (const float*)d_in[10];
  const float* se     = (const float*)d_in[11];
  const float* ow     = (const float*)d_in[12];
  const float* ob     = (const float*)d_in[13];
  const float* rg     = (const float*)d_in[14];
  float* out = (float*)d_out;

  char* ws = (char*)d_ws;
  // layout (~168 MB):
  //   0          xnorm / xcg bf16 (33.5 MB)
  //   33554432   wA bf16 (12.58 MB) -> Hbuf after in_proj
  //   46137344   wX bf16 (9.83 MB)
  //   55967744   wO bf16 (6.29 MB)
  //   62259200   xz bf16 8192x3072 (50.3 MB; x-half reused for Y_intra)
  //   112590848  xp2 bf16 head-blocked 96x2048x136 (53.5 MB)
  //   166068224  xmean fp32 (786 KB)
  //   166854656  al fp32 (786 KB)
  //   167641088  Dc fp32 (6 KB)
  //   167647232  hc fp32 (384 B)
  unsigned short* xnorm = (unsigned short*)(ws);
  unsigned short* wA    = (unsigned short*)(ws + 33554432ull);
  unsigned short* wX    = (unsigned short*)(ws + 46137344ull);
  unsigned short* wO    = (unsigned short*)(ws + 55967744ull);
  unsigned short* xz    = (unsigned short*)(ws + 62259200ull);
  unsigned short* xp2   = (unsigned short*)(ws + 112590848ull);
  float* xmean          = (float*)(ws + 166068224ull);
  float* al             = (float*)(ws + 166854656ull);
  float* Dc             = (float*)(ws + 167641088ull);
  float* hc             = (float*)(ws + 167647232ull);
  unsigned short* xcg   = xnorm;
  unsigned short* Hbuf  = wA;

  // fused front: weight convert (56064 blocks) + RMSNorm (8192) + hc (1)
  k_pre<<<WBLK + MROWS + 1, 256, 0, stream>>>(in_w, wA, xw, wX, ow, wO,
                                              hs, norm_w, xnorm,
                                              A_log, l2ab, l2b, se, hc);
  // in_proj: 64 x 12 = 768 blocks, bf16 out
  k_gemm6<1><<<768, 512, 0, stream>>>(xnorm, wA, in_b, xz, nullptr, nullptr,
                                      nullptr, nullptr, nullptr,
                                      DMODEL, 12, N2, N2);
  // conv + silu + xmean
  k_dwconv<<<(MROWS / 4) * 192 / 256, 256, 0, stream>>>(xz, cw, cb, xcg, xmean);
  // x_proj: 64 x 13 = 832 blocks; head-blocked xp2 (stride 136) + inline alpha
  k_gemm6<3><<<832, 512, 0, stream>>>(xcg, wX, xb, xp2, nullptr, nullptr,
                                      xmean, al, hc,
                                      DI, 13, NP, 0);
  // chunked scan
  k_chunk1<<<BB * NH * NCHUNK, 256, 0, stream>>>(xp2, xcg, al, xz, Hbuf, Dc);
  k_carry<<<BB * NH, 256, 0, stream>>>(Hbuf, Dc);
  k_chunk2<<<BB * NH * NCHUNK, 256, 0, stream>>>(xp2, al, Hbuf, xz, xcg);
  // out_proj: 64 x 8 = 512 blocks, fp32 + residual
  k_gemm6<2><<<512, 512, 0, stream>>>(xcg, wO, ob, out, hs, rg,
                                      nullptr, nullptr, nullptr,
                                      DI, 8, DMODEL, DMODEL);
}

// Round 14
// 442.777 us; speedup vs baseline: 1.2003x; 1.0948x over previous
//
#include <hip/hip_runtime.h>
#include <stdint.h>

// Problem constants
#define BB 4
#define LLEN 2048
#define DMODEL 2048
#define NH 24
#define DH 64
#define SS 64
#define DI 1536          // NH*DH
#define N2 3072          // 2*DI
#define NP 3096          // NH*(1+2*S)
#define NP_PAD 3200      // weight rows padded (zero rows 3096..3199)
#define MROWS 8192       // BB*LLEN
#define NCHUNK 16
#define QC 128           // chunk length
// xp2 row stride: 136 elems = 272B = 17*16B (non-power-of-2; see r12 note).
// Slots: B 0..63, C 64..127, 128..135 pad.
#define XP2LD 136
#define WBLK 56064       // weight-convert blocks in k_pre

using bf16x8 = __bf16 __attribute__((ext_vector_type(8)));
using f32x4  = float __attribute__((ext_vector_type(4)));

__device__ __forceinline__ unsigned short f2bf(float f) {
  union { float f; unsigned int u; } v; v.f = f;
  unsigned int u = v.u + 0x7fffu + ((v.u >> 16) & 1u);
  return (unsigned short)(u >> 16);
}
__device__ __forceinline__ float bf2f(unsigned short h) {
  union { unsigned int u; float f; } v; v.u = ((unsigned int)h) << 16;
  return v.f;
}

__device__ __forceinline__ void gload16(const void* g, void* l) {
  __builtin_amdgcn_global_load_lds(
    reinterpret_cast<const __attribute__((address_space(1))) void*>(reinterpret_cast<uintptr_t>(g)),
    reinterpret_cast<__attribute__((address_space(3))) void*>((uint32_t)(reinterpret_cast<uintptr_t>(l))),
    16, 0, 0);
}

// ---------------- fused front kernel: weight conversion + RMSNorm + hc table ---
__global__ __launch_bounds__(256) void k_pre(
    const float* __restrict__ in_w, unsigned short* __restrict__ wA,
    const float* __restrict__ xw, unsigned short* __restrict__ wX,
    const float* __restrict__ ow, unsigned short* __restrict__ wO,
    const float* __restrict__ hs, const float* __restrict__ norm_w,
    unsigned short* __restrict__ xnorm,
    const float* __restrict__ A_log, const float* __restrict__ l2ab,
    const float* __restrict__ l2b, const float* __restrict__ se,
    float* __restrict__ hc) {
  const int blk = blockIdx.x;
  const int t = threadIdx.x;
  if (blk < WBLK) {
    int i = blk * 256 + t;
    if (i < N2 * DMODEL) { wA[i] = f2bf(in_w[i]); return; }
    i -= N2 * DMODEL;
    if (i < NP_PAD * DI) { wX[i] = (i < NP * DI) ? f2bf(xw[i]) : (unsigned short)0; return; }
    i -= NP_PAD * DI;
    wO[i] = f2bf(ow[i]);
    return;
  }
  if (blk == WBLK + MROWS) {
    if (t < NH) {
      hc[t]          = fminf(fmaxf(A_log[t], -2.3f), -0.01f);
      hc[NH + t]     = exp2f(fminf(fmaxf(l2b[t], -2.f), 2.f));
      hc[2 * NH + t] = 1.f - exp2f(fminf(fmaxf(l2ab[t], -3.32f), -0.015f));
      hc[3 * NH + t] = 1.f / (se[t] + 1e-6f);
    }
    return;
  }
  const int row = blk - WBLK;
  const float* x = hs + (size_t)row * DMODEL;
  float4 v0 = reinterpret_cast<const float4*>(x)[t * 2 + 0];
  float4 v1 = reinterpret_cast<const float4*>(x)[t * 2 + 1];
  float ss = v0.x * v0.x + v0.y * v0.y + v0.z * v0.z + v0.w * v0.w +
             v1.x * v1.x + v1.y * v1.y + v1.z * v1.z + v1.w * v1.w;
#pragma unroll
  for (int o = 32; o; o >>= 1) ss += __shfl_xor(ss, o);
  __shared__ float red[4];
  if ((t & 63) == 0) red[t >> 6] = ss;
  __syncthreads();
  ss = red[0] + red[1] + red[2] + red[3];
  const float r = rsqrtf(ss * (1.0f / DMODEL) + 1.1920928955078125e-07f);
  float4 w0 = reinterpret_cast<const float4*>(norm_w)[t * 2 + 0];
  float4 w1 = reinterpret_cast<const float4*>(norm_w)[t * 2 + 1];
  union { unsigned short u[8]; uint4 v; } pk;
  pk.u[0] = f2bf(v0.x * r * w0.x); pk.u[1] = f2bf(v0.y * r * w0.y);
  pk.u[2] = f2bf(v0.z * r * w0.z); pk.u[3] = f2bf(v0.w * r * w0.w);
  pk.u[4] = f2bf(v1.x * r * w1.x); pk.u[5] = f2bf(v1.y * r * w1.y);
  pk.u[6] = f2bf(v1.z * r * w1.z); pk.u[7] = f2bf(v1.w * r * w1.w);
  *reinterpret_cast<uint4*>(xnorm + (size_t)row * DMODEL + t * 8) = pk.v;
}

// ---------------- drift + distance-2 bf16 NT GEMM (128x256 tile, BK=64) --------
// EPI 1: bf16 C = acc+bias. EPI 2: fp32 C = resid + rg*(acc+bias).
// EPI 3: head-blocked xp2 write (B/C cols, stride XP2LD); dt cols (e==0) ->
//        compact fp32 dtbuf[r2] (alpha math lives in k_alpha, NOT here — the
//        inline tanh/exp version perturbed the whole kernel's codegen: r12/13
//        x_proj 118->161us; keep the epilogue dumb).
template <int EPI>
__global__ __launch_bounds__(512, 2)
void k_gemm6(const unsigned short* __restrict__ A, const unsigned short* __restrict__ B,
             const float* __restrict__ bias, void* __restrict__ Cv,
             const float* __restrict__ resid, const float* __restrict__ gatep,
             float* __restrict__ dtbuf,
             int K, int NT_N, int Nout, int ldc) {
  constexpr int AELEM = 128 * 64;
  constexpr int BUFE = AELEM + 16384;
  __shared__ alignas(16) unsigned short sm[3 * BUFE];
  const int tid = threadIdx.x;
  const int lane = tid & 63, wid = tid >> 6;
  const int wm = wid >> 2, wn = wid & 3;
  const int fr = lane & 15, kg = lane >> 4;
  const int nwg = gridDim.x;
  const int wg = ((int)blockIdx.x & 7) * (nwg >> 3) + ((int)blockIdx.x >> 3);
  const int m0 = (wg / NT_N) * 128, n0 = (wg % NT_N) * 256;
  const int NT = K >> 6;

  const unsigned short* asrc[2];
  const unsigned short* bsrc[4];
#pragma unroll
  for (int li = 0; li < 2; ++li) {
    const int gi = li * 512 + tid, r = gi >> 3, q = gi & 7;
    asrc[li] = A + (size_t)(m0 + r) * K + ((q ^ (r & 7)) << 3);
  }
#pragma unroll
  for (int li = 0; li < 4; ++li) {
    const int gi = li * 512 + tid, r = gi >> 3, q = gi & 7;
    bsrc[li] = B + (size_t)(n0 + r) * K + ((q ^ (r & 7)) << 3);
  }
  const int wlds = wid * 64;

#define STG6(buf, ko)                                                          \
  { unsigned short* da_ = sm + (buf) * BUFE;                                   \
    gload16(asrc[0] + (ko), da_ + ((0 * 512 + wlds) << 3));                    \
    gload16(asrc[1] + (ko), da_ + ((1 * 512 + wlds) << 3));                    \
    unsigned short* db_ = sm + (buf) * BUFE + AELEM;                           \
    _Pragma("unroll") for (int li = 0; li < 4; ++li)                           \
      gload16(bsrc[li] + (ko), db_ + ((li * 512 + wlds) << 3)); }

#define ARD6(bufp, f, kk)                                                      \
  (*(const bf16x8*)((bufp) + (wm * 64 + (f) * 16 + fr) * 64 +                  \
      ((((kk) * 4 + kg) ^ (fr & 7)) << 3)))
#define BRD6(bufp, nf, kk)                                                     \
  (*(const bf16x8*)((bufp) + AELEM + (wn * 64 + (nf) * 16 + fr) * 64 +         \
      ((((kk) * 4 + kg) ^ (fr & 7)) << 3)))

  f32x4 acc[4][4] = {};

  STG6(0, 0)
  STG6(1, 64)
  asm volatile("s_waitcnt vmcnt(6)" ::: "memory");
  __builtin_amdgcn_s_barrier();

  int bc_i = 0;
  for (int t = 0; t < NT; ++t) {
    unsigned short* bc = sm + bc_i * BUFE;
    const int bn_i = (bc_i + 2 >= 3) ? (bc_i - 1) : (bc_i + 2);
    const bool st = (t + 2) < NT;
    if (st) STG6(bn_i, (t + 2) << 6)

    bf16x8 bfv[4][2], af[4][2];
#pragma unroll
    for (int nf = 0; nf < 4; ++nf) {
      bfv[nf][0] = BRD6(bc, nf, 0);
      bfv[nf][1] = BRD6(bc, nf, 1);
    }
#pragma unroll
    for (int mf = 0; mf < 4; ++mf) {
      af[mf][0] = ARD6(bc, mf, 0);
      af[mf][1] = ARD6(bc, mf, 1);
    }
    __builtin_amdgcn_sched_barrier(0);
    asm volatile("s_waitcnt lgkmcnt(0)" ::: "memory");
    __builtin_amdgcn_sched_barrier(0);
    __builtin_amdgcn_s_setprio(1);
#pragma unroll
    for (int mf = 0; mf < 4; ++mf)
#pragma unroll
      for (int nf = 0; nf < 4; ++nf)
#pragma unroll
        for (int kk = 0; kk < 2; ++kk)
          acc[mf][nf] = __builtin_amdgcn_mfma_f32_16x16x32_bf16(
              af[mf][kk], bfv[nf][kk], acc[mf][nf], 0, 0, 0);
    __builtin_amdgcn_s_setprio(0);

    if (st) { asm volatile("s_waitcnt vmcnt(6)" ::: "memory"); }
    else    { asm volatile("s_waitcnt vmcnt(0)" ::: "memory"); }
    __builtin_amdgcn_s_barrier();
    bc_i = (bc_i + 1 >= 3) ? 0 : (bc_i + 1);
  }

  // epilogue
  float* Cf = (float*)Cv;
  unsigned short* Ch = (unsigned short*)Cv;
  const float rg = (EPI == 2) ? gatep[0] : 0.f;
#pragma unroll
  for (int nf = 0; nf < 4; ++nf) {
    const int col = n0 + wn * 64 + nf * 16 + fr;
    if (col >= Nout) continue;
    const float bv = bias[col];
    if (EPI == 3) {
      const int h = col / 129;
      const int e = col - h * 129;
      if (e == 0) {
#pragma unroll
        for (int mf = 0; mf < 4; ++mf) {
          const int rowb = m0 + wm * 64 + mf * 16 + kg * 4;
#pragma unroll
          for (int r = 0; r < 4; ++r) {
            const int row = rowb + r;
            const size_t r2 = (((size_t)((row >> 11) * NH + h)) << 11) + (row & (LLEN - 1));
            dtbuf[r2] = acc[mf][nf][r] + bv;
          }
        }
      } else {
        const int ep = e - 1;
#pragma unroll
        for (int mf = 0; mf < 4; ++mf) {
          const int rowb = m0 + wm * 64 + mf * 16 + kg * 4;
#pragma unroll
          for (int r = 0; r < 4; ++r) {
            const int row = rowb + r;
            const size_t dst =
                (((size_t)((row >> 11) * NH + h) << 11) + (row & (LLEN - 1))) * XP2LD + ep;
            Ch[dst] = f2bf(acc[mf][nf][r] + bv);
          }
        }
      }
    } else {
#pragma unroll
      for (int mf = 0; mf < 4; ++mf) {
        const int rowb = m0 + wm * 64 + mf * 16 + kg * 4;
#pragma unroll
        for (int r = 0; r < 4; ++r) {
          const size_t o = (size_t)(rowb + r) * ldc + col;
          float v = acc[mf][nf][r] + bv;
          if (EPI == 1) {
            Ch[o] = f2bf(v);
          } else {
            v = resid[o] + rg * v;
            Cf[o] = v;
          }
        }
      }
    }
  }
#undef STG6
#undef ARD6
#undef BRD6
}

// ---------------- alpha: dtbuf + xmean + hc -> al (coalesced, tiny) ------------
__global__ __launch_bounds__(256) void k_alpha(const float* __restrict__ dtbuf,
                                               const float* __restrict__ xmean,
                                               const float* __restrict__ hc,
                                               float* __restrict__ al) {
  const int i = blockIdx.x * 256 + threadIdx.x;   // < BB*NH*LLEN
  const int h = (i >> 11) % NH;
  const float dt = dtbuf[i];
  const float sp = (dt > 20.f) ? dt : log1pf(expf(dt));
  const float one_a = 1.f - expf(hc[h] * sp);
  const float xm = xmean[i];
  const float pe = one_a * one_a * xm * xm * (1.f / 64.f);
  const float boost = fmaxf(tanhf(hc[NH + h] * pe * hc[3 * NH + h]), 0.f);
  const float ab = hc[2 * NH + h];
  al[i] = fminf(fmaxf(ab + (1.f - ab) * boost, 0.01f), 0.999f);
}

// ---------------- depthwise causal conv(4) + silu + per-head x-mean ------------
__global__ __launch_bounds__(256) void k_dwconv(const unsigned short* __restrict__ xz,
                                                const float* __restrict__ cw,
                                                const float* __restrict__ cb,
                                                unsigned short* __restrict__ out,
                                                float* __restrict__ xmean) {
  const int idx = blockIdx.x * 256 + threadIdx.x;  // < (MROWS/4)*192
  const int c0 = (idx % 192) * 8;
  const int bl0 = (idx / 192) * 4;
  const int lpos0 = bl0 & (LLEN - 1);
  float w[8][4];
#pragma unroll
  for (int j = 0; j < 8; ++j) {
    const float4 wv = *(const float4*)(cw + (c0 + j) * 4);
    w[j][0] = wv.x; w[j][1] = wv.y; w[j][2] = wv.z; w[j][3] = wv.w;
  }
  float xr[7][8];
#pragma unroll
  for (int m = 0; m < 7; ++m) {
    uint4 xv = make_uint4(0u, 0u, 0u, 0u);
    if (lpos0 - 3 + m >= 0)
      xv = *(const uint4*)(xz + (size_t)(bl0 - 3 + m) * N2 + c0);
    const unsigned short* xs = (const unsigned short*)&xv;
#pragma unroll
    for (int j = 0; j < 8; ++j) xr[m][j] = bf2f(xs[j]);
  }
  const float4 cb0 = *(const float4*)(cb + c0);
  const float4 cb1 = *(const float4*)(cb + c0 + 4);
  const float cbv[8] = {cb0.x, cb0.y, cb0.z, cb0.w, cb1.x, cb1.y, cb1.z, cb1.w};
  float hsum[4] = {0.f, 0.f, 0.f, 0.f};
#pragma unroll
  for (int t4 = 0; t4 < 4; ++t4) {
    union { unsigned short u[8]; uint4 v; } pk;
#pragma unroll
    for (int j = 0; j < 8; ++j) {
      float a = cbv[j];
#pragma unroll
      for (int k = 0; k < 4; ++k) a = fmaf(w[j][k], xr[t4 + k][j], a);
      a = a / (1.f + __expf(-a));
      hsum[t4] += a;
      pk.u[j] = f2bf(a);
    }
    *(uint4*)(out + (size_t)(bl0 + t4) * DI + c0) = pk.v;
  }
#pragma unroll
  for (int o = 1; o < 8; o <<= 1) {
#pragma unroll
    for (int t4 = 0; t4 < 4; ++t4) hsum[t4] += __shfl_xor(hsum[t4], o);
  }
  if ((threadIdx.x & 7) == 0) {
    const int h = (idx % 192) >> 3;
    const int b = bl0 >> 11;
    float4 xm = make_float4(hsum[0] * (1.f / 64.f), hsum[1] * (1.f / 64.f),
                            hsum[2] * (1.f / 64.f), hsum[3] * (1.f / 64.f));
    *(float4*)(xmean + (((size_t)(b * NH + h)) << 11) + lpos0) = xm;
  }
}

// ---------------- chunked scan, stage 1: intra-chunk Y + local state -----------
__global__ __launch_bounds__(256) void k_chunk1(
    const unsigned short* __restrict__ xp2, const unsigned short* __restrict__ xcg,
    const float* __restrict__ al, unsigned short* __restrict__ xz,
    unsigned short* __restrict__ Hbuf, float* __restrict__ Dc) {
  const int blk = blockIdx.x;          // bh*16 + c
  const int bh = blk >> 4, c = blk & 15;
  const int b = bh / NH, h = bh % NH;
  const int tid = threadIdx.x, w = tid >> 6, lane = tid & 63;
  const int fr = lane & 15, kg = lane >> 4;
  const int rbase = b * LLEN + c * QC;
  const size_t rbase2 = ((size_t)bh << 11) + c * QC;

  __shared__ float lc[QC], ia[QC], escl[QC], rbA[QC], rcC[QC];
  __shared__ float wtot[2];
  __shared__ alignas(16) unsigned short XT[64][152];
  __shared__ alignas(16) unsigned short BsT[64][152];
  __shared__ alignas(16) unsigned short Pt[128][88];

  float a = 1.f, la = 0.f;
  if (tid < QC) { a = al[(size_t)bh * LLEN + c * QC + tid]; la = __logf(a); }
  float s = la;
#pragma unroll
  for (int o = 1; o < 64; o <<= 1) { float t2 = __shfl_up(s, o); if (lane >= o) s += t2; }
  if (tid < QC && lane == 63) wtot[w] = s;
  __syncthreads();
  if (tid < QC) { lc[tid] = s + ((w == 1) ? wtot[0] : 0.f); ia[tid] = 1.f - a; }
  __syncthreads();
  const float lcE = lc[QC - 1];
  if (tid < QC) escl[tid] = __expf(lcE - lc[tid]);
  if (tid == 0) Dc[blk] = __expf(lcE);
  __syncthreads();

  {
    const int r8 = tid >> 3, q8 = tid & 7;
#pragma unroll
    for (int it = 0; it < 4; ++it) {
      const int u = it * 32 + r8;
      const uint4 xv = *(const uint4*)(xcg + (size_t)(rbase + u) * DI + h * DH + q8 * 8);
      const unsigned short* xs = (const unsigned short*)&xv;
#pragma unroll
      for (int j = 0; j < 8; ++j) XT[q8 * 8 + j][u] = xs[j];
      const size_t prow = (rbase2 + u) * XP2LD;
      const uint4 bv = *(const uint4*)(xp2 + prow + q8 * 8);
      const uint4 cv = *(const uint4*)(xp2 + prow + 64 + q8 * 8);
      const unsigned short* bsv = (const unsigned short*)&bv;
      const unsigned short* csv = (const unsigned short*)&cv;
      float bb[8], sb = 0.f, sc2 = 0.f;
#pragma unroll
      for (int j = 0; j < 8; ++j) {
        bb[j] = bf2f(bsv[j]);
        sb = fmaf(bb[j], bb[j], sb);
        const float cc = bf2f(csv[j]);
        sc2 = fmaf(cc, cc, sc2);
      }
      sb += __shfl_xor(sb, 1); sb += __shfl_xor(sb, 2); sb += __shfl_xor(sb, 4);
      sc2 += __shfl_xor(sc2, 1); sc2 += __shfl_xor(sc2, 2); sc2 += __shfl_xor(sc2, 4);
      const float rcpB = 1.f / fmaxf(sqrtf(sb), 1e-12f);
      const float e = escl[u] * ia[u] * rcpB;
#pragma unroll
      for (int j = 0; j < 8; ++j) BsT[q8 * 8 + j][u] = f2bf(bb[j] * e);
      if (q8 == 0) {
        rbA[u] = ia[u] * rcpB;
        rcC[u] = 1.f / fmaxf(sqrtf(sc2), 1e-12f);
      }
    }
  }
  __syncthreads();

  bf16x8 cf[2][2];
#pragma unroll
  for (int fi = 0; fi < 2; ++fi)
#pragma unroll
    for (int kk = 0; kk < 2; ++kk) {
      const int t = w * 32 + fi * 16 + fr;
      const uint4 v = *(const uint4*)(xp2 + (rbase2 + t) * XP2LD + 64 + kk * 32 + kg * 8);
      cf[fi][kk] = *(const bf16x8*)&v;
    }

  float lct[2][4], rct[2][4];
#pragma unroll
  for (int fi = 0; fi < 2; ++fi)
#pragma unroll
    for (int r = 0; r < 4; ++r) {
      const int t = w * 32 + fi * 16 + kg * 4 + r;
      lct[fi][r] = lc[t];
      rct[fi][r] = rcC[t];
    }

  f32x4 yacc[2][4] = {};
  f32x4 hacc[4] = {};
#pragma unroll
  for (int ut = 0; ut < 2; ++ut) {
    f32x4 g[2][4] = {};
#pragma unroll
    for (int kk = 0; kk < 2; ++kk)
#pragma unroll
      for (int fj = 0; fj < 4; ++fj) {
        const int u = ut * 64 + fj * 16 + fr;
        const uint4 v = *(const uint4*)(xp2 + (rbase2 + u) * XP2LD + kk * 32 + kg * 8);
        const bf16x8 bfrag = *(const bf16x8*)&v;
#pragma unroll
        for (int fi = 0; fi < 2; ++fi)
          g[fi][fj] = __builtin_amdgcn_mfma_f32_16x16x32_bf16(cf[fi][kk], bfrag, g[fi][fj], 0, 0, 0);
      }
#pragma unroll
    for (int fi = 0; fi < 2; ++fi)
#pragma unroll
      for (int fj = 0; fj < 4; ++fj) {
        const int u = ut * 64 + fj * 16 + fr;
        const float lcu = lc[u], sbu = rbA[u];
#pragma unroll
        for (int r = 0; r < 4; ++r) {
          const int t = w * 32 + fi * 16 + kg * 4 + r;
          const float v = (t >= u) ? g[fi][fj][r] * __expf(lct[fi][r] - lcu) * sbu * rct[fi][r] : 0.f;
          Pt[t][fj * 16 + fr] = f2bf(v);
        }
      }
#pragma unroll
    for (int kk = 0; kk < 2; ++kk) {
      bf16x8 xf[4];
#pragma unroll
      for (int fj = 0; fj < 4; ++fj)
        xf[fj] = *(const bf16x8*)&XT[fj * 16 + fr][ut * 64 + kk * 32 + kg * 8];
      bf16x8 pf[2];
#pragma unroll
      for (int fi = 0; fi < 2; ++fi)
        pf[fi] = *(const bf16x8*)&Pt[w * 32 + fi * 16 + fr][kk * 32 + kg * 8];
#pragma unroll
      for (int fi = 0; fi < 2; ++fi)
#pragma unroll
        for (int fj = 0; fj < 4; ++fj)
          yacc[fi][fj] = __builtin_amdgcn_mfma_f32_16x16x32_bf16(pf[fi], xf[fj], yacc[fi][fj], 0, 0, 0);
      const bf16x8 xh = *(const bf16x8*)&XT[w * 16 + fr][ut * 64 + kk * 32 + kg * 8];
#pragma unroll
      for (int fi = 0; fi < 4; ++fi) {
        const bf16x8 bs = *(const bf16x8*)&BsT[fi * 16 + fr][ut * 64 + kk * 32 + kg * 8];
        hacc[fi] = __builtin_amdgcn_mfma_f32_16x16x32_bf16(bs, xh, hacc[fi], 0, 0, 0);
      }
    }
  }
#pragma unroll
  for (int fi = 0; fi < 2; ++fi)
#pragma unroll
    for (int fj = 0; fj < 4; ++fj)
#pragma unroll
      for (int r = 0; r < 4; ++r) {
        const int t = w * 32 + fi * 16 + kg * 4 + r;
        const int d = fj * 16 + fr;
        xz[(size_t)(rbase + t) * N2 + h * DH + d] = f2bf(yacc[fi][fj][r]);
      }
  const int dcol = w * 16 + fr;
#pragma unroll
  for (int fi = 0; fi < 4; ++fi) {
    ushort4 pk;
    pk.x = f2bf(hacc[fi][0]); pk.y = f2bf(hacc[fi][1]);
    pk.z = f2bf(hacc[fi][2]); pk.w = f2bf(hacc[fi][3]);
    *(ushort4*)(Hbuf + ((size_t)blk * 64 + dcol) * 64 + fi * 16 + kg * 4) = pk;
  }
}

// ---------------- chunked scan, stage 2: carry across chunks (in place) --------
__global__ __launch_bounds__(256) void k_carry(unsigned short* __restrict__ Hbuf,
                                               const float* __restrict__ Dc) {
  const int bh = blockIdx.x, tid = threadIdx.x;
  float carry[16];
#pragma unroll
  for (int j = 0; j < 16; ++j) carry[j] = 0.f;
  for (int c = 0; c < NCHUNK; ++c) {
    unsigned short* p = Hbuf + (((size_t)(bh * NCHUNK + c)) << 12) + tid * 16;
    const uint4 v0 = *(const uint4*)(p);
    const uint4 v1 = *(const uint4*)(p + 8);
    const unsigned short* hs0 = (const unsigned short*)&v0;
    const unsigned short* hs1 = (const unsigned short*)&v1;
    float hl[16];
#pragma unroll
    for (int j = 0; j < 8; ++j) { hl[j] = bf2f(hs0[j]); hl[8 + j] = bf2f(hs1[j]); }
    uint4 o0, o1;
    unsigned short* os0 = (unsigned short*)&o0;
    unsigned short* os1 = (unsigned short*)&o1;
#pragma unroll
    for (int j = 0; j < 8; ++j) { os0[j] = f2bf(carry[j]); os1[j] = f2bf(carry[8 + j]); }
    *(uint4*)(p) = o0;
    *(uint4*)(p + 8) = o1;
    const float dc = Dc[bh * NCHUNK + c];
#pragma unroll
    for (int j = 0; j < 16; ++j) carry[j] = fmaf(dc, carry[j], hl[j]);
  }
}

// ---------------- chunked scan, stage 3: inter-chunk Y + fused gating ----------
__global__ __launch_bounds__(256) void k_chunk2(
    const unsigned short* __restrict__ xp2, const float* __restrict__ al,
    const unsigned short* __restrict__ Hbuf, const unsigned short* __restrict__ xz,
    unsigned short* __restrict__ xcg) {
  const int blk = blockIdx.x;
  const int bh = blk >> 4, c = blk & 15;
  const int b = bh / NH, h = bh % NH;
  const int tid = threadIdx.x, w = tid >> 6, lane = tid & 63;
  const int fr = lane & 15, kg = lane >> 4;
  const int rbase = b * LLEN + c * QC;
  const size_t rbase2 = ((size_t)bh << 11) + c * QC;
  __shared__ float lc[QC], rc2[QC];
  __shared__ float wtot[2];
  float a = 1.f, la = 0.f;
  if (tid < QC) { a = al[(size_t)bh * LLEN + c * QC + tid]; la = __logf(a); }
  float s = la;
#pragma unroll
  for (int o = 1; o < 64; o <<= 1) { float t2 = __shfl_up(s, o); if (lane >= o) s += t2; }
  if (tid < QC && lane == 63) wtot[w] = s;
  __syncthreads();
  if (tid < QC) lc[tid] = s + ((w == 1) ? wtot[0] : 0.f);
  __syncthreads();
  bf16x8 cf[2][2];
#pragma unroll
  for (int fi = 0; fi < 2; ++fi) {
    const int t = w * 32 + fi * 16 + fr;
    float ss = 0.f;
#pragma unroll
    for (int kk = 0; kk < 2; ++kk) {
      const uint4 v = *(const uint4*)(xp2 + (rbase2 + t) * XP2LD + 64 + kk * 32 + kg * 8);
      cf[fi][kk] = *(const bf16x8*)&v;
      const unsigned short* cs = (const unsigned short*)&v;
#pragma unroll
      for (int q = 0; q < 8; ++q) { const float cc = bf2f(cs[q]); ss = fmaf(cc, cc, ss); }
    }
    ss += __shfl_xor(ss, 16);
    ss += __shfl_xor(ss, 32);
    if (kg == 0) rc2[t] = 1.f / fmaxf(sqrtf(ss), 1e-12f);
  }
  bf16x8 hf[4][2];
#pragma unroll
  for (int fj = 0; fj < 4; ++fj)
#pragma unroll
    for (int kk = 0; kk < 2; ++kk) {
      const uint4 v = *(const uint4*)(Hbuf + ((size_t)blk * 64 + fj * 16 + fr) * 64 + kk * 32 + kg * 8);
      hf[fj][kk] = *(const bf16x8*)&v;
    }
  __syncthreads();
  f32x4 y[2][4] = {};
#pragma unroll
  for (int kk = 0; kk < 2; ++kk)
#pragma unroll
    for (int fi = 0; fi < 2; ++fi)
#pragma unroll
      for (int fj = 0; fj < 4; ++fj)
        y[fi][fj] = __builtin_amdgcn_mfma_f32_16x16x32_bf16(cf[fi][kk], hf[fj][kk], y[fi][fj], 0, 0, 0);
#pragma unroll
  for (int fi = 0; fi < 2; ++fi)
#pragma unroll
    for (int fj = 0; fj < 4; ++fj)
#pragma unroll
      for (int r = 0; r < 4; ++r) {
        const int t = w * 32 + fi * 16 + kg * 4 + r;
        const int d = fj * 16 + fr;
        const float scl = rc2[t] * __expf(lc[t]);
        const size_t rowg = (size_t)(rbase + t);
        const float yv = y[fi][fj][r] * scl + bf2f(xz[rowg * N2 + h * DH + d]);
        const float zv = bf2f(xz[rowg * N2 + DI + h * DH + d]);
        const float g = yv * (zv / (1.f + __expf(-zv)));
        xcg[rowg * DI + h * DH + d] = f2bf(g);
      }
}

extern "C" void kernel_launch(void* const* d_in, const int* in_sizes, int n_in,
                              void* d_out, int out_size, void* d_ws, size_t ws_size,
                              hipStream_t stream) {
  const float* hs     = (const float*)d_in[0];
  const float* norm_w = (const float*)d_in[1];
  const float* in_w   = (const float*)d_in[2];
  const float* in_b   = (const float*)d_in[3];
  const float* cw     = (const float*)d_in[4];
  const float* cb     = (const float*)d_in[5];
  const float* xw     = (const float*)d_in[6];
  const float* xb     = (const float*)d_in[7];
  const float* A_log  = (const float*)d_in[8];
  const float* l2ab   = (const float*)d_in[9];
  const float* l2b    = (const float*)d_in[10];
  const float* se     = (const float*)d_in[11];
  const float* ow     = (const float*)d_in[12];
  const float* ob     = (const float*)d_in[13];
  const float* rg     = (const float*)d_in[14];
  float* out = (float*)d_out;

  char* ws = (char*)d_ws;
  // layout (~169 MB):
  //   0          xnorm / xcg bf16 (33.5 MB)
  //   33554432   wA bf16 (12.58 MB) -> Hbuf after in_proj
  //   46137344   wX bf16 (9.83 MB)
  //   55967744   wO bf16 (6.29 MB)
  //   62259200   xz bf16 8192x3072 (50.3 MB; x-half reused for Y_intra)
  //   112590848  xp2 bf16 head-blocked 96x2048x136 (53.5 MB)
  //   166068224  xmean fp32 (786 KB)
  //   166854656  al fp32 (786 KB)
  //   167641088  Dc fp32 (6 KB)
  //   167647232  hc fp32 (384 B)
  //   167651328  dtbuf fp32 (786 KB)
  unsigned short* xnorm = (unsigned short*)(ws);
  unsigned short* wA    = (unsigned short*)(ws + 33554432ull);
  unsigned short* wX    = (unsigned short*)(ws + 46137344ull);
  unsigned short* wO    = (unsigned short*)(ws + 55967744ull);
  unsigned short* xz    = (unsigned short*)(ws + 62259200ull);
  unsigned short* xp2   = (unsigned short*)(ws + 112590848ull);
  float* xmean          = (float*)(ws + 166068224ull);
  float* al             = (float*)(ws + 166854656ull);
  float* Dc             = (float*)(ws + 167641088ull);
  float* hc             = (float*)(ws + 167647232ull);
  float* dtbuf          = (float*)(ws + 167651328ull);
  unsigned short* xcg   = xnorm;
  unsigned short* Hbuf  = wA;

  // fused front: weight convert (56064 blocks) + RMSNorm (8192) + hc (1)
  k_pre<<<WBLK + MROWS + 1, 256, 0, stream>>>(in_w, wA, xw, wX, ow, wO,
                                              hs, norm_w, xnorm,
                                              A_log, l2ab, l2b, se, hc);
  // in_proj: 64 x 12 = 768 blocks, bf16 out
  k_gemm6<1><<<768, 512, 0, stream>>>(xnorm, wA, in_b, xz, nullptr, nullptr,
                                      nullptr, DMODEL, 12, N2, N2);
  // conv + silu + xmean
  k_dwconv<<<(MROWS / 4) * 192 / 256, 256, 0, stream>>>(xz, cw, cb, xcg, xmean);
  // x_proj: 64 x 13 = 832 blocks; head-blocked xp2 (stride 136) + fp32 dtbuf
  k_gemm6<3><<<832, 512, 0, stream>>>(xcg, wX, xb, xp2, nullptr, nullptr,
                                      dtbuf, DI, 13, NP, 0);
  // alpha (coalesced, tiny)
  k_alpha<<<(BB * NH * LLEN) / 256, 256, 0, stream>>>(dtbuf, xmean, hc, al);
  // chunked scan
  k_chunk1<<<BB * NH * NCHUNK, 256, 0, stream>>>(xp2, xcg, al, xz, Hbuf, Dc);
  k_carry<<<BB * NH, 256, 0, stream>>>(Hbuf, Dc);
  k_chunk2<<<BB * NH * NCHUNK, 256, 0, stream>>>(xp2, al, Hbuf, xz, xcg);
  // out_proj: 64 x 8 = 512 blocks, fp32 + residual
  k_gemm6<2><<<512, 512, 0, stream>>>(xcg, wO, ob, out, hs, rg,
                                      nullptr, DI, 8, DMODEL, DMODEL);
}

// Round 15
// 417.763 us; speedup vs baseline: 1.2722x; 1.0599x over previous
//
#include <hip/hip_runtime.h>
#include <stdint.h>

// Problem constants
#define BB 4
#define LLEN 2048
#define DMODEL 2048
#define NH 24
#define DH 64
#define SS 64
#define DI 1536          // NH*DH
#define N2 3072          // 2*DI
#define NP 3096          // NH*(1+2*S)
#define NP_PAD 3200      // weight rows padded (zero rows 3096..3199)
#define MROWS 8192       // BB*LLEN
#define NCHUNK 16
#define QC 128           // chunk length
// xp2 row stride: 136 elems = 272B = 17*16B (non-power-of-2; see r12 note).
#define XP2LD 136
#define WBLK 56064       // weight-convert blocks in k_pre

using bf16x8 = __bf16 __attribute__((ext_vector_type(8)));
using f32x4  = float __attribute__((ext_vector_type(4)));

__device__ __forceinline__ unsigned short f2bf(float f) {
  union { float f; unsigned int u; } v; v.f = f;
  unsigned int u = v.u + 0x7fffu + ((v.u >> 16) & 1u);
  return (unsigned short)(u >> 16);
}
__device__ __forceinline__ float bf2f(unsigned short h) {
  union { unsigned int u; float f; } v; v.u = ((unsigned int)h) << 16;
  return v.f;
}

__device__ __forceinline__ void gload16(const void* g, void* l) {
  __builtin_amdgcn_global_load_lds(
    reinterpret_cast<const __attribute__((address_space(1))) void*>(reinterpret_cast<uintptr_t>(g)),
    reinterpret_cast<__attribute__((address_space(3))) void*>((uint32_t)(reinterpret_cast<uintptr_t>(l))),
    16, 0, 0);
}

// ---------------- fused front kernel: weight conversion + RMSNorm + hc table ---
__global__ __launch_bounds__(256) void k_pre(
    const float* __restrict__ in_w, unsigned short* __restrict__ wA,
    const float* __restrict__ xw, unsigned short* __restrict__ wX,
    const float* __restrict__ ow, unsigned short* __restrict__ wO,
    const float* __restrict__ hs, const float* __restrict__ norm_w,
    unsigned short* __restrict__ xnorm,
    const float* __restrict__ A_log, const float* __restrict__ l2ab,
    const float* __restrict__ l2b, const float* __restrict__ se,
    float* __restrict__ hc) {
  const int blk = blockIdx.x;
  const int t = threadIdx.x;
  if (blk < WBLK) {
    int i = blk * 256 + t;
    if (i < N2 * DMODEL) { wA[i] = f2bf(in_w[i]); return; }
    i -= N2 * DMODEL;
    if (i < NP_PAD * DI) { wX[i] = (i < NP * DI) ? f2bf(xw[i]) : (unsigned short)0; return; }
    i -= NP_PAD * DI;
    wO[i] = f2bf(ow[i]);
    return;
  }
  if (blk == WBLK + MROWS) {
    if (t < NH) {
      hc[t]          = fminf(fmaxf(A_log[t], -2.3f), -0.01f);
      hc[NH + t]     = exp2f(fminf(fmaxf(l2b[t], -2.f), 2.f));
      hc[2 * NH + t] = 1.f - exp2f(fminf(fmaxf(l2ab[t], -3.32f), -0.015f));
      hc[3 * NH + t] = 1.f / (se[t] + 1e-6f);
    }
    return;
  }
  const int row = blk - WBLK;
  const float* x = hs + (size_t)row * DMODEL;
  float4 v0 = reinterpret_cast<const float4*>(x)[t * 2 + 0];
  float4 v1 = reinterpret_cast<const float4*>(x)[t * 2 + 1];
  float ss = v0.x * v0.x + v0.y * v0.y + v0.z * v0.z + v0.w * v0.w +
             v1.x * v1.x + v1.y * v1.y + v1.z * v1.z + v1.w * v1.w;
#pragma unroll
  for (int o = 32; o; o >>= 1) ss += __shfl_xor(ss, o);
  __shared__ float red[4];
  if ((t & 63) == 0) red[t >> 6] = ss;
  __syncthreads();
  ss = red[0] + red[1] + red[2] + red[3];
  const float r = rsqrtf(ss * (1.0f / DMODEL) + 1.1920928955078125e-07f);
  float4 w0 = reinterpret_cast<const float4*>(norm_w)[t * 2 + 0];
  float4 w1 = reinterpret_cast<const float4*>(norm_w)[t * 2 + 1];
  union { unsigned short u[8]; uint4 v; } pk;
  pk.u[0] = f2bf(v0.x * r * w0.x); pk.u[1] = f2bf(v0.y * r * w0.y);
  pk.u[2] = f2bf(v0.z * r * w0.z); pk.u[3] = f2bf(v0.w * r * w0.w);
  pk.u[4] = f2bf(v1.x * r * w1.x); pk.u[5] = f2bf(v1.y * r * w1.y);
  pk.u[6] = f2bf(v1.z * r * w1.z); pk.u[7] = f2bf(v1.w * r * w1.w);
  *reinterpret_cast<uint4*>(xnorm + (size_t)row * DMODEL + t * 8) = pk.v;
}

// ---------------- 2-blocks/CU drift bf16 NT GEMM (128x192 tile, BK=64) ---------
// LDS = 2 x (A 16KB + B 24KB) = 80KB exactly -> 2 blocks/CU (16 waves/CU in two
// INDEPENDENT barrier domains: one block's MFMA covers the other's vmcnt/barrier
// drain — the cross-block TLP that m97/m114 relied on; every kernel since r4 had
// 1 block/CU). Dist-1 prefetch, vmcnt(0) at tile boundary (drain covered by
// sibling block). 8 waves (2M x 4N), per-wave 64x48, acc 4x3.
// EPI 1: bf16 C. EPI 2: fp32 C = resid + rg*(acc+bias). EPI 3: xp2 + dtbuf.
template <int EPI>
__global__ __launch_bounds__(512, 4)
void k_gemm7(const unsigned short* __restrict__ A, const unsigned short* __restrict__ B,
             const float* __restrict__ bias, void* __restrict__ Cv,
             const float* __restrict__ resid, const float* __restrict__ gatep,
             float* __restrict__ dtbuf,
             int K, int NT_N, int Nout, int ldc) {
  constexpr int AELEM = 128 * 64;        // 16KB
  constexpr int BELEM = 192 * 64;        // 24KB
  constexpr int BUFE = AELEM + BELEM;    // 20480 elems = 40KB
  __shared__ alignas(16) unsigned short sm[2 * BUFE];  // 80KB
  const int tid = threadIdx.x;
  const int lane = tid & 63, wid = tid >> 6;
  const int wm = wid >> 2, wn = wid & 3;
  const int fr = lane & 15, kg = lane >> 4;
  const int nwg = gridDim.x;
  const int wg = ((int)blockIdx.x & 7) * (nwg >> 3) + ((int)blockIdx.x >> 3);
  const int m0 = (wg / NT_N) * 128, n0 = (wg % NT_N) * 192;
  const int NT = K >> 6;

  // pre-swizzled per-lane staging sources (granule q ^= row&7)
  const unsigned short* asrc[2];
  const unsigned short* bsrc[3];
#pragma unroll
  for (int li = 0; li < 2; ++li) {
    const int gi = li * 512 + tid, r = gi >> 3, q = gi & 7;
    asrc[li] = A + (size_t)(m0 + r) * K + ((q ^ (r & 7)) << 3);
  }
#pragma unroll
  for (int li = 0; li < 3; ++li) {
    const int gi = li * 512 + tid, r = gi >> 3, q = gi & 7;
    bsrc[li] = B + (size_t)(n0 + r) * K + ((q ^ (r & 7)) << 3);
  }
  const int wlds = wid * 64;

#define STG7(buf, ko)                                                          \
  { unsigned short* da_ = sm + (buf) * BUFE;                                   \
    gload16(asrc[0] + (ko), da_ + ((0 * 512 + wlds) << 3));                    \
    gload16(asrc[1] + (ko), da_ + ((1 * 512 + wlds) << 3));                    \
    unsigned short* db_ = sm + (buf) * BUFE + AELEM;                           \
    gload16(bsrc[0] + (ko), db_ + ((0 * 512 + wlds) << 3));                    \
    gload16(bsrc[1] + (ko), db_ + ((1 * 512 + wlds) << 3));                    \
    gload16(bsrc[2] + (ko), db_ + ((2 * 512 + wlds) << 3)); }

#define ARD7(bufp, f, kk)                                                      \
  (*(const bf16x8*)((bufp) + (wm * 64 + (f) * 16 + fr) * 64 +                  \
      ((((kk) * 4 + kg) ^ (fr & 7)) << 3)))
#define BRD7(bufp, nf, kk)                                                     \
  (*(const bf16x8*)((bufp) + AELEM + (wn * 48 + (nf) * 16 + fr) * 64 +         \
      ((((kk) * 4 + kg) ^ (fr & 7)) << 3)))

  f32x4 acc[4][3] = {};

  STG7(0, 0)
  asm volatile("s_waitcnt vmcnt(0)" ::: "memory");
  __builtin_amdgcn_s_barrier();

  for (int t = 0; t < NT; ++t) {
    unsigned short* bc = sm + (t & 1) * BUFE;
    if (t + 1 < NT) STG7((t & 1) ^ 1, (t + 1) << 6)

    bf16x8 bfv[3][2], af[4][2];
#pragma unroll
    for (int nf = 0; nf < 3; ++nf) {
      bfv[nf][0] = BRD7(bc, nf, 0);
      bfv[nf][1] = BRD7(bc, nf, 1);
    }
#pragma unroll
    for (int mf = 0; mf < 4; ++mf) {
      af[mf][0] = ARD7(bc, mf, 0);
      af[mf][1] = ARD7(bc, mf, 1);
    }
    __builtin_amdgcn_sched_barrier(0);
    asm volatile("s_waitcnt lgkmcnt(0)" ::: "memory");
    __builtin_amdgcn_sched_barrier(0);
    __builtin_amdgcn_s_setprio(1);
#pragma unroll
    for (int mf = 0; mf < 4; ++mf)
#pragma unroll
      for (int nf = 0; nf < 3; ++nf)
#pragma unroll
        for (int kk = 0; kk < 2; ++kk)
          acc[mf][nf] = __builtin_amdgcn_mfma_f32_16x16x32_bf16(
              af[mf][kk], bfv[nf][kk], acc[mf][nf], 0, 0, 0);
    __builtin_amdgcn_s_setprio(0);

    asm volatile("s_waitcnt vmcnt(0)" ::: "memory");
    __builtin_amdgcn_s_barrier();
  }

  // epilogue
  float* Cf = (float*)Cv;
  unsigned short* Ch = (unsigned short*)Cv;
  const float rg = (EPI == 2) ? gatep[0] : 0.f;
#pragma unroll
  for (int nf = 0; nf < 3; ++nf) {
    const int col = n0 + wn * 48 + nf * 16 + fr;
    if (col >= Nout) continue;
    const float bv = bias[col];
    if (EPI == 3) {
      const int h = col / 129;
      const int e = col - h * 129;
      if (e == 0) {
#pragma unroll
        for (int mf = 0; mf < 4; ++mf) {
          const int rowb = m0 + wm * 64 + mf * 16 + kg * 4;
#pragma unroll
          for (int r = 0; r < 4; ++r) {
            const int row = rowb + r;
            const size_t r2 = (((size_t)((row >> 11) * NH + h)) << 11) + (row & (LLEN - 1));
            dtbuf[r2] = acc[mf][nf][r] + bv;
          }
        }
      } else {
        const int ep = e - 1;
#pragma unroll
        for (int mf = 0; mf < 4; ++mf) {
          const int rowb = m0 + wm * 64 + mf * 16 + kg * 4;
#pragma unroll
          for (int r = 0; r < 4; ++r) {
            const int row = rowb + r;
            const size_t dst =
                (((size_t)((row >> 11) * NH + h) << 11) + (row & (LLEN - 1))) * XP2LD + ep;
            Ch[dst] = f2bf(acc[mf][nf][r] + bv);
          }
        }
      }
    } else {
#pragma unroll
      for (int mf = 0; mf < 4; ++mf) {
        const int rowb = m0 + wm * 64 + mf * 16 + kg * 4;
#pragma unroll
        for (int r = 0; r < 4; ++r) {
          const size_t o = (size_t)(rowb + r) * ldc + col;
          float v = acc[mf][nf][r] + bv;
          if (EPI == 1) {
            Ch[o] = f2bf(v);
          } else {
            v = resid[o] + rg * v;
            Cf[o] = v;
          }
        }
      }
    }
  }
#undef STG7
#undef ARD7
#undef BRD7
}

// ---------------- alpha: dtbuf + xmean + hc -> al (coalesced, tiny) ------------
__global__ __launch_bounds__(256) void k_alpha(const float* __restrict__ dtbuf,
                                               const float* __restrict__ xmean,
                                               const float* __restrict__ hc,
                                               float* __restrict__ al) {
  const int i = blockIdx.x * 256 + threadIdx.x;   // < BB*NH*LLEN
  const int h = (i >> 11) % NH;
  const float dt = dtbuf[i];
  const float sp = (dt > 20.f) ? dt : log1pf(expf(dt));
  const float one_a = 1.f - expf(hc[h] * sp);
  const float xm = xmean[i];
  const float pe = one_a * one_a * xm * xm * (1.f / 64.f);
  const float boost = fmaxf(tanhf(hc[NH + h] * pe * hc[3 * NH + h]), 0.f);
  const float ab = hc[2 * NH + h];
  al[i] = fminf(fmaxf(ab + (1.f - ab) * boost, 0.01f), 0.999f);
}

// ---------------- depthwise causal conv(4) + silu + per-head x-mean ------------
__global__ __launch_bounds__(256) void k_dwconv(const unsigned short* __restrict__ xz,
                                                const float* __restrict__ cw,
                                                const float* __restrict__ cb,
                                                unsigned short* __restrict__ out,
                                                float* __restrict__ xmean) {
  const int idx = blockIdx.x * 256 + threadIdx.x;  // < (MROWS/4)*192
  const int c0 = (idx % 192) * 8;
  const int bl0 = (idx / 192) * 4;
  const int lpos0 = bl0 & (LLEN - 1);
  float w[8][4];
#pragma unroll
  for (int j = 0; j < 8; ++j) {
    const float4 wv = *(const float4*)(cw + (c0 + j) * 4);
    w[j][0] = wv.x; w[j][1] = wv.y; w[j][2] = wv.z; w[j][3] = wv.w;
  }
  float xr[7][8];
#pragma unroll
  for (int m = 0; m < 7; ++m) {
    uint4 xv = make_uint4(0u, 0u, 0u, 0u);
    if (lpos0 - 3 + m >= 0)
      xv = *(const uint4*)(xz + (size_t)(bl0 - 3 + m) * N2 + c0);
    const unsigned short* xs = (const unsigned short*)&xv;
#pragma unroll
    for (int j = 0; j < 8; ++j) xr[m][j] = bf2f(xs[j]);
  }
  const float4 cb0 = *(const float4*)(cb + c0);
  const float4 cb1 = *(const float4*)(cb + c0 + 4);
  const float cbv[8] = {cb0.x, cb0.y, cb0.z, cb0.w, cb1.x, cb1.y, cb1.z, cb1.w};
  float hsum[4] = {0.f, 0.f, 0.f, 0.f};
#pragma unroll
  for (int t4 = 0; t4 < 4; ++t4) {
    union { unsigned short u[8]; uint4 v; } pk;
#pragma unroll
    for (int j = 0; j < 8; ++j) {
      float a = cbv[j];
#pragma unroll
      for (int k = 0; k < 4; ++k) a = fmaf(w[j][k], xr[t4 + k][j], a);
      a = a / (1.f + __expf(-a));
      hsum[t4] += a;
      pk.u[j] = f2bf(a);
    }
    *(uint4*)(out + (size_t)(bl0 + t4) * DI + c0) = pk.v;
  }
#pragma unroll
  for (int o = 1; o < 8; o <<= 1) {
#pragma unroll
    for (int t4 = 0; t4 < 4; ++t4) hsum[t4] += __shfl_xor(hsum[t4], o);
  }
  if ((threadIdx.x & 7) == 0) {
    const int h = (idx % 192) >> 3;
    const int b = bl0 >> 11;
    float4 xm = make_float4(hsum[0] * (1.f / 64.f), hsum[1] * (1.f / 64.f),
                            hsum[2] * (1.f / 64.f), hsum[3] * (1.f / 64.f));
    *(float4*)(xmean + (((size_t)(b * NH + h)) << 11) + lpos0) = xm;
  }
}

// ---------------- chunked scan, stage 1: intra-chunk Y + local state -----------
__global__ __launch_bounds__(256) void k_chunk1(
    const unsigned short* __restrict__ xp2, const unsigned short* __restrict__ xcg,
    const float* __restrict__ al, unsigned short* __restrict__ xz,
    unsigned short* __restrict__ Hbuf, float* __restrict__ Dc) {
  const int blk = blockIdx.x;          // bh*16 + c
  const int bh = blk >> 4, c = blk & 15;
  const int b = bh / NH, h = bh % NH;
  const int tid = threadIdx.x, w = tid >> 6, lane = tid & 63;
  const int fr = lane & 15, kg = lane >> 4;
  const int rbase = b * LLEN + c * QC;
  const size_t rbase2 = ((size_t)bh << 11) + c * QC;

  __shared__ float lc[QC], ia[QC], escl[QC], rbA[QC], rcC[QC];
  __shared__ float wtot[2];
  __shared__ alignas(16) unsigned short XT[64][152];
  __shared__ alignas(16) unsigned short BsT[64][152];
  __shared__ alignas(16) unsigned short Pt[128][88];

  float a = 1.f, la = 0.f;
  if (tid < QC) { a = al[(size_t)bh * LLEN + c * QC + tid]; la = __logf(a); }
  float s = la;
#pragma unroll
  for (int o = 1; o < 64; o <<= 1) { float t2 = __shfl_up(s, o); if (lane >= o) s += t2; }
  if (tid < QC && lane == 63) wtot[w] = s;
  __syncthreads();
  if (tid < QC) { lc[tid] = s + ((w == 1) ? wtot[0] : 0.f); ia[tid] = 1.f - a; }
  __syncthreads();
  const float lcE = lc[QC - 1];
  if (tid < QC) escl[tid] = __expf(lcE - lc[tid]);
  if (tid == 0) Dc[blk] = __expf(lcE);
  __syncthreads();

  {
    const int r8 = tid >> 3, q8 = tid & 7;
#pragma unroll
    for (int it = 0; it < 4; ++it) {
      const int u = it * 32 + r8;
      const uint4 xv = *(const uint4*)(xcg + (size_t)(rbase + u) * DI + h * DH + q8 * 8);
      const unsigned short* xs = (const unsigned short*)&xv;
#pragma unroll
      for (int j = 0; j < 8; ++j) XT[q8 * 8 + j][u] = xs[j];
      const size_t prow = (rbase2 + u) * XP2LD;
      const uint4 bv = *(const uint4*)(xp2 + prow + q8 * 8);
      const uint4 cv = *(const uint4*)(xp2 + prow + 64 + q8 * 8);
      const unsigned short* bsv = (const unsigned short*)&bv;
      const unsigned short* csv = (const unsigned short*)&cv;
      float bb[8], sb = 0.f, sc2 = 0.f;
#pragma unroll
      for (int j = 0; j < 8; ++j) {
        bb[j] = bf2f(bsv[j]);
        sb = fmaf(bb[j], bb[j], sb);
        const float cc = bf2f(csv[j]);
        sc2 = fmaf(cc, cc, sc2);
      }
      sb += __shfl_xor(sb, 1); sb += __shfl_xor(sb, 2); sb += __shfl_xor(sb, 4);
      sc2 += __shfl_xor(sc2, 1); sc2 += __shfl_xor(sc2, 2); sc2 += __shfl_xor(sc2, 4);
      const float rcpB = 1.f / fmaxf(sqrtf(sb), 1e-12f);
      const float e = escl[u] * ia[u] * rcpB;
#pragma unroll
      for (int j = 0; j < 8; ++j) BsT[q8 * 8 + j][u] = f2bf(bb[j] * e);
      if (q8 == 0) {
        rbA[u] = ia[u] * rcpB;
        rcC[u] = 1.f / fmaxf(sqrtf(sc2), 1e-12f);
      }
    }
  }
  __syncthreads();

  bf16x8 cf[2][2];
#pragma unroll
  for (int fi = 0; fi < 2; ++fi)
#pragma unroll
    for (int kk = 0; kk < 2; ++kk) {
      const int t = w * 32 + fi * 16 + fr;
      const uint4 v = *(const uint4*)(xp2 + (rbase2 + t) * XP2LD + 64 + kk * 32 + kg * 8);
      cf[fi][kk] = *(const bf16x8*)&v;
    }

  float lct[2][4], rct[2][4];
#pragma unroll
  for (int fi = 0; fi < 2; ++fi)
#pragma unroll
    for (int r = 0; r < 4; ++r) {
      const int t = w * 32 + fi * 16 + kg * 4 + r;
      lct[fi][r] = lc[t];
      rct[fi][r] = rcC[t];
    }

  f32x4 yacc[2][4] = {};
  f32x4 hacc[4] = {};
#pragma unroll
  for (int ut = 0; ut < 2; ++ut) {
    f32x4 g[2][4] = {};
#pragma unroll
    for (int kk = 0; kk < 2; ++kk)
#pragma unroll
      for (int fj = 0; fj < 4; ++fj) {
        const int u = ut * 64 + fj * 16 + fr;
        const uint4 v = *(const uint4*)(xp2 + (rbase2 + u) * XP2LD + kk * 32 + kg * 8);
        const bf16x8 bfrag = *(const bf16x8*)&v;
#pragma unroll
        for (int fi = 0; fi < 2; ++fi)
          g[fi][fj] = __builtin_amdgcn_mfma_f32_16x16x32_bf16(cf[fi][kk], bfrag, g[fi][fj], 0, 0, 0);
      }
#pragma unroll
    for (int fi = 0; fi < 2; ++fi)
#pragma unroll
      for (int fj = 0; fj < 4; ++fj) {
        const int u = ut * 64 + fj * 16 + fr;
        const float lcu = lc[u], sbu = rbA[u];
#pragma unroll
        for (int r = 0; r < 4; ++r) {
          const int t = w * 32 + fi * 16 + kg * 4 + r;
          const float v = (t >= u) ? g[fi][fj][r] * __expf(lct[fi][r] - lcu) * sbu * rct[fi][r] : 0.f;
          Pt[t][fj * 16 + fr] = f2bf(v);
        }
      }
#pragma unroll
    for (int kk = 0; kk < 2; ++kk) {
      bf16x8 xf[4];
#pragma unroll
      for (int fj = 0; fj < 4; ++fj)
        xf[fj] = *(const bf16x8*)&XT[fj * 16 + fr][ut * 64 + kk * 32 + kg * 8];
      bf16x8 pf[2];
#pragma unroll
      for (int fi = 0; fi < 2; ++fi)
        pf[fi] = *(const bf16x8*)&Pt[w * 32 + fi * 16 + fr][kk * 32 + kg * 8];
#pragma unroll
      for (int fi = 0; fi < 2; ++fi)
#pragma unroll
        for (int fj = 0; fj < 4; ++fj)
          yacc[fi][fj] = __builtin_amdgcn_mfma_f32_16x16x32_bf16(pf[fi], xf[fj], yacc[fi][fj], 0, 0, 0);
      const bf16x8 xh = *(const bf16x8*)&XT[w * 16 + fr][ut * 64 + kk * 32 + kg * 8];
#pragma unroll
      for (int fi = 0; fi < 4; ++fi) {
        const bf16x8 bs = *(const bf16x8*)&BsT[fi * 16 + fr][ut * 64 + kk * 32 + kg * 8];
        hacc[fi] = __builtin_amdgcn_mfma_f32_16x16x32_bf16(bs, xh, hacc[fi], 0, 0, 0);
      }
    }
  }
#pragma unroll
  for (int fi = 0; fi < 2; ++fi)
#pragma unroll
    for (int fj = 0; fj < 4; ++fj)
#pragma unroll
      for (int r = 0; r < 4; ++r) {
        const int t = w * 32 + fi * 16 + kg * 4 + r;
        const int d = fj * 16 + fr;
        xz[(size_t)(rbase + t) * N2 + h * DH + d] = f2bf(yacc[fi][fj][r]);
      }
  const int dcol = w * 16 + fr;
#pragma unroll
  for (int fi = 0; fi < 4; ++fi) {
    ushort4 pk;
    pk.x = f2bf(hacc[fi][0]); pk.y = f2bf(hacc[fi][1]);
    pk.z = f2bf(hacc[fi][2]); pk.w = f2bf(hacc[fi][3]);
    *(ushort4*)(Hbuf + ((size_t)blk * 64 + dcol) * 64 + fi * 16 + kg * 4) = pk;
  }
}

// ---------------- chunked scan, stage 2: carry across chunks (in place) --------
__global__ __launch_bounds__(256) void k_carry(unsigned short* __restrict__ Hbuf,
                                               const float* __restrict__ Dc) {
  const int bh = blockIdx.x, tid = threadIdx.x;
  float carry[16];
#pragma unroll
  for (int j = 0; j < 16; ++j) carry[j] = 0.f;
  for (int c = 0; c < NCHUNK; ++c) {
    unsigned short* p = Hbuf + (((size_t)(bh * NCHUNK + c)) << 12) + tid * 16;
    const uint4 v0 = *(const uint4*)(p);
    const uint4 v1 = *(const uint4*)(p + 8);
    const unsigned short* hs0 = (const unsigned short*)&v0;
    const unsigned short* hs1 = (const unsigned short*)&v1;
    float hl[16];
#pragma unroll
    for (int j = 0; j < 8; ++j) { hl[j] = bf2f(hs0[j]); hl[8 + j] = bf2f(hs1[j]); }
    uint4 o0, o1;
    unsigned short* os0 = (unsigned short*)&o0;
    unsigned short* os1 = (unsigned short*)&o1;
#pragma unroll
    for (int j = 0; j < 8; ++j) { os0[j] = f2bf(carry[j]); os1[j] = f2bf(carry[8 + j]); }
    *(uint4*)(p) = o0;
    *(uint4*)(p + 8) = o1;
    const float dc = Dc[bh * NCHUNK + c];
#pragma unroll
    for (int j = 0; j < 16; ++j) carry[j] = fmaf(dc, carry[j], hl[j]);
  }
}

// ---------------- chunked scan, stage 3: inter-chunk Y + fused gating ----------
__global__ __launch_bounds__(256) void k_chunk2(
    const unsigned short* __restrict__ xp2, const float* __restrict__ al,
    const unsigned short* __restrict__ Hbuf, const unsigned short* __restrict__ xz,
    unsigned short* __restrict__ xcg) {
  const int blk = blockIdx.x;
  const int bh = blk >> 4, c = blk & 15;
  const int b = bh / NH, h = bh % NH;
  const int tid = threadIdx.x, w = tid >> 6, lane = tid & 63;
  const int fr = lane & 15, kg = lane >> 4;
  const int rbase = b * LLEN + c * QC;
  const size_t rbase2 = ((size_t)bh << 11) + c * QC;
  __shared__ float lc[QC], rc2[QC];
  __shared__ float wtot[2];
  float a = 1.f, la = 0.f;
  if (tid < QC) { a = al[(size_t)bh * LLEN + c * QC + tid]; la = __logf(a); }
  float s = la;
#pragma unroll
  for (int o = 1; o < 64; o <<= 1) { float t2 = __shfl_up(s, o); if (lane >= o) s += t2; }
  if (tid < QC && lane == 63) wtot[w] = s;
  __syncthreads();
  if (tid < QC) lc[tid] = s + ((w == 1) ? wtot[0] : 0.f);
  __syncthreads();
  bf16x8 cf[2][2];
#pragma unroll
  for (int fi = 0; fi < 2; ++fi) {
    const int t = w * 32 + fi * 16 + fr;
    float ss = 0.f;
#pragma unroll
    for (int kk = 0; kk < 2; ++kk) {
      const uint4 v = *(const uint4*)(xp2 + (rbase2 + t) * XP2LD + 64 + kk * 32 + kg * 8);
      cf[fi][kk] = *(const bf16x8*)&v;
      const unsigned short* cs = (const unsigned short*)&v;
#pragma unroll
      for (int q = 0; q < 8; ++q) { const float cc = bf2f(cs[q]); ss = fmaf(cc, cc, ss); }
    }
    ss += __shfl_xor(ss, 16);
    ss += __shfl_xor(ss, 32);
    if (kg == 0) rc2[t] = 1.f / fmaxf(sqrtf(ss), 1e-12f);
  }
  bf16x8 hf[4][2];
#pragma unroll
  for (int fj = 0; fj < 4; ++fj)
#pragma unroll
    for (int kk = 0; kk < 2; ++kk) {
      const uint4 v = *(const uint4*)(Hbuf + ((size_t)blk * 64 + fj * 16 + fr) * 64 + kk * 32 + kg * 8);
      hf[fj][kk] = *(const bf16x8*)&v;
    }
  __syncthreads();
  f32x4 y[2][4] = {};
#pragma unroll
  for (int kk = 0; kk < 2; ++kk)
#pragma unroll
    for (int fi = 0; fi < 2; ++fi)
#pragma unroll
      for (int fj = 0; fj < 4; ++fj)
        y[fi][fj] = __builtin_amdgcn_mfma_f32_16x16x32_bf16(cf[fi][kk], hf[fj][kk], y[fi][fj], 0, 0, 0);
#pragma unroll
  for (int fi = 0; fi < 2; ++fi)
#pragma unroll
    for (int fj = 0; fj < 4; ++fj)
#pragma unroll
      for (int r = 0; r < 4; ++r) {
        const int t = w * 32 + fi * 16 + kg * 4 + r;
        const int d = fj * 16 + fr;
        const float scl = rc2[t] * __expf(lc[t]);
        const size_t rowg = (size_t)(rbase + t);
        const float yv = y[fi][fj][r] * scl + bf2f(xz[rowg * N2 + h * DH + d]);
        const float zv = bf2f(xz[rowg * N2 + DI + h * DH + d]);
        const float g = yv * (zv / (1.f + __expf(-zv)));
        xcg[rowg * DI + h * DH + d] = f2bf(g);
      }
}

extern "C" void kernel_launch(void* const* d_in, const int* in_sizes, int n_in,
                              void* d_out, int out_size, void* d_ws, size_t ws_size,
                              hipStream_t stream) {
  const float* hs     = (const float*)d_in[0];
  const float* norm_w = (const float*)d_in[1];
  const float* in_w   = (const float*)d_in[2];
  const float* in_b   = (const float*)d_in[3];
  const float* cw     = (const float*)d_in[4];
  const float* cb     = (const float*)d_in[5];
  const float* xw     = (const float*)d_in[6];
  const float* xb     = (const float*)d_in[7];
  const float* A_log  = (const float*)d_in[8];
  const float* l2ab   = (const float*)d_in[9];
  const float* l2b    = (const float*)d_in[10];
  const float* se     = (const float*)d_in[11];
  const float* ow     = (const float*)d_in[12];
  const float* ob     = (const float*)d_in[13];
  const float* rg     = (const float*)d_in[14];
  float* out = (float*)d_out;

  char* ws = (char*)d_ws;
  // layout (~169 MB): same as r14
  unsigned short* xnorm = (unsigned short*)(ws);
  unsigned short* wA    = (unsigned short*)(ws + 33554432ull);
  unsigned short* wX    = (unsigned short*)(ws + 46137344ull);
  unsigned short* wO    = (unsigned short*)(ws + 55967744ull);
  unsigned short* xz    = (unsigned short*)(ws + 62259200ull);
  unsigned short* xp2   = (unsigned short*)(ws + 112590848ull);
  float* xmean          = (float*)(ws + 166068224ull);
  float* al             = (float*)(ws + 166854656ull);
  float* Dc             = (float*)(ws + 167641088ull);
  float* hc             = (float*)(ws + 167647232ull);
  float* dtbuf          = (float*)(ws + 167651328ull);
  unsigned short* xcg   = xnorm;
  unsigned short* Hbuf  = wA;

  // fused front: weight convert (56064 blocks) + RMSNorm (8192) + hc (1)
  k_pre<<<WBLK + MROWS + 1, 256, 0, stream>>>(in_w, wA, xw, wX, ow, wO,
                                              hs, norm_w, xnorm,
                                              A_log, l2ab, l2b, se, hc);
  // in_proj: 64 x 16 = 1024 blocks (2 exact rounds at 2 blocks/CU), bf16 out
  k_gemm7<1><<<1024, 512, 0, stream>>>(xnorm, wA, in_b, xz, nullptr, nullptr,
                                       nullptr, DMODEL, 16, N2, N2);
  // conv + silu + xmean
  k_dwconv<<<(MROWS / 4) * 192 / 256, 256, 0, stream>>>(xz, cw, cb, xcg, xmean);
  // x_proj: 64 x 17 = 1088 blocks; head-blocked xp2 (stride 136) + fp32 dtbuf
  // (17th n-tile reads rows 3200..3263 past wX into wO — masked cols only)
  k_gemm7<3><<<1088, 512, 0, stream>>>(xcg, wX, xb, xp2, nullptr, nullptr,
                                       dtbuf, DI, 17, NP, 0);
  // alpha (coalesced, tiny)
  k_alpha<<<(BB * NH * LLEN) / 256, 256, 0, stream>>>(dtbuf, xmean, hc, al);
  // chunked scan
  k_chunk1<<<BB * NH * NCHUNK, 256, 0, stream>>>(xp2, xcg, al, xz, Hbuf, Dc);
  k_carry<<<BB * NH, 256, 0, stream>>>(Hbuf, Dc);
  k_chunk2<<<BB * NH * NCHUNK, 256, 0, stream>>>(xp2, al, Hbuf, xz, xcg);
  // out_proj: 64 x 11 = 704 blocks, fp32 + residual
  // (11th n-tile reads rows 2048..2111 past wO into xz — masked cols only)
  k_gemm7<2><<<704, 512, 0, stream>>>(xcg, wO, ob, out, hs, rg,
                                      nullptr, DI, 11, DMODEL, DMODEL);
}

// Round 16
// 413.424 us; speedup vs baseline: 1.2855x; 1.0105x over previous
//
#include <hip/hip_runtime.h>
#include <stdint.h>

// Problem constants
#define BB 4
#define LLEN 2048
#define DMODEL 2048
#define NH 24
#define DH 64
#define SS 64
#define DI 1536          // NH*DH
#define N2 3072          // 2*DI
#define NP 3096          // NH*(1+2*S)
#define NP_PAD 3200      // weight rows padded (zero rows 3096..3199)
#define MROWS 8192       // BB*LLEN
#define NCHUNK 16
#define QC 128           // chunk length
// xp2 row stride: 136 elems = 272B = 17*16B (non-power-of-2; see r12 note).
#define XP2LD 136
#define WBLK 56064       // weight-convert blocks in k_pre

using bf16x8 = __bf16 __attribute__((ext_vector_type(8)));
using f32x4  = float __attribute__((ext_vector_type(4)));

__device__ __forceinline__ unsigned short f2bf(float f) {
  union { float f; unsigned int u; } v; v.f = f;
  unsigned int u = v.u + 0x7fffu + ((v.u >> 16) & 1u);
  return (unsigned short)(u >> 16);
}
__device__ __forceinline__ float bf2f(unsigned short h) {
  union { unsigned int u; float f; } v; v.u = ((unsigned int)h) << 16;
  return v.f;
}

__device__ __forceinline__ void gload16(const void* g, void* l) {
  __builtin_amdgcn_global_load_lds(
    reinterpret_cast<const __attribute__((address_space(1))) void*>(reinterpret_cast<uintptr_t>(g)),
    reinterpret_cast<__attribute__((address_space(3))) void*>((uint32_t)(reinterpret_cast<uintptr_t>(l))),
    16, 0, 0);
}

// ---------------- fused front kernel: weight conversion + RMSNorm + hc table ---
__global__ __launch_bounds__(256) void k_pre(
    const float* __restrict__ in_w, unsigned short* __restrict__ wA,
    const float* __restrict__ xw, unsigned short* __restrict__ wX,
    const float* __restrict__ ow, unsigned short* __restrict__ wO,
    const float* __restrict__ hs, const float* __restrict__ norm_w,
    unsigned short* __restrict__ xnorm,
    const float* __restrict__ A_log, const float* __restrict__ l2ab,
    const float* __restrict__ l2b, const float* __restrict__ se,
    float* __restrict__ hc) {
  const int blk = blockIdx.x;
  const int t = threadIdx.x;
  if (blk < WBLK) {
    int i = blk * 256 + t;
    if (i < N2 * DMODEL) { wA[i] = f2bf(in_w[i]); return; }
    i -= N2 * DMODEL;
    if (i < NP_PAD * DI) { wX[i] = (i < NP * DI) ? f2bf(xw[i]) : (unsigned short)0; return; }
    i -= NP_PAD * DI;
    wO[i] = f2bf(ow[i]);
    return;
  }
  if (blk == WBLK + MROWS) {
    if (t < NH) {
      hc[t]          = fminf(fmaxf(A_log[t], -2.3f), -0.01f);
      hc[NH + t]     = exp2f(fminf(fmaxf(l2b[t], -2.f), 2.f));
      hc[2 * NH + t] = 1.f - exp2f(fminf(fmaxf(l2ab[t], -3.32f), -0.015f));
      hc[3 * NH + t] = 1.f / (se[t] + 1e-6f);
    }
    return;
  }
  const int row = blk - WBLK;
  const float* x = hs + (size_t)row * DMODEL;
  float4 v0 = reinterpret_cast<const float4*>(x)[t * 2 + 0];
  float4 v1 = reinterpret_cast<const float4*>(x)[t * 2 + 1];
  float ss = v0.x * v0.x + v0.y * v0.y + v0.z * v0.z + v0.w * v0.w +
             v1.x * v1.x + v1.y * v1.y + v1.z * v1.z + v1.w * v1.w;
#pragma unroll
  for (int o = 32; o; o >>= 1) ss += __shfl_xor(ss, o);
  __shared__ float red[4];
  if ((t & 63) == 0) red[t >> 6] = ss;
  __syncthreads();
  ss = red[0] + red[1] + red[2] + red[3];
  const float r = rsqrtf(ss * (1.0f / DMODEL) + 1.1920928955078125e-07f);
  float4 w0 = reinterpret_cast<const float4*>(norm_w)[t * 2 + 0];
  float4 w1 = reinterpret_cast<const float4*>(norm_w)[t * 2 + 1];
  union { unsigned short u[8]; uint4 v; } pk;
  pk.u[0] = f2bf(v0.x * r * w0.x); pk.u[1] = f2bf(v0.y * r * w0.y);
  pk.u[2] = f2bf(v0.z * r * w0.z); pk.u[3] = f2bf(v0.w * r * w0.w);
  pk.u[4] = f2bf(v1.x * r * w1.x); pk.u[5] = f2bf(v1.y * r * w1.y);
  pk.u[6] = f2bf(v1.z * r * w1.z); pk.u[7] = f2bf(v1.w * r * w1.w);
  *reinterpret_cast<uint4*>(xnorm + (size_t)row * DMODEL + t * 8) = pk.v;
}

// ---------------- 2-blocks/CU drift bf16 NT GEMM (128 x NF*64 tile, BK=64) -----
// NF=3: BN=192, LDS 80KB. NF=2: BN=128, LDS 64KB. Both -> 2 blocks/CU (two
// independent barrier domains; cross-block TLP covers the vmcnt/barrier drain).
// 8 waves (2M x 4N), per-wave 64 x NF*16, acc 4xNF. nbase offsets the n-range
// (used for the x_proj tail tile at cols 3072..3199).
// EPI 1: bf16 C. EPI 2: fp32 C = resid + rg*(acc+bias). EPI 3: xp2 + dtbuf.
template <int EPI, int NF>
__global__ __launch_bounds__(512, 4)
void k_gemm7(const unsigned short* __restrict__ A, const unsigned short* __restrict__ B,
             const float* __restrict__ bias, void* __restrict__ Cv,
             const float* __restrict__ resid, const float* __restrict__ gatep,
             float* __restrict__ dtbuf, int nbase,
             int K, int NT_N, int Nout, int ldc) {
  constexpr int BN = NF * 64;
  constexpr int AELEM = 128 * 64;        // 16KB
  constexpr int BELEM = BN * 64;         // NF*8KB
  constexpr int BUFE = AELEM + BELEM;
  __shared__ alignas(16) unsigned short sm[2 * BUFE];
  const int tid = threadIdx.x;
  const int lane = tid & 63, wid = tid >> 6;
  const int wm = wid >> 2, wn = wid & 3;
  const int fr = lane & 15, kg = lane >> 4;
  const int nwg = gridDim.x;
  const int wg = ((int)blockIdx.x & 7) * (nwg >> 3) + ((int)blockIdx.x >> 3);
  const int m0 = (wg / NT_N) * 128, n0 = nbase + (wg % NT_N) * BN;
  const int NT = K >> 6;

  // pre-swizzled per-lane staging sources (granule q ^= row&7)
  const unsigned short* asrc[2];
  const unsigned short* bsrc[NF];
#pragma unroll
  for (int li = 0; li < 2; ++li) {
    const int gi = li * 512 + tid, r = gi >> 3, q = gi & 7;
    asrc[li] = A + (size_t)(m0 + r) * K + ((q ^ (r & 7)) << 3);
  }
#pragma unroll
  for (int li = 0; li < NF; ++li) {
    const int gi = li * 512 + tid, r = gi >> 3, q = gi & 7;
    bsrc[li] = B + (size_t)(n0 + r) * K + ((q ^ (r & 7)) << 3);
  }
  const int wlds = wid * 64;

#define STG7(buf, ko)                                                          \
  { unsigned short* da_ = sm + (buf) * BUFE;                                   \
    gload16(asrc[0] + (ko), da_ + ((0 * 512 + wlds) << 3));                    \
    gload16(asrc[1] + (ko), da_ + ((1 * 512 + wlds) << 3));                    \
    unsigned short* db_ = sm + (buf) * BUFE + AELEM;                           \
    _Pragma("unroll") for (int li = 0; li < NF; ++li)                          \
      gload16(bsrc[li] + (ko), db_ + ((li * 512 + wlds) << 3)); }

#define ARD7(bufp, f, kk)                                                      \
  (*(const bf16x8*)((bufp) + (wm * 64 + (f) * 16 + fr) * 64 +                  \
      ((((kk) * 4 + kg) ^ (fr & 7)) << 3)))
#define BRD7(bufp, nf, kk)                                                     \
  (*(const bf16x8*)((bufp) + AELEM + (wn * (NF * 16) + (nf) * 16 + fr) * 64 +  \
      ((((kk) * 4 + kg) ^ (fr & 7)) << 3)))

  f32x4 acc[4][NF] = {};

  STG7(0, 0)
  asm volatile("s_waitcnt vmcnt(0)" ::: "memory");
  __builtin_amdgcn_s_barrier();

  for (int t = 0; t < NT; ++t) {
    unsigned short* bc = sm + (t & 1) * BUFE;
    if (t + 1 < NT) STG7((t & 1) ^ 1, (t + 1) << 6)

    bf16x8 bfv[NF][2], af[4][2];
#pragma unroll
    for (int nf = 0; nf < NF; ++nf) {
      bfv[nf][0] = BRD7(bc, nf, 0);
      bfv[nf][1] = BRD7(bc, nf, 1);
    }
#pragma unroll
    for (int mf = 0; mf < 4; ++mf) {
      af[mf][0] = ARD7(bc, mf, 0);
      af[mf][1] = ARD7(bc, mf, 1);
    }
    __builtin_amdgcn_sched_barrier(0);
    asm volatile("s_waitcnt lgkmcnt(0)" ::: "memory");
    __builtin_amdgcn_sched_barrier(0);
    __builtin_amdgcn_s_setprio(1);
#pragma unroll
    for (int mf = 0; mf < 4; ++mf)
#pragma unroll
      for (int nf = 0; nf < NF; ++nf)
#pragma unroll
        for (int kk = 0; kk < 2; ++kk)
          acc[mf][nf] = __builtin_amdgcn_mfma_f32_16x16x32_bf16(
              af[mf][kk], bfv[nf][kk], acc[mf][nf], 0, 0, 0);
    __builtin_amdgcn_s_setprio(0);

    asm volatile("s_waitcnt vmcnt(0)" ::: "memory");
    __builtin_amdgcn_s_barrier();
  }

  // epilogue
  float* Cf = (float*)Cv;
  unsigned short* Ch = (unsigned short*)Cv;
  const float rg = (EPI == 2) ? gatep[0] : 0.f;
#pragma unroll
  for (int nf = 0; nf < NF; ++nf) {
    const int col = n0 + wn * (NF * 16) + nf * 16 + fr;
    if (col >= Nout) continue;
    const float bv = bias[col];
    if (EPI == 3) {
      const int h = col / 129;
      const int e = col - h * 129;
      if (e == 0) {
#pragma unroll
        for (int mf = 0; mf < 4; ++mf) {
          const int rowb = m0 + wm * 64 + mf * 16 + kg * 4;
#pragma unroll
          for (int r = 0; r < 4; ++r) {
            const int row = rowb + r;
            const size_t r2 = (((size_t)((row >> 11) * NH + h)) << 11) + (row & (LLEN - 1));
            dtbuf[r2] = acc[mf][nf][r] + bv;
          }
        }
      } else {
        const int ep = e - 1;
#pragma unroll
        for (int mf = 0; mf < 4; ++mf) {
          const int rowb = m0 + wm * 64 + mf * 16 + kg * 4;
#pragma unroll
          for (int r = 0; r < 4; ++r) {
            const int row = rowb + r;
            const size_t dst =
                (((size_t)((row >> 11) * NH + h) << 11) + (row & (LLEN - 1))) * XP2LD + ep;
            Ch[dst] = f2bf(acc[mf][nf][r] + bv);
          }
        }
      }
    } else {
#pragma unroll
      for (int mf = 0; mf < 4; ++mf) {
        const int rowb = m0 + wm * 64 + mf * 16 + kg * 4;
#pragma unroll
        for (int r = 0; r < 4; ++r) {
          const size_t o = (size_t)(rowb + r) * ldc + col;
          float v = acc[mf][nf][r] + bv;
          if (EPI == 1) {
            Ch[o] = f2bf(v);
          } else {
            v = resid[o] + rg * v;
            Cf[o] = v;
          }
        }
      }
    }
  }
#undef STG7
#undef ARD7
#undef BRD7
}

// ---------------- alpha: dtbuf + xmean + hc -> al (coalesced, tiny) ------------
__global__ __launch_bounds__(256) void k_alpha(const float* __restrict__ dtbuf,
                                               const float* __restrict__ xmean,
                                               const float* __restrict__ hc,
                                               float* __restrict__ al) {
  const int i = blockIdx.x * 256 + threadIdx.x;   // < BB*NH*LLEN
  const int h = (i >> 11) % NH;
  const float dt = dtbuf[i];
  const float sp = (dt > 20.f) ? dt : log1pf(expf(dt));
  const float one_a = 1.f - expf(hc[h] * sp);
  const float xm = xmean[i];
  const float pe = one_a * one_a * xm * xm * (1.f / 64.f);
  const float boost = fmaxf(tanhf(hc[NH + h] * pe * hc[3 * NH + h]), 0.f);
  const float ab = hc[2 * NH + h];
  al[i] = fminf(fmaxf(ab + (1.f - ab) * boost, 0.01f), 0.999f);
}

// ---------------- depthwise causal conv(4) + silu + per-head x-mean ------------
__global__ __launch_bounds__(256) void k_dwconv(const unsigned short* __restrict__ xz,
                                                const float* __restrict__ cw,
                                                const float* __restrict__ cb,
                                                unsigned short* __restrict__ out,
                                                float* __restrict__ xmean) {
  const int idx = blockIdx.x * 256 + threadIdx.x;  // < (MROWS/4)*192
  const int c0 = (idx % 192) * 8;
  const int bl0 = (idx / 192) * 4;
  const int lpos0 = bl0 & (LLEN - 1);
  float w[8][4];
#pragma unroll
  for (int j = 0; j < 8; ++j) {
    const float4 wv = *(const float4*)(cw + (c0 + j) * 4);
    w[j][0] = wv.x; w[j][1] = wv.y; w[j][2] = wv.z; w[j][3] = wv.w;
  }
  float xr[7][8];
#pragma unroll
  for (int m = 0; m < 7; ++m) {
    uint4 xv = make_uint4(0u, 0u, 0u, 0u);
    if (lpos0 - 3 + m >= 0)
      xv = *(const uint4*)(xz + (size_t)(bl0 - 3 + m) * N2 + c0);
    const unsigned short* xs = (const unsigned short*)&xv;
#pragma unroll
    for (int j = 0; j < 8; ++j) xr[m][j] = bf2f(xs[j]);
  }
  const float4 cb0 = *(const float4*)(cb + c0);
  const float4 cb1 = *(const float4*)(cb + c0 + 4);
  const float cbv[8] = {cb0.x, cb0.y, cb0.z, cb0.w, cb1.x, cb1.y, cb1.z, cb1.w};
  float hsum[4] = {0.f, 0.f, 0.f, 0.f};
#pragma unroll
  for (int t4 = 0; t4 < 4; ++t4) {
    union { unsigned short u[8]; uint4 v; } pk;
#pragma unroll
    for (int j = 0; j < 8; ++j) {
      float a = cbv[j];
#pragma unroll
      for (int k = 0; k < 4; ++k) a = fmaf(w[j][k], xr[t4 + k][j], a);
      a = a / (1.f + __expf(-a));
      hsum[t4] += a;
      pk.u[j] = f2bf(a);
    }
    *(uint4*)(out + (size_t)(bl0 + t4) * DI + c0) = pk.v;
  }
#pragma unroll
  for (int o = 1; o < 8; o <<= 1) {
#pragma unroll
    for (int t4 = 0; t4 < 4; ++t4) hsum[t4] += __shfl_xor(hsum[t4], o);
  }
  if ((threadIdx.x & 7) == 0) {
    const int h = (idx % 192) >> 3;
    const int b = bl0 >> 11;
    float4 xm = make_float4(hsum[0] * (1.f / 64.f), hsum[1] * (1.f / 64.f),
                            hsum[2] * (1.f / 64.f), hsum[3] * (1.f / 64.f));
    *(float4*)(xmean + (((size_t)(b * NH + h)) << 11) + lpos0) = xm;
  }
}

// ---------------- chunked scan, stage 1: intra-chunk Y + local state -----------
__global__ __launch_bounds__(256) void k_chunk1(
    const unsigned short* __restrict__ xp2, const unsigned short* __restrict__ xcg,
    const float* __restrict__ al, unsigned short* __restrict__ xz,
    unsigned short* __restrict__ Hbuf, float* __restrict__ Dc) {
  const int blk = blockIdx.x;          // bh*16 + c
  const int bh = blk >> 4, c = blk & 15;
  const int b = bh / NH, h = bh % NH;
  const int tid = threadIdx.x, w = tid >> 6, lane = tid & 63;
  const int fr = lane & 15, kg = lane >> 4;
  const int rbase = b * LLEN + c * QC;
  const size_t rbase2 = ((size_t)bh << 11) + c * QC;

  __shared__ float lc[QC], ia[QC], escl[QC], rbA[QC], rcC[QC];
  __shared__ float wtot[2];
  __shared__ alignas(16) unsigned short XT[64][152];
  __shared__ alignas(16) unsigned short BsT[64][152];
  __shared__ alignas(16) unsigned short Pt[128][88];

  float a = 1.f, la = 0.f;
  if (tid < QC) { a = al[(size_t)bh * LLEN + c * QC + tid]; la = __logf(a); }
  float s = la;
#pragma unroll
  for (int o = 1; o < 64; o <<= 1) { float t2 = __shfl_up(s, o); if (lane >= o) s += t2; }
  if (tid < QC && lane == 63) wtot[w] = s;
  __syncthreads();
  if (tid < QC) { lc[tid] = s + ((w == 1) ? wtot[0] : 0.f); ia[tid] = 1.f - a; }
  __syncthreads();
  const float lcE = lc[QC - 1];
  if (tid < QC) escl[tid] = __expf(lcE - lc[tid]);
  if (tid == 0) Dc[blk] = __expf(lcE);
  __syncthreads();

  {
    const int r8 = tid >> 3, q8 = tid & 7;
#pragma unroll
    for (int it = 0; it < 4; ++it) {
      const int u = it * 32 + r8;
      const uint4 xv = *(const uint4*)(xcg + (size_t)(rbase + u) * DI + h * DH + q8 * 8);
      const unsigned short* xs = (const unsigned short*)&xv;
#pragma unroll
      for (int j = 0; j < 8; ++j) XT[q8 * 8 + j][u] = xs[j];
      const size_t prow = (rbase2 + u) * XP2LD;
      const uint4 bv = *(const uint4*)(xp2 + prow + q8 * 8);
      const uint4 cv = *(const uint4*)(xp2 + prow + 64 + q8 * 8);
      const unsigned short* bsv = (const unsigned short*)&bv;
      const unsigned short* csv = (const unsigned short*)&cv;
      float bb[8], sb = 0.f, sc2 = 0.f;
#pragma unroll
      for (int j = 0; j < 8; ++j) {
        bb[j] = bf2f(bsv[j]);
        sb = fmaf(bb[j], bb[j], sb);
        const float cc = bf2f(csv[j]);
        sc2 = fmaf(cc, cc, sc2);
      }
      sb += __shfl_xor(sb, 1); sb += __shfl_xor(sb, 2); sb += __shfl_xor(sb, 4);
      sc2 += __shfl_xor(sc2, 1); sc2 += __shfl_xor(sc2, 2); sc2 += __shfl_xor(sc2, 4);
      const float rcpB = 1.f / fmaxf(sqrtf(sb), 1e-12f);
      const float e = escl[u] * ia[u] * rcpB;
#pragma unroll
      for (int j = 0; j < 8; ++j) BsT[q8 * 8 + j][u] = f2bf(bb[j] * e);
      if (q8 == 0) {
        rbA[u] = ia[u] * rcpB;
        rcC[u] = 1.f / fmaxf(sqrtf(sc2), 1e-12f);
      }
    }
  }
  __syncthreads();

  bf16x8 cf[2][2];
#pragma unroll
  for (int fi = 0; fi < 2; ++fi)
#pragma unroll
    for (int kk = 0; kk < 2; ++kk) {
      const int t = w * 32 + fi * 16 + fr;
      const uint4 v = *(const uint4*)(xp2 + (rbase2 + t) * XP2LD + 64 + kk * 32 + kg * 8);
      cf[fi][kk] = *(const bf16x8*)&v;
    }

  float lct[2][4], rct[2][4];
#pragma unroll
  for (int fi = 0; fi < 2; ++fi)
#pragma unroll
    for (int r = 0; r < 4; ++r) {
      const int t = w * 32 + fi * 16 + kg * 4 + r;
      lct[fi][r] = lc[t];
      rct[fi][r] = rcC[t];
    }

  f32x4 yacc[2][4] = {};
  f32x4 hacc[4] = {};
#pragma unroll
  for (int ut = 0; ut < 2; ++ut) {
    f32x4 g[2][4] = {};
#pragma unroll
    for (int kk = 0; kk < 2; ++kk)
#pragma unroll
      for (int fj = 0; fj < 4; ++fj) {
        const int u = ut * 64 + fj * 16 + fr;
        const uint4 v = *(const uint4*)(xp2 + (rbase2 + u) * XP2LD + kk * 32 + kg * 8);
        const bf16x8 bfrag = *(const bf16x8*)&v;
#pragma unroll
        for (int fi = 0; fi < 2; ++fi)
          g[fi][fj] = __builtin_amdgcn_mfma_f32_16x16x32_bf16(cf[fi][kk], bfrag, g[fi][fj], 0, 0, 0);
      }
#pragma unroll
    for (int fi = 0; fi < 2; ++fi)
#pragma unroll
      for (int fj = 0; fj < 4; ++fj) {
        const int u = ut * 64 + fj * 16 + fr;
        const float lcu = lc[u], sbu = rbA[u];
#pragma unroll
        for (int r = 0; r < 4; ++r) {
          const int t = w * 32 + fi * 16 + kg * 4 + r;
          const float v = (t >= u) ? g[fi][fj][r] * __expf(lct[fi][r] - lcu) * sbu * rct[fi][r] : 0.f;
          Pt[t][fj * 16 + fr] = f2bf(v);
        }
      }
#pragma unroll
    for (int kk = 0; kk < 2; ++kk) {
      bf16x8 xf[4];
#pragma unroll
      for (int fj = 0; fj < 4; ++fj)
        xf[fj] = *(const bf16x8*)&XT[fj * 16 + fr][ut * 64 + kk * 32 + kg * 8];
      bf16x8 pf[2];
#pragma unroll
      for (int fi = 0; fi < 2; ++fi)
        pf[fi] = *(const bf16x8*)&Pt[w * 32 + fi * 16 + fr][kk * 32 + kg * 8];
#pragma unroll
      for (int fi = 0; fi < 2; ++fi)
#pragma unroll
        for (int fj = 0; fj < 4; ++fj)
          yacc[fi][fj] = __builtin_amdgcn_mfma_f32_16x16x32_bf16(pf[fi], xf[fj], yacc[fi][fj], 0, 0, 0);
      const bf16x8 xh = *(const bf16x8*)&XT[w * 16 + fr][ut * 64 + kk * 32 + kg * 8];
#pragma unroll
      for (int fi = 0; fi < 4; ++fi) {
        const bf16x8 bs = *(const bf16x8*)&BsT[fi * 16 + fr][ut * 64 + kk * 32 + kg * 8];
        hacc[fi] = __builtin_amdgcn_mfma_f32_16x16x32_bf16(bs, xh, hacc[fi], 0, 0, 0);
      }
    }
  }
#pragma unroll
  for (int fi = 0; fi < 2; ++fi)
#pragma unroll
    for (int fj = 0; fj < 4; ++fj)
#pragma unroll
      for (int r = 0; r < 4; ++r) {
        const int t = w * 32 + fi * 16 + kg * 4 + r;
        const int d = fj * 16 + fr;
        xz[(size_t)(rbase + t) * N2 + h * DH + d] = f2bf(yacc[fi][fj][r]);
      }
  const int dcol = w * 16 + fr;
#pragma unroll
  for (int fi = 0; fi < 4; ++fi) {
    ushort4 pk;
    pk.x = f2bf(hacc[fi][0]); pk.y = f2bf(hacc[fi][1]);
    pk.z = f2bf(hacc[fi][2]); pk.w = f2bf(hacc[fi][3]);
    *(ushort4*)(Hbuf + ((size_t)blk * 64 + dcol) * 64 + fi * 16 + kg * 4) = pk;
  }
}

// ---------------- chunked scan, stage 2: carry across chunks (in place) --------
__global__ __launch_bounds__(256) void k_carry(unsigned short* __restrict__ Hbuf,
                                               const float* __restrict__ Dc) {
  const int bh = blockIdx.x, tid = threadIdx.x;
  float carry[16];
#pragma unroll
  for (int j = 0; j < 16; ++j) carry[j] = 0.f;
  for (int c = 0; c < NCHUNK; ++c) {
    unsigned short* p = Hbuf + (((size_t)(bh * NCHUNK + c)) << 12) + tid * 16;
    const uint4 v0 = *(const uint4*)(p);
    const uint4 v1 = *(const uint4*)(p + 8);
    const unsigned short* hs0 = (const unsigned short*)&v0;
    const unsigned short* hs1 = (const unsigned short*)&v1;
    float hl[16];
#pragma unroll
    for (int j = 0; j < 8; ++j) { hl[j] = bf2f(hs0[j]); hl[8 + j] = bf2f(hs1[j]); }
    uint4 o0, o1;
    unsigned short* os0 = (unsigned short*)&o0;
    unsigned short* os1 = (unsigned short*)&o1;
#pragma unroll
    for (int j = 0; j < 8; ++j) { os0[j] = f2bf(carry[j]); os1[j] = f2bf(carry[8 + j]); }
    *(uint4*)(p) = o0;
    *(uint4*)(p + 8) = o1;
    const float dc = Dc[bh * NCHUNK + c];
#pragma unroll
    for (int j = 0; j < 16; ++j) carry[j] = fmaf(dc, carry[j], hl[j]);
  }
}

// ---------------- chunked scan, stage 3: inter-chunk Y + fused gating ----------
__global__ __launch_bounds__(256) void k_chunk2(
    const unsigned short* __restrict__ xp2, const float* __restrict__ al,
    const unsigned short* __restrict__ Hbuf, const unsigned short* __restrict__ xz,
    unsigned short* __restrict__ xcg) {
  const int blk = blockIdx.x;
  const int bh = blk >> 4, c = blk & 15;
  const int b = bh / NH, h = bh % NH;
  const int tid = threadIdx.x, w = tid >> 6, lane = tid & 63;
  const int fr = lane & 15, kg = lane >> 4;
  const int rbase = b * LLEN + c * QC;
  const size_t rbase2 = ((size_t)bh << 11) + c * QC;
  __shared__ float lc[QC], rc2[QC];
  __shared__ float wtot[2];
  float a = 1.f, la = 0.f;
  if (tid < QC) { a = al[(size_t)bh * LLEN + c * QC + tid]; la = __logf(a); }
  float s = la;
#pragma unroll
  for (int o = 1; o < 64; o <<= 1) { float t2 = __shfl_up(s, o); if (lane >= o) s += t2; }
  if (tid < QC && lane == 63) wtot[w] = s;
  __syncthreads();
  if (tid < QC) lc[tid] = s + ((w == 1) ? wtot[0] : 0.f);
  __syncthreads();
  bf16x8 cf[2][2];
#pragma unroll
  for (int fi = 0; fi < 2; ++fi) {
    const int t = w * 32 + fi * 16 + fr;
    float ss = 0.f;
#pragma unroll
    for (int kk = 0; kk < 2; ++kk) {
      const uint4 v = *(const uint4*)(xp2 + (rbase2 + t) * XP2LD + 64 + kk * 32 + kg * 8);
      cf[fi][kk] = *(const bf16x8*)&v;
      const unsigned short* cs = (const unsigned short*)&v;
#pragma unroll
      for (int q = 0; q < 8; ++q) { const float cc = bf2f(cs[q]); ss = fmaf(cc, cc, ss); }
    }
    ss += __shfl_xor(ss, 16);
    ss += __shfl_xor(ss, 32);
    if (kg == 0) rc2[t] = 1.f / fmaxf(sqrtf(ss), 1e-12f);
  }
  bf16x8 hf[4][2];
#pragma unroll
  for (int fj = 0; fj < 4; ++fj)
#pragma unroll
    for (int kk = 0; kk < 2; ++kk) {
      const uint4 v = *(const uint4*)(Hbuf + ((size_t)blk * 64 + fj * 16 + fr) * 64 + kk * 32 + kg * 8);
      hf[fj][kk] = *(const bf16x8*)&v;
    }
  __syncthreads();
  f32x4 y[2][4] = {};
#pragma unroll
  for (int kk = 0; kk < 2; ++kk)
#pragma unroll
    for (int fi = 0; fi < 2; ++fi)
#pragma unroll
      for (int fj = 0; fj < 4; ++fj)
        y[fi][fj] = __builtin_amdgcn_mfma_f32_16x16x32_bf16(cf[fi][kk], hf[fj][kk], y[fi][fj], 0, 0, 0);
#pragma unroll
  for (int fi = 0; fi < 2; ++fi)
#pragma unroll
    for (int fj = 0; fj < 4; ++fj)
#pragma unroll
      for (int r = 0; r < 4; ++r) {
        const int t = w * 32 + fi * 16 + kg * 4 + r;
        const int d = fj * 16 + fr;
        const float scl = rc2[t] * __expf(lc[t]);
        const size_t rowg = (size_t)(rbase + t);
        const float yv = y[fi][fj][r] * scl + bf2f(xz[rowg * N2 + h * DH + d]);
        const float zv = bf2f(xz[rowg * N2 + DI + h * DH + d]);
        const float g = yv * (zv / (1.f + __expf(-zv)));
        xcg[rowg * DI + h * DH + d] = f2bf(g);
      }
}

extern "C" void kernel_launch(void* const* d_in, const int* in_sizes, int n_in,
                              void* d_out, int out_size, void* d_ws, size_t ws_size,
                              hipStream_t stream) {
  const float* hs     = (const float*)d_in[0];
  const float* norm_w = (const float*)d_in[1];
  const float* in_w   = (const float*)d_in[2];
  const float* in_b   = (const float*)d_in[3];
  const float* cw     = (const float*)d_in[4];
  const float* cb     = (const float*)d_in[5];
  const float* xw     = (const float*)d_in[6];
  const float* xb     = (const float*)d_in[7];
  const float* A_log  = (const float*)d_in[8];
  const float* l2ab   = (const float*)d_in[9];
  const float* l2b    = (const float*)d_in[10];
  const float* se     = (const float*)d_in[11];
  const float* ow     = (const float*)d_in[12];
  const float* ob     = (const float*)d_in[13];
  const float* rg     = (const float*)d_in[14];
  float* out = (float*)d_out;

  char* ws = (char*)d_ws;
  // layout (~169 MB): same as r14/r15
  unsigned short* xnorm = (unsigned short*)(ws);
  unsigned short* wA    = (unsigned short*)(ws + 33554432ull);
  unsigned short* wX    = (unsigned short*)(ws + 46137344ull);
  unsigned short* wO    = (unsigned short*)(ws + 55967744ull);
  unsigned short* xz    = (unsigned short*)(ws + 62259200ull);
  unsigned short* xp2   = (unsigned short*)(ws + 112590848ull);
  float* xmean          = (float*)(ws + 166068224ull);
  float* al             = (float*)(ws + 166854656ull);
  float* Dc             = (float*)(ws + 167641088ull);
  float* hc             = (float*)(ws + 167647232ull);
  float* dtbuf          = (float*)(ws + 167651328ull);
  unsigned short* xcg   = xnorm;
  unsigned short* Hbuf  = wA;

  // fused front: weight convert (56064 blocks) + RMSNorm (8192) + hc (1)
  k_pre<<<WBLK + MROWS + 1, 256, 0, stream>>>(in_w, wA, xw, wX, ow, wO,
                                              hs, norm_w, xnorm,
                                              A_log, l2ab, l2b, se, hc);
  // in_proj: BN=192, 64 x 16 = 1024 blocks (2 exact rounds at 2 blocks/CU)
  k_gemm7<1, 3><<<1024, 512, 0, stream>>>(xnorm, wA, in_b, xz, nullptr, nullptr,
                                          nullptr, 0, DMODEL, 16, N2, N2);
  // conv + silu + xmean
  k_dwconv<<<(MROWS / 4) * 192 / 256, 256, 0, stream>>>(xz, cw, cb, xcg, xmean);
  // x_proj main: BN=192, cols 0..3071, 64 x 16 = 1024 blocks (2 exact rounds)
  k_gemm7<3, 3><<<1024, 512, 0, stream>>>(xcg, wX, xb, xp2, nullptr, nullptr,
                                          dtbuf, 0, DI, 16, NP, 0);
  // x_proj tail: BN=128, cols 3072..3199 (24 real), 64 x 1 = 64 blocks
  k_gemm7<3, 2><<<64, 512, 0, stream>>>(xcg, wX, xb, xp2, nullptr, nullptr,
                                        dtbuf, 3072, DI, 1, NP, 0);
  // alpha (coalesced, tiny)
  k_alpha<<<(BB * NH * LLEN) / 256, 256, 0, stream>>>(dtbuf, xmean, hc, al);
  // chunked scan
  k_chunk1<<<BB * NH * NCHUNK, 256, 0, stream>>>(xp2, xcg, al, xz, Hbuf, Dc);
  k_carry<<<BB * NH, 256, 0, stream>>>(Hbuf, Dc);
  k_chunk2<<<BB * NH * NCHUNK, 256, 0, stream>>>(xp2, al, Hbuf, xz, xcg);
  // out_proj: BN=128, 64 x 16 = 1024 blocks (2 exact rounds), fp32 + residual
  k_gemm7<2, 2><<<1024, 512, 0, stream>>>(xcg, wO, ob, out, hs, rg,
                                          nullptr, 0, DI, 16, DMODEL, DMODEL);
}

// Round 17
// 408.996 us; speedup vs baseline: 1.2994x; 1.0108x over previous
//
#include <hip/hip_runtime.h>
#include <stdint.h>

// Problem constants
#define BB 4
#define LLEN 2048
#define DMODEL 2048
#define NH 24
#define DH 64
#define SS 64
#define DI 1536          // NH*DH
#define N2 3072          // 2*DI
#define NP 3096          // NH*(1+2*S)
#define NP_PAD 3200      // weight rows padded (zero rows 3096..3199)
#define MROWS 8192       // BB*LLEN
#define NCHUNK 16
#define QC 128           // chunk length
// xp2 row stride: 136 elems = 272B = 17*16B (non-power-of-2; see r12 note).
#define XP2LD 136
#define WBLK 56064       // weight-convert blocks in k_pre

using bf16x8 = __bf16 __attribute__((ext_vector_type(8)));
using f32x4  = float __attribute__((ext_vector_type(4)));

__device__ __forceinline__ unsigned short f2bf(float f) {
  union { float f; unsigned int u; } v; v.f = f;
  unsigned int u = v.u + 0x7fffu + ((v.u >> 16) & 1u);
  return (unsigned short)(u >> 16);
}
__device__ __forceinline__ float bf2f(unsigned short h) {
  union { unsigned int u; float f; } v; v.u = ((unsigned int)h) << 16;
  return v.f;
}

__device__ __forceinline__ void gload16(const void* g, void* l) {
  __builtin_amdgcn_global_load_lds(
    reinterpret_cast<const __attribute__((address_space(1))) void*>(reinterpret_cast<uintptr_t>(g)),
    reinterpret_cast<__attribute__((address_space(3))) void*>((uint32_t)(reinterpret_cast<uintptr_t>(l))),
    16, 0, 0);
}

// ---------------- fused front kernel: weight conversion + RMSNorm + hc table ---
__global__ __launch_bounds__(256) void k_pre(
    const float* __restrict__ in_w, unsigned short* __restrict__ wA,
    const float* __restrict__ xw, unsigned short* __restrict__ wX,
    const float* __restrict__ ow, unsigned short* __restrict__ wO,
    const float* __restrict__ hs, const float* __restrict__ norm_w,
    unsigned short* __restrict__ xnorm,
    const float* __restrict__ A_log, const float* __restrict__ l2ab,
    const float* __restrict__ l2b, const float* __restrict__ se,
    float* __restrict__ hc) {
  const int blk = blockIdx.x;
  const int t = threadIdx.x;
  if (blk < WBLK) {
    int i = blk * 256 + t;
    if (i < N2 * DMODEL) { wA[i] = f2bf(in_w[i]); return; }
    i -= N2 * DMODEL;
    if (i < NP_PAD * DI) { wX[i] = (i < NP * DI) ? f2bf(xw[i]) : (unsigned short)0; return; }
    i -= NP_PAD * DI;
    wO[i] = f2bf(ow[i]);
    return;
  }
  if (blk == WBLK + MROWS) {
    if (t < NH) {
      hc[t]          = fminf(fmaxf(A_log[t], -2.3f), -0.01f);
      hc[NH + t]     = exp2f(fminf(fmaxf(l2b[t], -2.f), 2.f));
      hc[2 * NH + t] = 1.f - exp2f(fminf(fmaxf(l2ab[t], -3.32f), -0.015f));
      hc[3 * NH + t] = 1.f / (se[t] + 1e-6f);
    }
    return;
  }
  const int row = blk - WBLK;
  const float* x = hs + (size_t)row * DMODEL;
  float4 v0 = reinterpret_cast<const float4*>(x)[t * 2 + 0];
  float4 v1 = reinterpret_cast<const float4*>(x)[t * 2 + 1];
  float ss = v0.x * v0.x + v0.y * v0.y + v0.z * v0.z + v0.w * v0.w +
             v1.x * v1.x + v1.y * v1.y + v1.z * v1.z + v1.w * v1.w;
#pragma unroll
  for (int o = 32; o; o >>= 1) ss += __shfl_xor(ss, o);
  __shared__ float red[4];
  if ((t & 63) == 0) red[t >> 6] = ss;
  __syncthreads();
  ss = red[0] + red[1] + red[2] + red[3];
  const float r = rsqrtf(ss * (1.0f / DMODEL) + 1.1920928955078125e-07f);
  float4 w0 = reinterpret_cast<const float4*>(norm_w)[t * 2 + 0];
  float4 w1 = reinterpret_cast<const float4*>(norm_w)[t * 2 + 1];
  union { unsigned short u[8]; uint4 v; } pk;
  pk.u[0] = f2bf(v0.x * r * w0.x); pk.u[1] = f2bf(v0.y * r * w0.y);
  pk.u[2] = f2bf(v0.z * r * w0.z); pk.u[3] = f2bf(v0.w * r * w0.w);
  pk.u[4] = f2bf(v1.x * r * w1.x); pk.u[5] = f2bf(v1.y * r * w1.y);
  pk.u[6] = f2bf(v1.z * r * w1.z); pk.u[7] = f2bf(v1.w * r * w1.w);
  *reinterpret_cast<uint4*>(xnorm + (size_t)row * DMODEL + t * 8) = pk.v;
}

// ---------------- 2-blocks/CU drift bf16 NT GEMM (128 x NF*64 tile, BK=64) -----
// NF=3: BN=192, LDS 80KB. NF=2: BN=128, LDS 64KB. Both -> 2 blocks/CU.
// EPI 1: bf16 C. EPI 2: fp32 C = resid + rg*(acc+bias). EPI 3: xp2 + dtbuf.
template <int EPI, int NF>
__global__ __launch_bounds__(512, 4)
void k_gemm7(const unsigned short* __restrict__ A, const unsigned short* __restrict__ B,
             const float* __restrict__ bias, void* __restrict__ Cv,
             const float* __restrict__ resid, const float* __restrict__ gatep,
             float* __restrict__ dtbuf, int nbase,
             int K, int NT_N, int Nout, int ldc) {
  constexpr int BN = NF * 64;
  constexpr int AELEM = 128 * 64;
  constexpr int BELEM = BN * 64;
  constexpr int BUFE = AELEM + BELEM;
  __shared__ alignas(16) unsigned short sm[2 * BUFE];
  const int tid = threadIdx.x;
  const int lane = tid & 63, wid = tid >> 6;
  const int wm = wid >> 2, wn = wid & 3;
  const int fr = lane & 15, kg = lane >> 4;
  const int nwg = gridDim.x;
  const int wg = ((int)blockIdx.x & 7) * (nwg >> 3) + ((int)blockIdx.x >> 3);
  const int m0 = (wg / NT_N) * 128, n0 = nbase + (wg % NT_N) * BN;
  const int NT = K >> 6;

  const unsigned short* asrc[2];
  const unsigned short* bsrc[NF];
#pragma unroll
  for (int li = 0; li < 2; ++li) {
    const int gi = li * 512 + tid, r = gi >> 3, q = gi & 7;
    asrc[li] = A + (size_t)(m0 + r) * K + ((q ^ (r & 7)) << 3);
  }
#pragma unroll
  for (int li = 0; li < NF; ++li) {
    const int gi = li * 512 + tid, r = gi >> 3, q = gi & 7;
    bsrc[li] = B + (size_t)(n0 + r) * K + ((q ^ (r & 7)) << 3);
  }
  const int wlds = wid * 64;

#define STG7(buf, ko)                                                          \
  { unsigned short* da_ = sm + (buf) * BUFE;                                   \
    gload16(asrc[0] + (ko), da_ + ((0 * 512 + wlds) << 3));                    \
    gload16(asrc[1] + (ko), da_ + ((1 * 512 + wlds) << 3));                    \
    unsigned short* db_ = sm + (buf) * BUFE + AELEM;                           \
    _Pragma("unroll") for (int li = 0; li < NF; ++li)                          \
      gload16(bsrc[li] + (ko), db_ + ((li * 512 + wlds) << 3)); }

#define ARD7(bufp, f, kk)                                                      \
  (*(const bf16x8*)((bufp) + (wm * 64 + (f) * 16 + fr) * 64 +                  \
      ((((kk) * 4 + kg) ^ (fr & 7)) << 3)))
#define BRD7(bufp, nf, kk)                                                     \
  (*(const bf16x8*)((bufp) + AELEM + (wn * (NF * 16) + (nf) * 16 + fr) * 64 +  \
      ((((kk) * 4 + kg) ^ (fr & 7)) << 3)))

  f32x4 acc[4][NF] = {};

  STG7(0, 0)
  asm volatile("s_waitcnt vmcnt(0)" ::: "memory");
  __builtin_amdgcn_s_barrier();

  for (int t = 0; t < NT; ++t) {
    unsigned short* bc = sm + (t & 1) * BUFE;
    if (t + 1 < NT) STG7((t & 1) ^ 1, (t + 1) << 6)

    bf16x8 bfv[NF][2], af[4][2];
#pragma unroll
    for (int nf = 0; nf < NF; ++nf) {
      bfv[nf][0] = BRD7(bc, nf, 0);
      bfv[nf][1] = BRD7(bc, nf, 1);
    }
#pragma unroll
    for (int mf = 0; mf < 4; ++mf) {
      af[mf][0] = ARD7(bc, mf, 0);
      af[mf][1] = ARD7(bc, mf, 1);
    }
    __builtin_amdgcn_sched_barrier(0);
    asm volatile("s_waitcnt lgkmcnt(0)" ::: "memory");
    __builtin_amdgcn_sched_barrier(0);
    __builtin_amdgcn_s_setprio(1);
#pragma unroll
    for (int mf = 0; mf < 4; ++mf)
#pragma unroll
      for (int nf = 0; nf < NF; ++nf)
#pragma unroll
        for (int kk = 0; kk < 2; ++kk)
          acc[mf][nf] = __builtin_amdgcn_mfma_f32_16x16x32_bf16(
              af[mf][kk], bfv[nf][kk], acc[mf][nf], 0, 0, 0);
    __builtin_amdgcn_s_setprio(0);

    asm volatile("s_waitcnt vmcnt(0)" ::: "memory");
    __builtin_amdgcn_s_barrier();
  }

  // epilogue
  float* Cf = (float*)Cv;
  unsigned short* Ch = (unsigned short*)Cv;
  const float rg = (EPI == 2) ? gatep[0] : 0.f;
#pragma unroll
  for (int nf = 0; nf < NF; ++nf) {
    const int col = n0 + wn * (NF * 16) + nf * 16 + fr;
    if (col >= Nout) continue;
    const float bv = bias[col];
    if (EPI == 3) {
      const int h = col / 129;
      const int e = col - h * 129;
      if (e == 0) {
#pragma unroll
        for (int mf = 0; mf < 4; ++mf) {
          const int rowb = m0 + wm * 64 + mf * 16 + kg * 4;
#pragma unroll
          for (int r = 0; r < 4; ++r) {
            const int row = rowb + r;
            const size_t r2 = (((size_t)((row >> 11) * NH + h)) << 11) + (row & (LLEN - 1));
            dtbuf[r2] = acc[mf][nf][r] + bv;
          }
        }
      } else {
        const int ep = e - 1;
#pragma unroll
        for (int mf = 0; mf < 4; ++mf) {
          const int rowb = m0 + wm * 64 + mf * 16 + kg * 4;
#pragma unroll
          for (int r = 0; r < 4; ++r) {
            const int row = rowb + r;
            const size_t dst =
                (((size_t)((row >> 11) * NH + h) << 11) + (row & (LLEN - 1))) * XP2LD + ep;
            Ch[dst] = f2bf(acc[mf][nf][r] + bv);
          }
        }
      }
    } else {
#pragma unroll
      for (int mf = 0; mf < 4; ++mf) {
        const int rowb = m0 + wm * 64 + mf * 16 + kg * 4;
#pragma unroll
        for (int r = 0; r < 4; ++r) {
          const size_t o = (size_t)(rowb + r) * ldc + col;
          float v = acc[mf][nf][r] + bv;
          if (EPI == 1) {
            Ch[o] = f2bf(v);
          } else {
            v = resid[o] + rg * v;
            Cf[o] = v;
          }
        }
      }
    }
  }
#undef STG7
#undef ARD7
#undef BRD7
}

// ---------------- x_proj tail, split-K x4 (cols 3072..3199, 24 real) -----------
// 256 blocks = 64 m-tiles x 4 K-splits (K=384 each, NT=6). Same drift loop,
// BN=128, LDS 64KB. Writes fp32 partials to pt[ks][8192][128]; reduction+bias
// fused into k_alpha2. Separate kernel (no template coupling with k_gemm7).
__global__ __launch_bounds__(512, 4)
void k_tailsk(const unsigned short* __restrict__ A, const unsigned short* __restrict__ B,
              float* __restrict__ pt) {
  constexpr int AELEM = 128 * 64;
  constexpr int BELEM = 128 * 64;
  constexpr int BUFE = AELEM + BELEM;
  __shared__ alignas(16) unsigned short sm[2 * BUFE];
  const int tid = threadIdx.x;
  const int lane = tid & 63, wid = tid >> 6;
  const int wm = wid >> 2, wn = wid & 3;
  const int fr = lane & 15, kg = lane >> 4;
  const int nwg = gridDim.x;
  const int wg = ((int)blockIdx.x & 7) * (nwg >> 3) + ((int)blockIdx.x >> 3);
  const int ks = wg & 3, m0 = (wg >> 2) * 128;
  const int kbase = ks * 384;
  const int NT = 6;
  const int K = DI, n0 = 3072;

  const unsigned short* asrc[2];
  const unsigned short* bsrc[2];
#pragma unroll
  for (int li = 0; li < 2; ++li) {
    const int gi = li * 512 + tid, r = gi >> 3, q = gi & 7;
    asrc[li] = A + (size_t)(m0 + r) * K + kbase + ((q ^ (r & 7)) << 3);
    bsrc[li] = B + (size_t)(n0 + r) * K + kbase + ((q ^ (r & 7)) << 3);
  }
  const int wlds = wid * 64;

#define STGT(buf, ko)                                                          \
  { unsigned short* da_ = sm + (buf) * BUFE;                                   \
    gload16(asrc[0] + (ko), da_ + ((0 * 512 + wlds) << 3));                    \
    gload16(asrc[1] + (ko), da_ + ((1 * 512 + wlds) << 3));                    \
    unsigned short* db_ = sm + (buf) * BUFE + AELEM;                           \
    gload16(bsrc[0] + (ko), db_ + ((0 * 512 + wlds) << 3));                    \
    gload16(bsrc[1] + (ko), db_ + ((1 * 512 + wlds) << 3)); }

#define ARDT(bufp, f, kk)                                                      \
  (*(const bf16x8*)((bufp) + (wm * 64 + (f) * 16 + fr) * 64 +                  \
      ((((kk) * 4 + kg) ^ (fr & 7)) << 3)))
#define BRDT(bufp, nf, kk)                                                     \
  (*(const bf16x8*)((bufp) + AELEM + (wn * 32 + (nf) * 16 + fr) * 64 +         \
      ((((kk) * 4 + kg) ^ (fr & 7)) << 3)))

  f32x4 acc[4][2] = {};

  STGT(0, 0)
  asm volatile("s_waitcnt vmcnt(0)" ::: "memory");
  __builtin_amdgcn_s_barrier();

  for (int t = 0; t < NT; ++t) {
    unsigned short* bc = sm + (t & 1) * BUFE;
    if (t + 1 < NT) STGT((t & 1) ^ 1, (t + 1) << 6)

    bf16x8 bfv[2][2], af[4][2];
#pragma unroll
    for (int nf = 0; nf < 2; ++nf) {
      bfv[nf][0] = BRDT(bc, nf, 0);
      bfv[nf][1] = BRDT(bc, nf, 1);
    }
#pragma unroll
    for (int mf = 0; mf < 4; ++mf) {
      af[mf][0] = ARDT(bc, mf, 0);
      af[mf][1] = ARDT(bc, mf, 1);
    }
    __builtin_amdgcn_sched_barrier(0);
    asm volatile("s_waitcnt lgkmcnt(0)" ::: "memory");
    __builtin_amdgcn_sched_barrier(0);
    __builtin_amdgcn_s_setprio(1);
#pragma unroll
    for (int mf = 0; mf < 4; ++mf)
#pragma unroll
      for (int nf = 0; nf < 2; ++nf)
#pragma unroll
        for (int kk = 0; kk < 2; ++kk)
          acc[mf][nf] = __builtin_amdgcn_mfma_f32_16x16x32_bf16(
              af[mf][kk], bfv[nf][kk], acc[mf][nf], 0, 0, 0);
    __builtin_amdgcn_s_setprio(0);

    asm volatile("s_waitcnt vmcnt(0)" ::: "memory");
    __builtin_amdgcn_s_barrier();
  }

  // epilogue: fp32 partials (only cols < 24 real; write all 128, harmless)
#pragma unroll
  for (int nf = 0; nf < 2; ++nf) {
    const int cl = wn * 32 + nf * 16 + fr;   // 0..127 local col
    if (cl >= 24) continue;
#pragma unroll
    for (int mf = 0; mf < 4; ++mf) {
      const int rowb = m0 + wm * 64 + mf * 16 + kg * 4;
#pragma unroll
      for (int r = 0; r < 4; ++r)
        pt[((size_t)ks * MROWS + rowb + r) * 32 + cl] = acc[mf][nf][r];
    }
  }
#undef STGT
#undef ARDT
#undef BRDT
}

// ---------------- alpha + tail reduce, fused -----------------------------------
// blocks [0,768): alpha from dtbuf+xmean+hc. blocks [768,1536): reduce the 4
// split-K partials for cols 3072..3095 (head 23, C slots 104..127) -> xp2.
__global__ __launch_bounds__(256) void k_alpha2(const float* __restrict__ dtbuf,
                                                const float* __restrict__ xmean,
                                                const float* __restrict__ hc,
                                                float* __restrict__ al,
                                                const float* __restrict__ pt,
                                                const float* __restrict__ xb,
                                                unsigned short* __restrict__ xp2) {
  const int blk = blockIdx.x;
  if (blk < 768) {
    const int i = blk * 256 + threadIdx.x;   // < BB*NH*LLEN
    const int h = (i >> 11) % NH;
    const float dt = dtbuf[i];
    const float sp = (dt > 20.f) ? dt : log1pf(expf(dt));
    const float one_a = 1.f - expf(hc[h] * sp);
    const float xm = xmean[i];
    const float pe = one_a * one_a * xm * xm * (1.f / 64.f);
    const float boost = fmaxf(tanhf(hc[NH + h] * pe * hc[3 * NH + h]), 0.f);
    const float ab = hc[2 * NH + h];
    al[i] = fminf(fmaxf(ab + (1.f - ab) * boost, 0.01f), 0.999f);
    return;
  }
  const int i = (blk - 768) * 256 + threadIdx.x;  // < 8192*24
  if (i >= MROWS * 24) return;
  const int row = i / 24, c = i - (i / 24) * 24;
  float v = xb[3072 + c];
#pragma unroll
  for (int ks = 0; ks < 4; ++ks)
    v += pt[((size_t)ks * MROWS + row) * 32 + c];
  // col 3072+c -> h=23, e=105+c, ep=104+c
  const size_t r2 = (((size_t)((row >> 11) * NH + 23)) << 11) + (row & (LLEN - 1));
  xp2[r2 * XP2LD + 104 + c] = f2bf(v);
}

// ---------------- depthwise causal conv(4) + silu + per-head x-mean ------------
__global__ __launch_bounds__(256) void k_dwconv(const unsigned short* __restrict__ xz,
                                                const float* __restrict__ cw,
                                                const float* __restrict__ cb,
                                                unsigned short* __restrict__ out,
                                                float* __restrict__ xmean) {
  const int idx = blockIdx.x * 256 + threadIdx.x;  // < (MROWS/4)*192
  const int c0 = (idx % 192) * 8;
  const int bl0 = (idx / 192) * 4;
  const int lpos0 = bl0 & (LLEN - 1);
  float w[8][4];
#pragma unroll
  for (int j = 0; j < 8; ++j) {
    const float4 wv = *(const float4*)(cw + (c0 + j) * 4);
    w[j][0] = wv.x; w[j][1] = wv.y; w[j][2] = wv.z; w[j][3] = wv.w;
  }
  float xr[7][8];
#pragma unroll
  for (int m = 0; m < 7; ++m) {
    uint4 xv = make_uint4(0u, 0u, 0u, 0u);
    if (lpos0 - 3 + m >= 0)
      xv = *(const uint4*)(xz + (size_t)(bl0 - 3 + m) * N2 + c0);
    const unsigned short* xs = (const unsigned short*)&xv;
#pragma unroll
    for (int j = 0; j < 8; ++j) xr[m][j] = bf2f(xs[j]);
  }
  const float4 cb0 = *(const float4*)(cb + c0);
  const float4 cb1 = *(const float4*)(cb + c0 + 4);
  const float cbv[8] = {cb0.x, cb0.y, cb0.z, cb0.w, cb1.x, cb1.y, cb1.z, cb1.w};
  float hsum[4] = {0.f, 0.f, 0.f, 0.f};
#pragma unroll
  for (int t4 = 0; t4 < 4; ++t4) {
    union { unsigned short u[8]; uint4 v; } pk;
#pragma unroll
    for (int j = 0; j < 8; ++j) {
      float a = cbv[j];
#pragma unroll
      for (int k = 0; k < 4; ++k) a = fmaf(w[j][k], xr[t4 + k][j], a);
      a = a / (1.f + __expf(-a));
      hsum[t4] += a;
      pk.u[j] = f2bf(a);
    }
    *(uint4*)(out + (size_t)(bl0 + t4) * DI + c0) = pk.v;
  }
#pragma unroll
  for (int o = 1; o < 8; o <<= 1) {
#pragma unroll
    for (int t4 = 0; t4 < 4; ++t4) hsum[t4] += __shfl_xor(hsum[t4], o);
  }
  if ((threadIdx.x & 7) == 0) {
    const int h = (idx % 192) >> 3;
    const int b = bl0 >> 11;
    float4 xm = make_float4(hsum[0] * (1.f / 64.f), hsum[1] * (1.f / 64.f),
                            hsum[2] * (1.f / 64.f), hsum[3] * (1.f / 64.f));
    *(float4*)(xmean + (((size_t)(b * NH + h)) << 11) + lpos0) = xm;
  }
}

// ---------------- chunked scan, stage 1: intra-chunk Y + local state -----------
__global__ __launch_bounds__(256) void k_chunk1(
    const unsigned short* __restrict__ xp2, const unsigned short* __restrict__ xcg,
    const float* __restrict__ al, unsigned short* __restrict__ xz,
    unsigned short* __restrict__ Hbuf, float* __restrict__ Dc) {
  const int blk = blockIdx.x;          // bh*16 + c
  const int bh = blk >> 4, c = blk & 15;
  const int b = bh / NH, h = bh % NH;
  const int tid = threadIdx.x, w = tid >> 6, lane = tid & 63;
  const int fr = lane & 15, kg = lane >> 4;
  const int rbase = b * LLEN + c * QC;
  const size_t rbase2 = ((size_t)bh << 11) + c * QC;

  __shared__ float lc[QC], ia[QC], escl[QC], rbA[QC], rcC[QC];
  __shared__ float wtot[2];
  __shared__ alignas(16) unsigned short XT[64][152];
  __shared__ alignas(16) unsigned short BsT[64][152];
  __shared__ alignas(16) unsigned short Pt[128][88];

  float a = 1.f, la = 0.f;
  if (tid < QC) { a = al[(size_t)bh * LLEN + c * QC + tid]; la = __logf(a); }
  float s = la;
#pragma unroll
  for (int o = 1; o < 64; o <<= 1) { float t2 = __shfl_up(s, o); if (lane >= o) s += t2; }
  if (tid < QC && lane == 63) wtot[w] = s;
  __syncthreads();
  if (tid < QC) { lc[tid] = s + ((w == 1) ? wtot[0] : 0.f); ia[tid] = 1.f - a; }
  __syncthreads();
  const float lcE = lc[QC - 1];
  if (tid < QC) escl[tid] = __expf(lcE - lc[tid]);
  if (tid == 0) Dc[blk] = __expf(lcE);
  __syncthreads();

  {
    const int r8 = tid >> 3, q8 = tid & 7;
#pragma unroll
    for (int it = 0; it < 4; ++it) {
      const int u = it * 32 + r8;
      const uint4 xv = *(const uint4*)(xcg + (size_t)(rbase + u) * DI + h * DH + q8 * 8);
      const unsigned short* xs = (const unsigned short*)&xv;
#pragma unroll
      for (int j = 0; j < 8; ++j) XT[q8 * 8 + j][u] = xs[j];
      const size_t prow = (rbase2 + u) * XP2LD;
      const uint4 bv = *(const uint4*)(xp2 + prow + q8 * 8);
      const uint4 cv = *(const uint4*)(xp2 + prow + 64 + q8 * 8);
      const unsigned short* bsv = (const unsigned short*)&bv;
      const unsigned short* csv = (const unsigned short*)&cv;
      float bb[8], sb = 0.f, sc2 = 0.f;
#pragma unroll
      for (int j = 0; j < 8; ++j) {
        bb[j] = bf2f(bsv[j]);
        sb = fmaf(bb[j], bb[j], sb);
        const float cc = bf2f(csv[j]);
        sc2 = fmaf(cc, cc, sc2);
      }
      sb += __shfl_xor(sb, 1); sb += __shfl_xor(sb, 2); sb += __shfl_xor(sb, 4);
      sc2 += __shfl_xor(sc2, 1); sc2 += __shfl_xor(sc2, 2); sc2 += __shfl_xor(sc2, 4);
      const float rcpB = 1.f / fmaxf(sqrtf(sb), 1e-12f);
      const float e = escl[u] * ia[u] * rcpB;
#pragma unroll
      for (int j = 0; j < 8; ++j) BsT[q8 * 8 + j][u] = f2bf(bb[j] * e);
      if (q8 == 0) {
        rbA[u] = ia[u] * rcpB;
        rcC[u] = 1.f / fmaxf(sqrtf(sc2), 1e-12f);
      }
    }
  }
  __syncthreads();

  bf16x8 cf[2][2];
#pragma unroll
  for (int fi = 0; fi < 2; ++fi)
#pragma unroll
    for (int kk = 0; kk < 2; ++kk) {
      const int t = w * 32 + fi * 16 + fr;
      const uint4 v = *(const uint4*)(xp2 + (rbase2 + t) * XP2LD + 64 + kk * 32 + kg * 8);
      cf[fi][kk] = *(const bf16x8*)&v;
    }

  float lct[2][4], rct[2][4];
#pragma unroll
  for (int fi = 0; fi < 2; ++fi)
#pragma unroll
    for (int r = 0; r < 4; ++r) {
      const int t = w * 32 + fi * 16 + kg * 4 + r;
      lct[fi][r] = lc[t];
      rct[fi][r] = rcC[t];
    }

  f32x4 yacc[2][4] = {};
  f32x4 hacc[4] = {};
#pragma unroll
  for (int ut = 0; ut < 2; ++ut) {
    f32x4 g[2][4] = {};
#pragma unroll
    for (int kk = 0; kk < 2; ++kk)
#pragma unroll
      for (int fj = 0; fj < 4; ++fj) {
        const int u = ut * 64 + fj * 16 + fr;
        const uint4 v = *(const uint4*)(xp2 + (rbase2 + u) * XP2LD + kk * 32 + kg * 8);
        const bf16x8 bfrag = *(const bf16x8*)&v;
#pragma unroll
        for (int fi = 0; fi < 2; ++fi)
          g[fi][fj] = __builtin_amdgcn_mfma_f32_16x16x32_bf16(cf[fi][kk], bfrag, g[fi][fj], 0, 0, 0);
      }
#pragma unroll
    for (int fi = 0; fi < 2; ++fi)
#pragma unroll
      for (int fj = 0; fj < 4; ++fj) {
        const int u = ut * 64 + fj * 16 + fr;
        const float lcu = lc[u], sbu = rbA[u];
#pragma unroll
        for (int r = 0; r < 4; ++r) {
          const int t = w * 32 + fi * 16 + kg * 4 + r;
          const float v = (t >= u) ? g[fi][fj][r] * __expf(lct[fi][r] - lcu) * sbu * rct[fi][r] : 0.f;
          Pt[t][fj * 16 + fr] = f2bf(v);
        }
      }
#pragma unroll
    for (int kk = 0; kk < 2; ++kk) {
      bf16x8 xf[4];
#pragma unroll
      for (int fj = 0; fj < 4; ++fj)
        xf[fj] = *(const bf16x8*)&XT[fj * 16 + fr][ut * 64 + kk * 32 + kg * 8];
      bf16x8 pf[2];
#pragma unroll
      for (int fi = 0; fi < 2; ++fi)
        pf[fi] = *(const bf16x8*)&Pt[w * 32 + fi * 16 + fr][kk * 32 + kg * 8];
#pragma unroll
      for (int fi = 0; fi < 2; ++fi)
#pragma unroll
        for (int fj = 0; fj < 4; ++fj)
          yacc[fi][fj] = __builtin_amdgcn_mfma_f32_16x16x32_bf16(pf[fi], xf[fj], yacc[fi][fj], 0, 0, 0);
      const bf16x8 xh = *(const bf16x8*)&XT[w * 16 + fr][ut * 64 + kk * 32 + kg * 8];
#pragma unroll
      for (int fi = 0; fi < 4; ++fi) {
        const bf16x8 bs = *(const bf16x8*)&BsT[fi * 16 + fr][ut * 64 + kk * 32 + kg * 8];
        hacc[fi] = __builtin_amdgcn_mfma_f32_16x16x32_bf16(bs, xh, hacc[fi], 0, 0, 0);
      }
    }
  }
#pragma unroll
  for (int fi = 0; fi < 2; ++fi)
#pragma unroll
    for (int fj = 0; fj < 4; ++fj)
#pragma unroll
      for (int r = 0; r < 4; ++r) {
        const int t = w * 32 + fi * 16 + kg * 4 + r;
        const int d = fj * 16 + fr;
        xz[(size_t)(rbase + t) * N2 + h * DH + d] = f2bf(yacc[fi][fj][r]);
      }
  const int dcol = w * 16 + fr;
#pragma unroll
  for (int fi = 0; fi < 4; ++fi) {
    ushort4 pk;
    pk.x = f2bf(hacc[fi][0]); pk.y = f2bf(hacc[fi][1]);
    pk.z = f2bf(hacc[fi][2]); pk.w = f2bf(hacc[fi][3]);
    *(ushort4*)(Hbuf + ((size_t)blk * 64 + dcol) * 64 + fi * 16 + kg * 4) = pk;
  }
}

// ---------------- chunked scan, stage 2: carry across chunks (in place) --------
__global__ __launch_bounds__(256) void k_carry(unsigned short* __restrict__ Hbuf,
                                               const float* __restrict__ Dc) {
  const int bh = blockIdx.x, tid = threadIdx.x;
  float carry[16];
#pragma unroll
  for (int j = 0; j < 16; ++j) carry[j] = 0.f;
  for (int c = 0; c < NCHUNK; ++c) {
    unsigned short* p = Hbuf + (((size_t)(bh * NCHUNK + c)) << 12) + tid * 16;
    const uint4 v0 = *(const uint4*)(p);
    const uint4 v1 = *(const uint4*)(p + 8);
    const unsigned short* hs0 = (const unsigned short*)&v0;
    const unsigned short* hs1 = (const unsigned short*)&v1;
    float hl[16];
#pragma unroll
    for (int j = 0; j < 8; ++j) { hl[j] = bf2f(hs0[j]); hl[8 + j] = bf2f(hs1[j]); }
    uint4 o0, o1;
    unsigned short* os0 = (unsigned short*)&o0;
    unsigned short* os1 = (unsigned short*)&o1;
#pragma unroll
    for (int j = 0; j < 8; ++j) { os0[j] = f2bf(carry[j]); os1[j] = f2bf(carry[8 + j]); }
    *(uint4*)(p) = o0;
    *(uint4*)(p + 8) = o1;
    const float dc = Dc[bh * NCHUNK + c];
#pragma unroll
    for (int j = 0; j < 16; ++j) carry[j] = fmaf(dc, carry[j], hl[j]);
  }
}

// ---------------- chunked scan, stage 3: inter-chunk Y + fused gating ----------
__global__ __launch_bounds__(256) void k_chunk2(
    const unsigned short* __restrict__ xp2, const float* __restrict__ al,
    const unsigned short* __restrict__ Hbuf, const unsigned short* __restrict__ xz,
    unsigned short* __restrict__ xcg) {
  const int blk = blockIdx.x;
  const int bh = blk >> 4, c = blk & 15;
  const int b = bh / NH, h = bh % NH;
  const int tid = threadIdx.x, w = tid >> 6, lane = tid & 63;
  const int fr = lane & 15, kg = lane >> 4;
  const int rbase = b * LLEN + c * QC;
  const size_t rbase2 = ((size_t)bh << 11) + c * QC;
  __shared__ float lc[QC], rc2[QC];
  __shared__ float wtot[2];
  float a = 1.f, la = 0.f;
  if (tid < QC) { a = al[(size_t)bh * LLEN + c * QC + tid]; la = __logf(a); }
  float s = la;
#pragma unroll
  for (int o = 1; o < 64; o <<= 1) { float t2 = __shfl_up(s, o); if (lane >= o) s += t2; }
  if (tid < QC && lane == 63) wtot[w] = s;
  __syncthreads();
  if (tid < QC) lc[tid] = s + ((w == 1) ? wtot[0] : 0.f);
  __syncthreads();
  bf16x8 cf[2][2];
#pragma unroll
  for (int fi = 0; fi < 2; ++fi) {
    const int t = w * 32 + fi * 16 + fr;
    float ss = 0.f;
#pragma unroll
    for (int kk = 0; kk < 2; ++kk) {
      const uint4 v = *(const uint4*)(xp2 + (rbase2 + t) * XP2LD + 64 + kk * 32 + kg * 8);
      cf[fi][kk] = *(const bf16x8*)&v;
      const unsigned short* cs = (const unsigned short*)&v;
#pragma unroll
      for (int q = 0; q < 8; ++q) { const float cc = bf2f(cs[q]); ss = fmaf(cc, cc, ss); }
    }
    ss += __shfl_xor(ss, 16);
    ss += __shfl_xor(ss, 32);
    if (kg == 0) rc2[t] = 1.f / fmaxf(sqrtf(ss), 1e-12f);
  }
  bf16x8 hf[4][2];
#pragma unroll
  for (int fj = 0; fj < 4; ++fj)
#pragma unroll
    for (int kk = 0; kk < 2; ++kk) {
      const uint4 v = *(const uint4*)(Hbuf + ((size_t)blk * 64 + fj * 16 + fr) * 64 + kk * 32 + kg * 8);
      hf[fj][kk] = *(const bf16x8*)&v;
    }
  __syncthreads();
  f32x4 y[2][4] = {};
#pragma unroll
  for (int kk = 0; kk < 2; ++kk)
#pragma unroll
    for (int fi = 0; fi < 2; ++fi)
#pragma unroll
      for (int fj = 0; fj < 4; ++fj)
        y[fi][fj] = __builtin_amdgcn_mfma_f32_16x16x32_bf16(cf[fi][kk], hf[fj][kk], y[fi][fj], 0, 0, 0);
#pragma unroll
  for (int fi = 0; fi < 2; ++fi)
#pragma unroll
    for (int fj = 0; fj < 4; ++fj)
#pragma unroll
      for (int r = 0; r < 4; ++r) {
        const int t = w * 32 + fi * 16 + kg * 4 + r;
        const int d = fj * 16 + fr;
        const float scl = rc2[t] * __expf(lc[t]);
        const size_t rowg = (size_t)(rbase + t);
        const float yv = y[fi][fj][r] * scl + bf2f(xz[rowg * N2 + h * DH + d]);
        const float zv = bf2f(xz[rowg * N2 + DI + h * DH + d]);
        const float g = yv * (zv / (1.f + __expf(-zv)));
        xcg[rowg * DI + h * DH + d] = f2bf(g);
      }
}

extern "C" void kernel_launch(void* const* d_in, const int* in_sizes, int n_in,
                              void* d_out, int out_size, void* d_ws, size_t ws_size,
                              hipStream_t stream) {
  const float* hs     = (const float*)d_in[0];
  const float* norm_w = (const float*)d_in[1];
  const float* in_w   = (const float*)d_in[2];
  const float* in_b   = (const float*)d_in[3];
  const float* cw     = (const float*)d_in[4];
  const float* cb     = (const float*)d_in[5];
  const float* xw     = (const float*)d_in[6];
  const float* xb     = (const float*)d_in[7];
  const float* A_log  = (const float*)d_in[8];
  const float* l2ab   = (const float*)d_in[9];
  const float* l2b    = (const float*)d_in[10];
  const float* se     = (const float*)d_in[11];
  const float* ow     = (const float*)d_in[12];
  const float* ob     = (const float*)d_in[13];
  const float* rg     = (const float*)d_in[14];
  float* out = (float*)d_out;

  char* ws = (char*)d_ws;
  // layout (~173 MB):
  //   0          xnorm / xcg bf16 (33.5 MB)
  //   33554432   wA bf16 (12.58 MB) -> Hbuf after in_proj
  //   46137344   wX bf16 (9.83 MB)
  //   55967744   wO bf16 (6.29 MB)
  //   62259200   xz bf16 8192x3072 (50.3 MB)
  //   112590848  xp2 bf16 head-blocked 96x2048x136 (53.5 MB)
  //   166068224  xmean fp32 (786 KB)
  //   166854656  al fp32 (786 KB)
  //   167641088  Dc fp32 (6 KB)
  //   167647232  hc fp32 (384 B)
  //   167651328  dtbuf fp32 (786 KB)
  //   168437760  pt fp32 4x8192x32 (4.19 MB)
  unsigned short* xnorm = (unsigned short*)(ws);
  unsigned short* wA    = (unsigned short*)(ws + 33554432ull);
  unsigned short* wX    = (unsigned short*)(ws + 46137344ull);
  unsigned short* wO    = (unsigned short*)(ws + 55967744ull);
  unsigned short* xz    = (unsigned short*)(ws + 62259200ull);
  unsigned short* xp2   = (unsigned short*)(ws + 112590848ull);
  float* xmean          = (float*)(ws + 166068224ull);
  float* al             = (float*)(ws + 166854656ull);
  float* Dc             = (float*)(ws + 167641088ull);
  float* hc             = (float*)(ws + 167647232ull);
  float* dtbuf          = (float*)(ws + 167651328ull);
  float* pt             = (float*)(ws + 168437760ull);
  unsigned short* xcg   = xnorm;
  unsigned short* Hbuf  = wA;

  // fused front: weight convert (56064 blocks) + RMSNorm (8192) + hc (1)
  k_pre<<<WBLK + MROWS + 1, 256, 0, stream>>>(in_w, wA, xw, wX, ow, wO,
                                              hs, norm_w, xnorm,
                                              A_log, l2ab, l2b, se, hc);
  // in_proj: BN=192, 64 x 16 = 1024 blocks (2 exact rounds at 2 blocks/CU)
  k_gemm7<1, 3><<<1024, 512, 0, stream>>>(xnorm, wA, in_b, xz, nullptr, nullptr,
                                          nullptr, 0, DMODEL, 16, N2, N2);
  // conv + silu + xmean
  k_dwconv<<<(MROWS / 4) * 192 / 256, 256, 0, stream>>>(xz, cw, cb, xcg, xmean);
  // x_proj tail (split-K x4, 256 blocks): fp32 partials for cols 3072..3095
  k_tailsk<<<256, 512, 0, stream>>>(xcg, wX, pt);
  // x_proj main: BN=192, cols 0..3071, 64 x 16 = 1024 blocks (2 exact rounds)
  k_gemm7<3, 3><<<1024, 512, 0, stream>>>(xcg, wX, xb, xp2, nullptr, nullptr,
                                          dtbuf, 0, DI, 16, NP, 0);
  // alpha + tail reduce (fused)
  k_alpha2<<<1536, 256, 0, stream>>>(dtbuf, xmean, hc, al, pt, xb, xp2);
  // chunked scan
  k_chunk1<<<BB * NH * NCHUNK, 256, 0, stream>>>(xp2, xcg, al, xz, Hbuf, Dc);
  k_carry<<<BB * NH, 256, 0, stream>>>(Hbuf, Dc);
  k_chunk2<<<BB * NH * NCHUNK, 256, 0, stream>>>(xp2, al, Hbuf, xz, xcg);
  // out_proj: BN=128, 64 x 16 = 1024 blocks (2 exact rounds), fp32 + residual
  k_gemm7<2, 2><<<1024, 512, 0, stream>>>(xcg, wO, ob, out, hs, rg,
                                          nullptr, 0, DI, 16, DMODEL, DMODEL);
}